// Round 5
// baseline (1163.050 us; speedup 1.0000x reference)
//
#include <hip/hip_runtime.h>
#include <hip/hip_bf16.h>

typedef __attribute__((ext_vector_type(8))) short s8v;   // 8 x bf16 (as i16 bits)
typedef __attribute__((ext_vector_type(4))) short s4v;   // 4 x bf16 (8B)
typedef __attribute__((ext_vector_type(4))) float f4v;
typedef unsigned short u16;
typedef unsigned int u32;

__device__ __forceinline__ float b2f(u16 u) {
    union { unsigned int i; float f; } v; v.i = ((unsigned int)u) << 16; return v.f;
}
__device__ __forceinline__ u16 f2b(float f) {
    union { float f; unsigned int i; } v; v.f = f;
    unsigned int r = v.i + 0x7FFFu + ((v.i >> 16) & 1u);  // round-nearest-even
    return (u16)(r >> 16);
}
__device__ __forceinline__ float bv(const s8v& s, int j) { return b2f((u16)s[j]); }
// integer load valid for int32 or int64 (low word) storage
__device__ __forceinline__ int geti(const void* p, long i, int i64) {
    return i64 ? (int)((const u32*)p)[2 * i] : ((const int*)p)[i];
}

// async global -> LDS, 16 bytes per lane (linear LDS dest: uniform base + lane*16)
__device__ __forceinline__ void ld16(const u16* g, u16* l) {
    __builtin_amdgcn_global_load_lds(
        (const __attribute__((address_space(1))) unsigned int*)g,
        (__attribute__((address_space(3))) unsigned int*)l, 16, 0, 0);
}

// ---------------------------------------------------------------------------
// dtype detector: flags[0]=1 floats are bf16 (else f32); flags[1]=1 ints int64.
// ---------------------------------------------------------------------------
__global__ void k_detect(const u16* __restrict__ nf, const u32* __restrict__ EI,
                         int* __restrict__ flags) {
    __shared__ int cnt, nz;
    if (threadIdx.x == 0) { cnt = 0; nz = 0; }
    __syncthreads();
    int c = 0;
    for (int i = threadIdx.x; i < 4096; i += 256) {
        u16 v = nf[2 * i];
        int e = (v >> 7) & 0xFF;
        if (e >= 64 && e < 160) c++;
    }
    atomicAdd(&cnt, c);
    int z = 0;
    for (int i = threadIdx.x; i < 4096; i += 256)
        if (EI[2 * i + 1] != 0) z++;
    atomicAdd(&nz, z);
    __syncthreads();
    if (threadIdx.x == 0) { flags[0] = (cnt >= 2867) ? 1 : 0; flags[1] = (nz == 0) ? 1 : 0; }
}

__global__ void k_cvt(const void* __restrict__ src, float* __restrict__ dst, int n,
                      const int* __restrict__ flags) {
    const int isbf = flags[0];
    int t = blockIdx.x * 256 + threadIdx.x;
    if (t < n) dst[t] = isbf ? b2f(((const u16*)src)[t]) : ((const float*)src)[t];
}

// convert weights to bf16 (copy if already bf16)
__global__ void k_cvt16(const void* __restrict__ src, u16* __restrict__ dst, int n,
                        const int* __restrict__ flags) {
    const int isbf = flags[0];
    int t = blockIdx.x * 256 + threadIdx.x;
    if (t < n) dst[t] = isbf ? ((const u16*)src)[t] : f2b(((const float*)src)[t]);
}

__global__ void k_diag(u16* __restrict__ out, int n, float val) {
    int t = blockIdx.x * 256 + threadIdx.x;
    if (t < n) out[t] = f2b(val);
}

// ---------------------------------------------------------------------------
// GEMM: C[M,Nn] = A[M,K] @ B[Nn,K]^T (+bias f32, optional exact gelu)
// m97 K-loop: 128x128 tile, BK=32, global_load_lds(16B) staging, 4 waves.
// Epilogue: swapped-operand MFMA -> LDS (XOR b64) -> 64B coalesced stores.
// XCD-aware bijective block swizzle (T1/m204): consecutive logical tiles on
// the SAME XCD so A-panels/B are fetched once per XCD L2, not 8x.
// A,B bf16. Nn multiple of 128, K multiple of 32. M tail clamped on load.
// ---------------------------------------------------------------------------
template<int GELU>
__global__ __launch_bounds__(256) void gemm_bt(const u16* __restrict__ A,
                                               const u16* __restrict__ B,
                                               const float* __restrict__ bias,
                                               u16* __restrict__ C,
                                               int M, int Nn, int K) {
    __shared__ u16 smem[128 * 128];  // 32 KB; K-loop uses first 16 KB
    u16* ldsA = smem;                // [128][32] row-major, 8 KB
    u16* ldsB = smem + 4096;         // 8 KB
    const int t = threadIdx.x;
    const int wave = t >> 6;
    const int lane = t & 63;
    const int quad = lane >> 4;
    const int l16  = lane & 15;
    const int wm = wave >> 1, wn = wave & 1;

    // ---- XCD-aware bijective swizzle (consecutive IDs round-robin XCDs) ----
    const int nwg  = gridDim.x * gridDim.y;
    const int orig = blockIdx.y * gridDim.x + blockIdx.x;
    const int xcd  = orig & 7;
    const int qq   = nwg >> 3, rr = nwg & 7;
    const int base_l = (xcd < rr) ? xcd * (qq + 1) : rr * (qq + 1) + (xcd - rr) * qq;
    const int logical = base_l + (orig >> 3);
    const int tx = logical % gridDim.x;
    const int ty = logical / gridDim.x;
    const long m0 = (long)ty * 128;
    const long n0 = (long)tx * 128;

    // staging geometry: round r (0/1), thread t covers tile row (r*256+t)/4,
    // cols (t&3)*8 .. +8  (16 bytes). LDS dest byte = r*4096 + t*16 (linear).
    const int scol = (t & 3) * 8;
    long asrc[2], bsrc[2];
#pragma unroll
    for (int r = 0; r < 2; r++) {
        long ra = m0 + (r * 256 + t) / 4;
        if (ra >= M) ra = M - 1;             // clamp loads; stores guarded
        asrc[r] = ra * (long)K + scol;
        long rb = n0 + (r * 256 + t) / 4;    // Nn multiple of 128: in range
        bsrc[r] = rb * (long)K + scol;
    }
    u16* adst0 = ldsA + t * 8;               // t*16 bytes
    u16* adst1 = ldsA + 2048 + t * 8;        // +4096 bytes
    u16* bdst0 = ldsB + t * 8;
    u16* bdst1 = ldsB + 2048 + t * 8;

    f4v acc[4][4] = {};
    for (int k0 = 0; k0 < K; k0 += 32) {
        ld16(A + asrc[0] + k0, adst0);
        ld16(A + asrc[1] + k0, adst1);
        ld16(B + bsrc[0] + k0, bdst0);
        ld16(B + bsrc[1] + k0, bdst1);
        __syncthreads();                     // drains vmcnt -> LDS tiles ready
        s8v a[4], b[4];
#pragma unroll
        for (int i = 0; i < 4; i++)
            a[i] = *(const s8v*)(ldsA + (wm * 64 + i * 16 + l16) * 32 + quad * 8);
#pragma unroll
        for (int j = 0; j < 4; j++)
            b[j] = *(const s8v*)(ldsB + (wn * 64 + j * 16 + l16) * 32 + quad * 8);
#pragma unroll
        for (int i = 0; i < 4; i++)
#pragma unroll
            for (int j = 0; j < 4; j++)      // swapped operands: transposed frag
                acc[i][j] = __builtin_amdgcn_mfma_f32_16x16x32_bf16(b[j], a[i], acc[i][j], 0, 0, 0);
        __syncthreads();                     // protect LDS before next stage
    }
    // swapped layout: m = wm*64+i*16+l16 (row), n = wn*64+j*16+quad*4+r (col)

    // ---- epilogue stage 1: bias/gelu, pack 4 cols -> b64 LDS write ----
    // chunk = col_local/4 = wn*16+j*4+quad ; swizzle chunk ^ (row_local & 14)
#pragma unroll
    for (int j = 0; j < 4; j++) {
        const long ncol = n0 + wn * 64 + j * 16 + quad * 4;
        f4v bb = {0.f, 0.f, 0.f, 0.f};
        if (bias) bb = *(const f4v*)(bias + ncol);
#pragma unroll
        for (int i = 0; i < 4; i++) {
            const int row_local = wm * 64 + i * 16 + l16;
            const int ch = (wn * 16 + j * 4 + quad) ^ (row_local & 14);
            s4v pk;
#pragma unroll
            for (int r = 0; r < 4; r++) {
                float v = acc[i][j][r] + bb[r];
                if (GELU) v = 0.5f * v * (1.f + erff(v * 0.70710678118654752f));
                pk[r] = (short)f2b(v);
            }
            *(s4v*)(smem + row_local * 128 + ch * 4) = pk;
        }
    }
    __syncthreads();

    // ---- epilogue stage 2: coalesced copy-out, 64B per 4-lane group ----
    // thread t: row = pass*64 + (t>>2), quarter q = t&3; 4 x 16B stores.
    const int q4 = t & 3;
#pragma unroll
    for (int pass = 0; pass < 2; pass++) {
        const int row = pass * 64 + (t >> 2);
        const long grow = m0 + row;
        if (grow < M) {
            const u16* lrow = smem + row * 128;
            const int s = row & 14;
#pragma unroll
            for (int k = 0; k < 4; k++) {
                const int c0 = (q4 * 2 + k * 8) ^ s;   // even -> 16B aligned
                s8v v = *(const s8v*)(lrow + c0 * 4);
                *(s8v*)(C + grow * (long)Nn + n0 + q4 * 8 + k * 32) = v;
            }
        }
    }
}

// ---------------------------------------------------------------------------
// input norm: base = LN(nf + nte[node_type]) * g + b   (one wave per row)
// ---------------------------------------------------------------------------
__global__ __launch_bounds__(256) void k_innorm(const void* __restrict__ nf,
                                                const void* __restrict__ ntype,
                                                const void* __restrict__ nte,
                                                const float* __restrict__ g,
                                                const float* __restrict__ b,
                                                u16* __restrict__ base, int N,
                                                const int* __restrict__ flags) {
    const int isbf = flags[0], i64 = flags[1];
    const int wave = threadIdx.x >> 6, lane = threadIdx.x & 63;
    const int row = blockIdx.x * 4 + wave;
    if (row >= N) return;
    const long off = (long)row * 512 + lane * 8;
    const int nt = geti(ntype, row, i64);
    const long eoff = (long)nt * 512 + lane * 8;
    float x[8];
    if (isbf) {
        s8v xv = *(const s8v*)((const u16*)nf + off);
        s8v ev = *(const s8v*)((const u16*)nte + eoff);
#pragma unroll
        for (int j = 0; j < 8; j++) x[j] = bv(xv, j) + bv(ev, j);
    } else {
        f4v x0 = *(const f4v*)((const float*)nf + off);
        f4v x1 = *(const f4v*)((const float*)nf + off + 4);
        f4v e0 = *(const f4v*)((const float*)nte + eoff);
        f4v e1 = *(const f4v*)((const float*)nte + eoff + 4);
#pragma unroll
        for (int j = 0; j < 4; j++) { x[j] = x0[j] + e0[j]; x[4 + j] = x1[j] + e1[j]; }
    }
    float s = 0.f, s2 = 0.f;
#pragma unroll
    for (int j = 0; j < 8; j++) { s += x[j]; s2 += x[j] * x[j]; }
#pragma unroll
    for (int o = 32; o >= 1; o >>= 1) { s += __shfl_xor(s, o); s2 += __shfl_xor(s2, o); }
    const float mu = s * (1.f / 512.f);
    const float rs = rsqrtf(s2 * (1.f / 512.f) - mu * mu + 1e-5f);
    f4v g0 = *(const f4v*)(g + lane * 8); f4v g1 = *(const f4v*)(g + lane * 8 + 4);
    f4v b0 = *(const f4v*)(b + lane * 8); f4v b1 = *(const f4v*)(b + lane * 8 + 4);
    s8v o;
#pragma unroll
    for (int j = 0; j < 8; j++) {
        const float gg = j < 4 ? g0[j] : g1[j - 4];
        const float bb = j < 4 ? b0[j] : b1[j - 4];
        o[j] = (short)f2b((x[j] - mu) * rs * gg + bb);
    }
    *(s8v*)(base + off) = o;
}

// ===========================================================================
// FAST PATH: CSR build + gather (no feature atomics)
// ===========================================================================
__global__ __launch_bounds__(256) void k_count(const void* __restrict__ EI,
                                               u32* __restrict__ cnt, int E,
                                               const int* __restrict__ flags) {
    const int i64 = flags[1];
    const int t = blockIdx.x * 256 + threadIdx.x;
    if (t >= 2 * E) return;
    const int ed = (t < E) ? t : t - E;
    const int dst = (t < E) ? geti(EI, E + ed, i64) : geti(EI, ed, i64);
    atomicAdd(&cnt[dst], 1u);
}

// single-workgroup exclusive scan (1024 threads, Hillis-Steele per chunk)
__global__ __launch_bounds__(1024) void k_scan(const u32* __restrict__ cnt,
                                               u32* __restrict__ indptr, int N) {
    __shared__ u32 buf[1024];
    __shared__ u32 carry;
    if (threadIdx.x == 0) carry = 0;
    __syncthreads();
    for (int b0 = 0; b0 < N; b0 += 1024) {
        const int i = b0 + threadIdx.x;
        const u32 v = (i < N) ? cnt[i] : 0u;
        buf[threadIdx.x] = v;
        __syncthreads();
        for (int o = 1; o < 1024; o <<= 1) {
            u32 t = (threadIdx.x >= (u32)o) ? buf[threadIdx.x - o] : 0u;
            __syncthreads();
            buf[threadIdx.x] += t;
            __syncthreads();
        }
        const u32 excl = carry + buf[threadIdx.x] - v;
        __syncthreads();
        if (threadIdx.x == 1023) carry += buf[1023];
        if (i < N) indptr[i] = excl;
        __syncthreads();
    }
    if (threadIdx.x == 0) indptr[N] = carry;
}

__global__ void k_copy32(const u32* __restrict__ src, u32* __restrict__ dst, int n) {
    int t = blockIdx.x * 256 + threadIdx.x;
    if (t < n) dst[t] = src[t];
}

__global__ __launch_bounds__(256) void k_fill(const void* __restrict__ EI,
                                              const void* __restrict__ ET,
                                              const float* __restrict__ EW,
                                              u32* __restrict__ cursor,
                                              u32* __restrict__ srcrel,
                                              float* __restrict__ wts, int E,
                                              const int* __restrict__ flags) {
    const int i64 = flags[1];
    const int t = blockIdx.x * 256 + threadIdx.x;
    if (t >= 2 * E) return;
    int ed, src, dst, r;
    if (t < E) { ed = t;     r = geti(ET, ed, i64);     src = geti(EI, ed, i64);     dst = geti(EI, E + ed, i64); }
    else       { ed = t - E; r = geti(ET, ed, i64) + 2; src = geti(EI, E + ed, i64); dst = geti(EI, ed, i64); }
    const u32 pos = atomicAdd(&cursor[dst], 1u);
    srcrel[pos] = (u32)src | ((u32)r << 28);
    wts[pos] = EW[ed];
}

// gather + n1 fused: x1 = LN(base + S + b_self + agg/max(deg,1)) * g + b
// agg[d] = sum_e w*(Y4[src, rel*512+c]) + sum_r wsum_r * brel[r][c]
__global__ __launch_bounds__(256) void k_gather_n1(const u32* __restrict__ indptr,
                                                   const u32* __restrict__ srcrel,
                                                   const float* __restrict__ wts,
                                                   const u16* __restrict__ Y4,   // [N,2048]
                                                   const u16* __restrict__ S,    // [N,512]
                                                   const u16* __restrict__ base,
                                                   const float* __restrict__ brel,  // [4,512]
                                                   const float* __restrict__ bself,
                                                   const float* __restrict__ g,
                                                   const float* __restrict__ b,
                                                   u16* __restrict__ x1, int N) {
    const int wave = threadIdx.x >> 6, lane = threadIdx.x & 63;
    const int row = blockIdx.x * 4 + wave;
    if (row >= N) return;
    const int colb = lane * 8;
    float acc[8] = {}; float wsum[4] = {};
    const u32 beg = indptr[row], end = indptr[row + 1];
    for (u32 i = beg; i < end; i++) {
        const u32 pr = srcrel[i];
        const int src = (int)(pr & 0x0FFFFFFFu);
        const int rel = (int)(pr >> 28);
        const float w = wts[i];
        s8v yv = *(const s8v*)(Y4 + (long)src * 2048 + rel * 512 + colb);
#pragma unroll
        for (int j = 0; j < 8; j++) acc[j] += w * bv(yv, j);
        wsum[rel] += w;
    }
    const float deg = wsum[0] + wsum[1] + wsum[2] + wsum[3];
    const float dmx = 1.f / fmaxf(deg, 1.f);
    const long off = (long)row * 512 + colb;
    s8v sv = *(const s8v*)(S + off);
    s8v bs = *(const s8v*)(base + off);
    f4v sb0 = *(const f4v*)(bself + colb);
    f4v sb1 = *(const f4v*)(bself + colb + 4);
    // bias contribution from each relation
    float x[8], s = 0.f, s2 = 0.f;
#pragma unroll
    for (int h = 0; h < 2; h++) {
        f4v br0 = *(const f4v*)(brel + 0 * 512 + colb + 4 * h);
        f4v br1 = *(const f4v*)(brel + 1 * 512 + colb + 4 * h);
        f4v br2 = *(const f4v*)(brel + 2 * 512 + colb + 4 * h);
        f4v br3 = *(const f4v*)(brel + 3 * 512 + colb + 4 * h);
#pragma unroll
        for (int q = 0; q < 4; q++) {
            const int j = h * 4 + q;
            const float bias4 = wsum[0] * br0[q] + wsum[1] * br1[q] + wsum[2] * br2[q] + wsum[3] * br3[q];
            const float sbv = h ? sb1[q] : sb0[q];
            x[j] = bv(bs, j) + bv(sv, j) + sbv + (acc[j] + bias4) * dmx;
            s += x[j]; s2 += x[j] * x[j];
        }
    }
#pragma unroll
    for (int o = 32; o >= 1; o >>= 1) { s += __shfl_xor(s, o); s2 += __shfl_xor(s2, o); }
    const float mu = s * (1.f / 512.f);
    const float rs = rsqrtf(s2 * (1.f / 512.f) - mu * mu + 1e-5f);
    f4v g0 = *(const f4v*)(g + colb); f4v g1 = *(const f4v*)(g + colb + 4);
    f4v b0 = *(const f4v*)(b + colb); f4v b1 = *(const f4v*)(b + colb + 4);
    s8v o;
#pragma unroll
    for (int j = 0; j < 8; j++) {
        const float gg = j < 4 ? g0[j] : g1[j - 4];
        const float bb = j < 4 ? b0[j] : b1[j - 4];
        o[j] = (short)f2b((x[j] - mu) * rs * gg + bb);
    }
    *(s8v*)(x1 + off) = o;
}

// ===========================================================================
// SLOW PATH kernels (proven r3 fallback): scatter with f32 atomics
// ===========================================================================
__global__ __launch_bounds__(256) void k_deg(const void* __restrict__ EI,
                                             const float* __restrict__ EW,
                                             float* __restrict__ deg, int E,
                                             const int* __restrict__ flags) {
    const int i64 = flags[1];
    const int t = blockIdx.x * 256 + threadIdx.x;
    if (t >= 2 * E) return;
    const int ed = (t < E) ? t : t - E;
    const int dst = (t < E) ? geti(EI, E + ed, i64) : geti(EI, ed, i64);
    atomicAdd(&deg[dst], EW[ed]);
}

__global__ __launch_bounds__(256) void k_scatter(const void* __restrict__ EI,
                                                 const void* __restrict__ ET,
                                                 const float* __restrict__ EW,
                                                 const u16* __restrict__ Y,
                                                 const float* __restrict__ brel,
                                                 float* __restrict__ agg, int E, int rel,
                                                 const int* __restrict__ flags) {
    const int i64 = flags[1];
    const int wave = threadIdx.x >> 6, lane = threadIdx.x & 63;
    const long eid = (long)blockIdx.x * 4 + wave;
    if (eid >= 2 * (long)E) return;
    int ed, src, dst, r;
    if (eid < E) { ed = (int)eid;       r = geti(ET, ed, i64);     src = geti(EI, ed, i64);     dst = geti(EI, E + ed, i64); }
    else         { ed = (int)(eid - E); r = geti(ET, ed, i64) + 2; src = geti(EI, E + ed, i64); dst = geti(EI, ed, i64); }
    if (r != rel) return;
    const float w = EW[ed];
    s8v yv = *(const s8v*)(Y + (long)src * 512 + lane * 8);
    const float* bb = brel + (long)rel * 512 + lane * 8;
    float* ag = agg + (long)dst * 512 + lane * 8;
#pragma unroll
    for (int j = 0; j < 8; j++) atomicAdd(ag + j, w * (bv(yv, j) + bb[j]));
}

__global__ __launch_bounds__(256) void k_n1(const u16* __restrict__ S,
                                            const float* __restrict__ agg,
                                            const float* __restrict__ deg,
                                            const float* __restrict__ bself,
                                            const u16* __restrict__ base,
                                            const float* __restrict__ g,
                                            const float* __restrict__ b,
                                            u16* __restrict__ x1, int N) {
    const int wave = threadIdx.x >> 6, lane = threadIdx.x & 63;
    const int row = blockIdx.x * 4 + wave;
    if (row >= N) return;
    const long off = (long)row * 512 + lane * 8;
    s8v sv = *(const s8v*)(S + off);
    s8v bs = *(const s8v*)(base + off);
    f4v a0 = *(const f4v*)(agg + off);
    f4v a1 = *(const f4v*)(agg + off + 4);
    f4v sb0 = *(const f4v*)(bself + lane * 8);
    f4v sb1 = *(const f4v*)(bself + lane * 8 + 4);
    const float dmx = 1.f / fmaxf(deg[row], 1.f);
    float x[8], s = 0.f, s2 = 0.f;
#pragma unroll
    for (int j = 0; j < 8; j++) {
        const float av = (j < 4 ? a0[j] : a1[j - 4]);
        const float sbv = (j < 4 ? sb0[j] : sb1[j - 4]);
        x[j] = bv(bs, j) + bv(sv, j) + sbv + av * dmx;
        s += x[j]; s2 += x[j] * x[j];
    }
#pragma unroll
    for (int o = 32; o >= 1; o >>= 1) { s += __shfl_xor(s, o); s2 += __shfl_xor(s2, o); }
    const float mu = s * (1.f / 512.f);
    const float rs = rsqrtf(s2 * (1.f / 512.f) - mu * mu + 1e-5f);
    f4v g0 = *(const f4v*)(g + lane * 8); f4v g1 = *(const f4v*)(g + lane * 8 + 4);
    f4v b0 = *(const f4v*)(b + lane * 8); f4v b1 = *(const f4v*)(b + lane * 8 + 4);
    s8v o;
#pragma unroll
    for (int j = 0; j < 8; j++) {
        const float gg = j < 4 ? g0[j] : g1[j - 4];
        const float bb = j < 4 ? b0[j] : b1[j - 4];
        o[j] = (short)f2b((x[j] - mu) * rs * gg + bb);
    }
    *(s8v*)(x1 + off) = o;
}

// ---------------------------------------------------------------------------
// final: two LNs + graph-mix; writes final x bf16 IN PLACE over fio.
// (pure streaming; column sum done by k_colsum afterwards — no atomics here)
// ---------------------------------------------------------------------------
__global__ __launch_bounds__(256) void k_final(const u16* __restrict__ x1,
                                               u16* fio,
                                               const u16* __restrict__ base,
                                               const float* __restrict__ n2g,
                                               const float* __restrict__ n2b,
                                               const float* __restrict__ og,
                                               const float* __restrict__ ob,
                                               const float* __restrict__ gml,
                                               int N) {
    const int wave = threadIdx.x >> 6, lane = threadIdx.x & 63;
    const int row = blockIdx.x * 4 + wave;
    if (row >= N) return;
    const long off = (long)row * 512 + lane * 8;
    s8v xv = *(const s8v*)(x1 + off);
    s8v fv = *(const s8v*)(fio + off);
    float x[8], s = 0.f, s2 = 0.f;
#pragma unroll
    for (int j = 0; j < 8; j++) { x[j] = bv(xv, j) + bv(fv, j); s += x[j]; s2 += x[j] * x[j]; }
#pragma unroll
    for (int o = 32; o >= 1; o >>= 1) { s += __shfl_xor(s, o); s2 += __shfl_xor(s2, o); }
    float mu = s * (1.f / 512.f);
    float rs = rsqrtf(s2 * (1.f / 512.f) - mu * mu + 1e-5f);
    f4v g10 = *(const f4v*)(n2g + lane * 8); f4v g11 = *(const f4v*)(n2g + lane * 8 + 4);
    f4v b10 = *(const f4v*)(n2b + lane * 8); f4v b11 = *(const f4v*)(n2b + lane * 8 + 4);
    float t[8]; s = 0.f; s2 = 0.f;
#pragma unroll
    for (int j = 0; j < 8; j++) {
        const float gg = j < 4 ? g10[j] : g11[j - 4];
        const float bb = j < 4 ? b10[j] : b11[j - 4];
        t[j] = (x[j] - mu) * rs * gg + bb;
        s += t[j]; s2 += t[j] * t[j];
    }
#pragma unroll
    for (int o = 32; o >= 1; o >>= 1) { s += __shfl_xor(s, o); s2 += __shfl_xor(s2, o); }
    mu = s * (1.f / 512.f);
    rs = rsqrtf(s2 * (1.f / 512.f) - mu * mu + 1e-5f);
    f4v g20 = *(const f4v*)(og + lane * 8); f4v g21 = *(const f4v*)(og + lane * 8 + 4);
    f4v b20 = *(const f4v*)(ob + lane * 8); f4v b21 = *(const f4v*)(ob + lane * 8 + 4);
    s8v bs = *(const s8v*)(base + off);
    const float gm = 1.f / (1.f + expf(-gml[0]));
    s8v o;
#pragma unroll
    for (int j = 0; j < 8; j++) {
        const float gg = j < 4 ? g20[j] : g21[j - 4];
        const float bb = j < 4 ? b20[j] : b21[j - 4];
        const float u = (t[j] - mu) * rs * gg + bb;
        const float bsv = bv(bs, j);
        o[j] = (short)f2b(bsv + gm * (u - bsv));
    }
    *(s8v*)(fio + off) = o;
}

// ---------------------------------------------------------------------------
// column sum of final bf16 x: deterministic two-stage, zero atomics.
// stage 1: 512 blocks; block b accumulates rows b, b+512, ... (2 cols/thread)
// ---------------------------------------------------------------------------
__global__ __launch_bounds__(256) void k_colsum(const u16* __restrict__ x,
                                                float* __restrict__ partial, int N) {
    const int b = blockIdx.x, t = threadIdx.x;
    float s0 = 0.f, s1 = 0.f;
    for (int r = b; r < N; r += gridDim.x) {
        const u32 v = *(const u32*)(x + (long)r * 512 + 2 * t);
        s0 += b2f((u16)(v & 0xFFFFu));
        s1 += b2f((u16)(v >> 16));
    }
    partial[(long)b * 512 + 2 * t]     = s0;
    partial[(long)b * 512 + 2 * t + 1] = s1;
}

__global__ void k_emit(const u16* __restrict__ xout, void* __restrict__ dout, long n,
                       const int* __restrict__ flags) {
    const int isbf = flags[0];
    const long t = ((long)blockIdx.x * 256 + threadIdx.x) * 8;
    if (t >= n) return;
    s8v v = *(const s8v*)(xout + t);
    if (isbf) {
        *(s8v*)((u16*)dout + t) = v;
    } else {
        f4v o0, o1;
#pragma unroll
        for (int j = 0; j < 4; j++) { o0[j] = bv(v, j); o1[j] = bv(v, 4 + j); }
        *(f4v*)((float*)dout + t) = o0;
        *(f4v*)((float*)dout + t + 4) = o1;
    }
}

// stage 2 + pooled: sum 512 partial rows, mix with x[0]
__global__ void k_pooled(const u16* __restrict__ xout, const float* __restrict__ partial,
                         int npart, const float* __restrict__ dml, void* __restrict__ dout,
                         long pool_off, int N, const int* __restrict__ flags) {
    const int isbf = flags[0];
    const int c = threadIdx.x;  // 512
    float cs = 0.f;
    for (int p = 0; p < npart; p++) cs += partial[(long)p * 512 + c];
    const float dm = 1.f / (1.f + expf(-dml[0]));
    const float v = dm * b2f(xout[c]) + (1.f - dm) * (cs / (float)N);
    if (isbf) ((u16*)dout)[pool_off + c] = f2b(v);
    else      ((float*)dout)[pool_off + c] = v;
}

// ---------------------------------------------------------------------------
extern "C" void kernel_launch(void* const* d_in, const int* in_sizes, int n_in,
                              void* d_out, int out_size, void* d_ws, size_t ws_size,
                              hipStream_t stream) {
    const void* nf    = d_in[0];
    const void* EI    = d_in[1];
    const void* ET    = d_in[2];
    const void* NT    = d_in[3];
    const void* EW    = d_in[4];
    const void* NTE   = d_in[5];
    const void* Wself = d_in[6];
    const void* bself = d_in[7];
    const void* Wrel  = d_in[8];
    const void* brel  = d_in[9];
    const void* ing   = d_in[10];
    const void* inb   = d_in[11];
    const void* n1g   = d_in[12];
    const void* n1b   = d_in[13];
    const void* Wf1   = d_in[14];
    const void* bf1   = d_in[15];
    const void* Wf2   = d_in[16];
    const void* bf2   = d_in[17];
    const void* n2g   = d_in[18];
    const void* n2b   = d_in[19];
    const void* outg  = d_in[20];
    const void* outb  = d_in[21];
    const void* gml   = d_in[22];
    const void* dml   = d_in[23];

    const int N = in_sizes[0] / 512;     // 50000
    const int E = in_sizes[2];           // 100000

    const size_t ND2 = (size_t)N * 512 * 2;
    const size_t ND4 = (size_t)N * 512 * 4;
    const size_t arena_elems = (size_t)E + 2048 + 512 * 10 + 1024 + 2;
    const size_t arena_bytes = arena_elems * 4;
    // bf16 weight buffers: Wrel(4*512*512) + Wself(512*512) + Wf1(1024*512) + Wf2(512*1024)
    const size_t WRELN = 4ull * 512 * 512, WSELFN = 512ull * 512;
    const size_t WF1N = 1024ull * 512, WF2N = 512ull * 1024;
    const size_t WBFB = (WRELN + WSELFN + WF1N + WF2N) * 2;   // bytes
    const int NPART = 512;
    const size_t partB = (size_t)NPART * 512 * 4;             // 1 MB partial colsums

    // fast path: base + Y4[N,2048]bf16 + S + CSR + misc + bf16 weights
    const size_t Y4B = (size_t)N * 2048 * 2;
    const size_t csrB = (size_t)(N + 1) * 4 + (size_t)N * 4 + (size_t)(2 * E) * 4 * 2;
    const size_t need_fast = ND2 + Y4B + ND2 + csrB + partB + 64 + WBFB + arena_bytes;
    // slow path (r3-proven): base + agg f32 + Ybuf + deg/partial/flags + weights + arena
    const size_t need_slow = ND2 + ND4 + ND2 + (size_t)N * 4 + partB + 64 + WBFB + arena_bytes;

    const int rowBlocks = (N + 3) / 4;
    const dim3 g512(512 / 128, (N + 127) / 128);
    const dim3 g1024(1024 / 128, (N + 127) / 128);
    const dim3 g2048(2048 / 128, (N + 127) / 128);

    if (ws_size >= need_fast) {
        // ------------------- FAST PATH: CSR gather -------------------
        char* p = (char*)d_ws;
        u16*   base   = (u16*)p;                         // ND2
        u16*   Y4     = (u16*)(p + ND2);                 // Y4B; later aliased by mid
        u16*   mid    = Y4;                              // FFN hidden [N,1024] bf16
        u16*   Sbuf   = (u16*)(p + ND2 + Y4B);           // ND2: S, later ffn_out/final x
        char*  q      = p + ND2 + Y4B + ND2;
        u32*   indptr = (u32*)q;                 q += (size_t)(N + 1) * 4;
        u32*   cursor = (u32*)q;                 q += (size_t)N * 4;   // also cnt
        u32*   srcrel = (u32*)q;                 q += (size_t)(2 * E) * 4;
        float* wts    = (float*)q;               q += (size_t)(2 * E) * 4;
        float* partial= (float*)q;               q += partB;
        int*   flags  = (int*)q;                 q += 64;
        u16*   wrelc  = (u16*)q;                 q += WRELN * 2;
        u16*   wselfc = (u16*)q;                 q += WSELFN * 2;
        u16*   wf1c   = (u16*)q;                 q += WF1N * 2;
        u16*   wf2c   = (u16*)q;                 q += WF2N * 2;
        float* arena  = (float*)q;
        float* EWc   = arena;
        float* brelc = EWc + E;
        float* bselfc= brelc + 2048;
        float* ingc  = bselfc + 512;
        float* inbc  = ingc + 512;
        float* n1gc  = inbc + 512;
        float* n1bc  = n1gc + 512;
        float* bf1c  = n1bc + 512;
        float* bf2c  = bf1c + 1024;
        float* n2gc  = bf2c + 512;
        float* n2bc  = n2gc + 512;
        float* outgc = n2bc + 512;
        float* outbc = outgc + 512;
        float* gmlc  = outbc + 512;
        float* dmlc  = gmlc + 1;
        u16* x1 = (u16*)d_out;          // bf16 intermediate; overwritten by k_emit

        k_detect<<<1, 256, 0, stream>>>((const u16*)nf, (const u32*)EI, flags);
        hipMemsetAsync(cursor, 0, (size_t)N * 4, stream);   // cnt

        auto cvt = [&](const void* s, float* d, int n) {
            k_cvt<<<(n + 255) / 256, 256, 0, stream>>>(s, d, n, flags);
        };
        auto cvt16 = [&](const void* s, u16* d, int n) {
            k_cvt16<<<(n + 255) / 256, 256, 0, stream>>>(s, d, n, flags);
        };
        cvt(EW, EWc, E);        cvt(brel, brelc, 2048);  cvt(bself, bselfc, 512);
        cvt(ing, ingc, 512);    cvt(inb, inbc, 512);     cvt(n1g, n1gc, 512);
        cvt(n1b, n1bc, 512);    cvt(bf1, bf1c, 1024);    cvt(bf2, bf2c, 512);
        cvt(n2g, n2gc, 512);    cvt(n2b, n2bc, 512);     cvt(outg, outgc, 512);
        cvt(outb, outbc, 512);  cvt(gml, gmlc, 1);       cvt(dml, dmlc, 1);
        cvt16(Wrel, wrelc, (int)WRELN);   cvt16(Wself, wselfc, (int)WSELFN);
        cvt16(Wf1, wf1c, (int)WF1N);      cvt16(Wf2, wf2c, (int)WF2N);

        k_innorm<<<rowBlocks, 256, 0, stream>>>(nf, NT, NTE, ingc, inbc, base, N, flags);
        // CSR build
        k_count<<<(2 * E + 255) / 256, 256, 0, stream>>>(EI, cursor, E, flags);
        k_scan<<<1, 1024, 0, stream>>>(cursor, indptr, N);
        k_copy32<<<(N + 255) / 256, 256, 0, stream>>>(indptr, cursor, N);
        k_fill<<<(2 * E + 255) / 256, 256, 0, stream>>>(EI, ET, EWc, cursor, srcrel, wts, E, flags);
        // transforms: Y4 = base @ Wrel_cat^T   ;   S = base @ Wself^T
        gemm_bt<0><<<g2048, 256, 0, stream>>>(base, wrelc, nullptr, Y4, N, 2048, 512);
        gemm_bt<0><<<g512, 256, 0, stream>>>(base, wselfc, nullptr, Sbuf, N, 512, 512);
        // fused gather + n1
        k_gather_n1<<<rowBlocks, 256, 0, stream>>>(indptr, srcrel, wts, Y4, Sbuf, base,
                                                   brelc, bselfc, n1gc, n1bc, x1, N);
        // FFN (mid aliases Y4, which is dead now; ffn_out into Sbuf, dead too)
        gemm_bt<1><<<g1024, 256, 0, stream>>>(x1, wf1c, bf1c, mid, N, 1024, 512);
        gemm_bt<0><<<g512, 256, 0, stream>>>(mid, wf2c, bf2c, Sbuf, N, 512, 1024);

        k_final<<<rowBlocks, 256, 0, stream>>>(x1, Sbuf, base, n2gc, n2bc, outgc, outbc,
                                               gmlc, N);
        k_colsum<<<NPART, 256, 0, stream>>>(Sbuf, partial, N);
        k_emit<<<(int)(((long)N * 512 / 8 + 255) / 256), 256, 0, stream>>>(Sbuf, d_out,
                                                                           (long)N * 512, flags);
        k_pooled<<<1, 512, 0, stream>>>(Sbuf, partial, NPART, dmlc, d_out, (long)N * 512, N, flags);

    } else if (ws_size >= need_slow) {
        // ------------------- SLOW PATH (r3-proven) -------------------
        char* p = (char*)d_ws;
        u16*   base = (u16*)p;
        float* agg  = (float*)(p + ND2);
        u16*   mid  = (u16*)(p + ND2);
        u16*   Ybuf = (u16*)(p + ND2 + ND4);
        float* deg  = (float*)(p + ND2 + ND4 + ND2);
        float* partial = deg + N;
        int*   flags  = (int*)(partial + NPART * 512);
        char*  q2     = (char*)flags + 64;
        u16*   wrelc  = (u16*)q2;                q2 += WRELN * 2;
        u16*   wselfc = (u16*)q2;                q2 += WSELFN * 2;
        u16*   wf1c   = (u16*)q2;                q2 += WF1N * 2;
        u16*   wf2c   = (u16*)q2;                q2 += WF2N * 2;
        float* arena  = (float*)q2;
        float* EWc   = arena;
        float* brelc = EWc + E;
        float* bselfc= brelc + 2048;
        float* ingc  = bselfc + 512;
        float* inbc  = ingc + 512;
        float* n1gc  = inbc + 512;
        float* n1bc  = n1gc + 512;
        float* bf1c  = n1bc + 512;
        float* bf2c  = bf1c + 1024;
        float* n2gc  = bf2c + 512;
        float* n2bc  = n2gc + 512;
        float* outgc = n2bc + 512;
        float* outbc = outgc + 512;
        float* gmlc  = outbc + 512;
        float* dmlc  = gmlc + 1;
        u16* x1 = (u16*)d_out;

        k_detect<<<1, 256, 0, stream>>>((const u16*)nf, (const u32*)EI, flags);
        hipMemsetAsync(agg, 0, ND4, stream);
        hipMemsetAsync(deg, 0, (size_t)N * 4, stream);

        auto cvt = [&](const void* s, float* d, int n) {
            k_cvt<<<(n + 255) / 256, 256, 0, stream>>>(s, d, n, flags);
        };
        auto cvt16 = [&](const void* s, u16* d, int n) {
            k_cvt16<<<(n + 255) / 256, 256, 0, stream>>>(s, d, n, flags);
        };
        cvt(EW, EWc, E);        cvt(brel, brelc, 2048);  cvt(bself, bselfc, 512);
        cvt(ing, ingc, 512);    cvt(inb, inbc, 512);     cvt(n1g, n1gc, 512);
        cvt(n1b, n1bc, 512);    cvt(bf1, bf1c, 1024);    cvt(bf2, bf2c, 512);
        cvt(n2g, n2gc, 512);    cvt(n2b, n2bc, 512);     cvt(outg, outgc, 512);
        cvt(outb, outbc, 512);  cvt(gml, gmlc, 1);       cvt(dml, dmlc, 1);
        cvt16(Wrel, wrelc, (int)WRELN);   cvt16(Wself, wselfc, (int)WSELFN);
        cvt16(Wf1, wf1c, (int)WF1N);      cvt16(Wf2, wf2c, (int)WF2N);

        k_innorm<<<rowBlocks, 256, 0, stream>>>(nf, NT, NTE, ingc, inbc, base, N, flags);
        k_deg<<<(2 * E + 255) / 256, 256, 0, stream>>>(EI, EWc, deg, E, flags);

        for (int r = 0; r < 4; r++) {
            gemm_bt<0><<<g512, 256, 0, stream>>>(base, wrelc + (size_t)r * 512 * 512, nullptr,
                                                 Ybuf, N, 512, 512);
            k_scatter<<<(2 * E + 3) / 4, 256, 0, stream>>>(EI, ET, EWc, Ybuf, brelc, agg,
                                                           E, r, flags);
        }

        gemm_bt<0><<<g512, 256, 0, stream>>>(base, wselfc, nullptr, Ybuf, N, 512, 512);
        k_n1<<<rowBlocks, 256, 0, stream>>>(Ybuf, agg, deg, bselfc, base, n1gc, n1bc, x1, N);

        gemm_bt<1><<<g1024, 256, 0, stream>>>(x1, wf1c, bf1c, mid, N, 1024, 512);
        gemm_bt<0><<<g512, 256, 0, stream>>>(mid, wf2c, bf2c, Ybuf, N, 512, 1024);

        k_final<<<rowBlocks, 256, 0, stream>>>(x1, Ybuf, base, n2gc, n2bc, outgc, outbc,
                                               gmlc, N);
        k_colsum<<<NPART, 256, 0, stream>>>(Ybuf, partial, N);
        k_emit<<<(int)(((long)N * 512 / 8 + 255) / 256), 256, 0, stream>>>(Ybuf, d_out,
                                                                           (long)N * 512, flags);
        k_pooled<<<1, 512, 0, stream>>>(Ybuf, partial, NPART, dmlc, d_out, (long)N * 512, N, flags);
    } else {
        const float val = 2000.f + (float)(ws_size >> 20);
        k_diag<<<(out_size + 255) / 256, 256, 0, stream>>>((u16*)d_out, out_size, val);
    }
}

// Round 6
// 986.859 us; speedup vs baseline: 1.1785x; 1.1785x over previous
//
#include <hip/hip_runtime.h>
#include <hip/hip_bf16.h>

typedef __attribute__((ext_vector_type(8))) short s8v;   // 8 x bf16 (as i16 bits)
typedef __attribute__((ext_vector_type(4))) short s4v;   // 4 x bf16 (8B)
typedef __attribute__((ext_vector_type(4))) float f4v;
typedef unsigned short u16;
typedef unsigned int u32;

__device__ __forceinline__ float b2f(u16 u) {
    union { unsigned int i; float f; } v; v.i = ((unsigned int)u) << 16; return v.f;
}
__device__ __forceinline__ u16 f2b(float f) {
    union { float f; unsigned int i; } v; v.f = f;
    unsigned int r = v.i + 0x7FFFu + ((v.i >> 16) & 1u);  // round-nearest-even
    return (u16)(r >> 16);
}
__device__ __forceinline__ float bv(const s8v& s, int j) { return b2f((u16)s[j]); }
// integer load valid for int32 or int64 (low word) storage
__device__ __forceinline__ int geti(const void* p, long i, int i64) {
    return i64 ? (int)((const u32*)p)[2 * i] : ((const int*)p)[i];
}

// async global -> LDS, 16 bytes per lane (linear LDS dest: uniform base + lane*16)
__device__ __forceinline__ void ld16(const u16* g, u16* l) {
    __builtin_amdgcn_global_load_lds(
        (const __attribute__((address_space(1))) unsigned int*)g,
        (__attribute__((address_space(3))) unsigned int*)l, 16, 0, 0);
}

// ---------------------------------------------------------------------------
// dtype detector: flags[0]=1 floats are bf16 (else f32); flags[1]=1 ints int64.
// ---------------------------------------------------------------------------
__global__ void k_detect(const u16* __restrict__ nf, const u32* __restrict__ EI,
                         int* __restrict__ flags) {
    __shared__ int cnt, nz;
    if (threadIdx.x == 0) { cnt = 0; nz = 0; }
    __syncthreads();
    int c = 0;
    for (int i = threadIdx.x; i < 4096; i += 256) {
        u16 v = nf[2 * i];
        int e = (v >> 7) & 0xFF;
        if (e >= 64 && e < 160) c++;
    }
    atomicAdd(&cnt, c);
    int z = 0;
    for (int i = threadIdx.x; i < 4096; i += 256)
        if (EI[2 * i + 1] != 0) z++;
    atomicAdd(&nz, z);
    __syncthreads();
    if (threadIdx.x == 0) { flags[0] = (cnt >= 2867) ? 1 : 0; flags[1] = (nz == 0) ? 1 : 0; }
}

__global__ void k_cvt(const void* __restrict__ src, float* __restrict__ dst, int n,
                      const int* __restrict__ flags) {
    const int isbf = flags[0];
    int t = blockIdx.x * 256 + threadIdx.x;
    if (t < n) dst[t] = isbf ? b2f(((const u16*)src)[t]) : ((const float*)src)[t];
}

// convert weights to bf16 (copy if already bf16)
__global__ void k_cvt16(const void* __restrict__ src, u16* __restrict__ dst, int n,
                        const int* __restrict__ flags) {
    const int isbf = flags[0];
    int t = blockIdx.x * 256 + threadIdx.x;
    if (t < n) dst[t] = isbf ? ((const u16*)src)[t] : f2b(((const float*)src)[t]);
}

__global__ void k_diag(u16* __restrict__ out, int n, float val) {
    int t = blockIdx.x * 256 + threadIdx.x;
    if (t < n) out[t] = f2b(val);
}

// ---------------------------------------------------------------------------
// GEMM: C[M,Nn] = A[M,K] @ B[Nn,K]^T (+bias f32, optional exact gelu)
// m97 K-loop: 128x128 tile, BK=32, global_load_lds(16B) staging, 4 waves.
// Epilogue: swapped-operand MFMA -> LDS (XOR b64) -> 64B coalesced stores.
// XCD-aware bijective block swizzle (T1/m204): consecutive logical tiles on
// the SAME XCD so A-panels/B are fetched once per XCD L2, not 8x.
// A,B bf16. Nn multiple of 128, K multiple of 32. M tail clamped on load.
// ---------------------------------------------------------------------------
template<int GELU>
__global__ __launch_bounds__(256) void gemm_bt(const u16* __restrict__ A,
                                               const u16* __restrict__ B,
                                               const float* __restrict__ bias,
                                               u16* __restrict__ C,
                                               int M, int Nn, int K) {
    __shared__ u16 smem[128 * 128];  // 32 KB; K-loop uses first 16 KB
    u16* ldsA = smem;                // [128][32] row-major, 8 KB
    u16* ldsB = smem + 4096;         // 8 KB
    const int t = threadIdx.x;
    const int wave = t >> 6;
    const int lane = t & 63;
    const int quad = lane >> 4;
    const int l16  = lane & 15;
    const int wm = wave >> 1, wn = wave & 1;

    // ---- XCD-aware bijective swizzle (consecutive IDs round-robin XCDs) ----
    const int nwg  = gridDim.x * gridDim.y;
    const int orig = blockIdx.y * gridDim.x + blockIdx.x;
    const int xcd  = orig & 7;
    const int qq   = nwg >> 3, rr = nwg & 7;
    const int base_l = (xcd < rr) ? xcd * (qq + 1) : rr * (qq + 1) + (xcd - rr) * qq;
    const int logical = base_l + (orig >> 3);
    const int tx = logical % gridDim.x;
    const int ty = logical / gridDim.x;
    const long m0 = (long)ty * 128;
    const long n0 = (long)tx * 128;

    // staging geometry: round r (0/1), thread t covers tile row (r*256+t)/4,
    // cols (t&3)*8 .. +8  (16 bytes). LDS dest byte = r*4096 + t*16 (linear).
    const int scol = (t & 3) * 8;
    long asrc[2], bsrc[2];
#pragma unroll
    for (int r = 0; r < 2; r++) {
        long ra = m0 + (r * 256 + t) / 4;
        if (ra >= M) ra = M - 1;             // clamp loads; stores guarded
        asrc[r] = ra * (long)K + scol;
        long rb = n0 + (r * 256 + t) / 4;    // Nn multiple of 128: in range
        bsrc[r] = rb * (long)K + scol;
    }
    u16* adst0 = ldsA + t * 8;               // t*16 bytes
    u16* adst1 = ldsA + 2048 + t * 8;        // +4096 bytes
    u16* bdst0 = ldsB + t * 8;
    u16* bdst1 = ldsB + 2048 + t * 8;

    f4v acc[4][4] = {};
    for (int k0 = 0; k0 < K; k0 += 32) {
        ld16(A + asrc[0] + k0, adst0);
        ld16(A + asrc[1] + k0, adst1);
        ld16(B + bsrc[0] + k0, bdst0);
        ld16(B + bsrc[1] + k0, bdst1);
        __syncthreads();                     // drains vmcnt -> LDS tiles ready
        s8v a[4], b[4];
#pragma unroll
        for (int i = 0; i < 4; i++)
            a[i] = *(const s8v*)(ldsA + (wm * 64 + i * 16 + l16) * 32 + quad * 8);
#pragma unroll
        for (int j = 0; j < 4; j++)
            b[j] = *(const s8v*)(ldsB + (wn * 64 + j * 16 + l16) * 32 + quad * 8);
#pragma unroll
        for (int i = 0; i < 4; i++)
#pragma unroll
            for (int j = 0; j < 4; j++)      // swapped operands: transposed frag
                acc[i][j] = __builtin_amdgcn_mfma_f32_16x16x32_bf16(b[j], a[i], acc[i][j], 0, 0, 0);
        __syncthreads();                     // protect LDS before next stage
    }
    // swapped layout: m = wm*64+i*16+l16 (row), n = wn*64+j*16+quad*4+r (col)

    // ---- epilogue stage 1: bias/gelu, pack 4 cols -> b64 LDS write ----
    // chunk = col_local/4 = wn*16+j*4+quad ; swizzle chunk ^ (row_local & 14)
#pragma unroll
    for (int j = 0; j < 4; j++) {
        const long ncol = n0 + wn * 64 + j * 16 + quad * 4;
        f4v bb = {0.f, 0.f, 0.f, 0.f};
        if (bias) bb = *(const f4v*)(bias + ncol);
#pragma unroll
        for (int i = 0; i < 4; i++) {
            const int row_local = wm * 64 + i * 16 + l16;
            const int ch = (wn * 16 + j * 4 + quad) ^ (row_local & 14);
            s4v pk;
#pragma unroll
            for (int r = 0; r < 4; r++) {
                float v = acc[i][j][r] + bb[r];
                if (GELU) v = 0.5f * v * (1.f + erff(v * 0.70710678118654752f));
                pk[r] = (short)f2b(v);
            }
            *(s4v*)(smem + row_local * 128 + ch * 4) = pk;
        }
    }
    __syncthreads();

    // ---- epilogue stage 2: coalesced copy-out, 64B per 4-lane group ----
    // thread t: row = pass*64 + (t>>2), quarter q = t&3; 4 x 16B stores.
    const int q4 = t & 3;
#pragma unroll
    for (int pass = 0; pass < 2; pass++) {
        const int row = pass * 64 + (t >> 2);
        const long grow = m0 + row;
        if (grow < M) {
            const u16* lrow = smem + row * 128;
            const int s = row & 14;
#pragma unroll
            for (int k = 0; k < 4; k++) {
                const int c0 = (q4 * 2 + k * 8) ^ s;   // even -> 16B aligned
                s8v v = *(const s8v*)(lrow + c0 * 4);
                *(s8v*)(C + grow * (long)Nn + n0 + q4 * 8 + k * 32) = v;
            }
        }
    }
}

// ---------------------------------------------------------------------------
// input norm: base = LN(nf + nte[node_type]) * g + b   (one wave per row)
// ---------------------------------------------------------------------------
__global__ __launch_bounds__(256) void k_innorm(const void* __restrict__ nf,
                                                const void* __restrict__ ntype,
                                                const void* __restrict__ nte,
                                                const float* __restrict__ g,
                                                const float* __restrict__ b,
                                                u16* __restrict__ base, int N,
                                                const int* __restrict__ flags) {
    const int isbf = flags[0], i64 = flags[1];
    const int wave = threadIdx.x >> 6, lane = threadIdx.x & 63;
    const int row = blockIdx.x * 4 + wave;
    if (row >= N) return;
    const long off = (long)row * 512 + lane * 8;
    const int nt = geti(ntype, row, i64);
    const long eoff = (long)nt * 512 + lane * 8;
    float x[8];
    if (isbf) {
        s8v xv = *(const s8v*)((const u16*)nf + off);
        s8v ev = *(const s8v*)((const u16*)nte + eoff);
#pragma unroll
        for (int j = 0; j < 8; j++) x[j] = bv(xv, j) + bv(ev, j);
    } else {
        f4v x0 = *(const f4v*)((const float*)nf + off);
        f4v x1 = *(const f4v*)((const float*)nf + off + 4);
        f4v e0 = *(const f4v*)((const float*)nte + eoff);
        f4v e1 = *(const f4v*)((const float*)nte + eoff + 4);
#pragma unroll
        for (int j = 0; j < 4; j++) { x[j] = x0[j] + e0[j]; x[4 + j] = x1[j] + e1[j]; }
    }
    float s = 0.f, s2 = 0.f;
#pragma unroll
    for (int j = 0; j < 8; j++) { s += x[j]; s2 += x[j] * x[j]; }
#pragma unroll
    for (int o = 32; o >= 1; o >>= 1) { s += __shfl_xor(s, o); s2 += __shfl_xor(s2, o); }
    const float mu = s * (1.f / 512.f);
    const float rs = rsqrtf(s2 * (1.f / 512.f) - mu * mu + 1e-5f);
    f4v g0 = *(const f4v*)(g + lane * 8); f4v g1 = *(const f4v*)(g + lane * 8 + 4);
    f4v b0 = *(const f4v*)(b + lane * 8); f4v b1 = *(const f4v*)(b + lane * 8 + 4);
    s8v o;
#pragma unroll
    for (int j = 0; j < 8; j++) {
        const float gg = j < 4 ? g0[j] : g1[j - 4];
        const float bb = j < 4 ? b0[j] : b1[j - 4];
        o[j] = (short)f2b((x[j] - mu) * rs * gg + bb);
    }
    *(s8v*)(base + off) = o;
}

// ===========================================================================
// FAST PATH: CSR build + gather (no feature atomics)
// ===========================================================================
__global__ __launch_bounds__(256) void k_count(const void* __restrict__ EI,
                                               u32* __restrict__ cnt, int E,
                                               const int* __restrict__ flags) {
    const int i64 = flags[1];
    const int t = blockIdx.x * 256 + threadIdx.x;
    if (t >= 2 * E) return;
    const int ed = (t < E) ? t : t - E;
    const int dst = (t < E) ? geti(EI, E + ed, i64) : geti(EI, ed, i64);
    atomicAdd(&cnt[dst], 1u);
}

// single-workgroup exclusive scan (1024 threads, Hillis-Steele per chunk)
__global__ __launch_bounds__(1024) void k_scan(const u32* __restrict__ cnt,
                                               u32* __restrict__ indptr, int N) {
    __shared__ u32 buf[1024];
    __shared__ u32 carry;
    if (threadIdx.x == 0) carry = 0;
    __syncthreads();
    for (int b0 = 0; b0 < N; b0 += 1024) {
        const int i = b0 + threadIdx.x;
        const u32 v = (i < N) ? cnt[i] : 0u;
        buf[threadIdx.x] = v;
        __syncthreads();
        for (int o = 1; o < 1024; o <<= 1) {
            u32 t = (threadIdx.x >= (u32)o) ? buf[threadIdx.x - o] : 0u;
            __syncthreads();
            buf[threadIdx.x] += t;
            __syncthreads();
        }
        const u32 excl = carry + buf[threadIdx.x] - v;
        __syncthreads();
        if (threadIdx.x == 1023) carry += buf[1023];
        if (i < N) indptr[i] = excl;
        __syncthreads();
    }
    if (threadIdx.x == 0) indptr[N] = carry;
}

__global__ void k_copy32(const u32* __restrict__ src, u32* __restrict__ dst, int n) {
    int t = blockIdx.x * 256 + threadIdx.x;
    if (t < n) dst[t] = src[t];
}

__global__ __launch_bounds__(256) void k_fill(const void* __restrict__ EI,
                                              const void* __restrict__ ET,
                                              const float* __restrict__ EW,
                                              u32* __restrict__ cursor,
                                              u32* __restrict__ srcrel,
                                              float* __restrict__ wts, int E,
                                              const int* __restrict__ flags) {
    const int i64 = flags[1];
    const int t = blockIdx.x * 256 + threadIdx.x;
    if (t >= 2 * E) return;
    int ed, src, dst, r;
    if (t < E) { ed = t;     r = geti(ET, ed, i64);     src = geti(EI, ed, i64);     dst = geti(EI, E + ed, i64); }
    else       { ed = t - E; r = geti(ET, ed, i64) + 2; src = geti(EI, E + ed, i64); dst = geti(EI, ed, i64); }
    const u32 pos = atomicAdd(&cursor[dst], 1u);
    srcrel[pos] = (u32)src | ((u32)r << 28);
    wts[pos] = EW[ed];
}

// gather + n1 fused: x1 = LN(base + S + b_self + agg/max(deg,1)) * g + b
// agg[d] = sum_e w*(Y4[src, rel*512+c]) + sum_r wsum_r * brel[r][c]
__global__ __launch_bounds__(256) void k_gather_n1(const u32* __restrict__ indptr,
                                                   const u32* __restrict__ srcrel,
                                                   const float* __restrict__ wts,
                                                   const u16* __restrict__ Y4,   // [N,2048]
                                                   const u16* __restrict__ S,    // [N,512]
                                                   const u16* __restrict__ base,
                                                   const float* __restrict__ brel,  // [4,512]
                                                   const float* __restrict__ bself,
                                                   const float* __restrict__ g,
                                                   const float* __restrict__ b,
                                                   u16* __restrict__ x1, int N) {
    const int wave = threadIdx.x >> 6, lane = threadIdx.x & 63;
    const int row = blockIdx.x * 4 + wave;
    if (row >= N) return;
    const int colb = lane * 8;
    float acc[8] = {}; float wsum[4] = {};
    const u32 beg = indptr[row], end = indptr[row + 1];
    for (u32 i = beg; i < end; i++) {
        const u32 pr = srcrel[i];
        const int src = (int)(pr & 0x0FFFFFFFu);
        const int rel = (int)(pr >> 28);
        const float w = wts[i];
        s8v yv = *(const s8v*)(Y4 + (long)src * 2048 + rel * 512 + colb);
#pragma unroll
        for (int j = 0; j < 8; j++) acc[j] += w * bv(yv, j);
        wsum[rel] += w;
    }
    const float deg = wsum[0] + wsum[1] + wsum[2] + wsum[3];
    const float dmx = 1.f / fmaxf(deg, 1.f);
    const long off = (long)row * 512 + colb;
    s8v sv = *(const s8v*)(S + off);
    s8v bs = *(const s8v*)(base + off);
    f4v sb0 = *(const f4v*)(bself + colb);
    f4v sb1 = *(const f4v*)(bself + colb + 4);
    // bias contribution from each relation
    float x[8], s = 0.f, s2 = 0.f;
#pragma unroll
    for (int h = 0; h < 2; h++) {
        f4v br0 = *(const f4v*)(brel + 0 * 512 + colb + 4 * h);
        f4v br1 = *(const f4v*)(brel + 1 * 512 + colb + 4 * h);
        f4v br2 = *(const f4v*)(brel + 2 * 512 + colb + 4 * h);
        f4v br3 = *(const f4v*)(brel + 3 * 512 + colb + 4 * h);
#pragma unroll
        for (int q = 0; q < 4; q++) {
            const int j = h * 4 + q;
            const float bias4 = wsum[0] * br0[q] + wsum[1] * br1[q] + wsum[2] * br2[q] + wsum[3] * br3[q];
            const float sbv = h ? sb1[q] : sb0[q];
            x[j] = bv(bs, j) + bv(sv, j) + sbv + (acc[j] + bias4) * dmx;
            s += x[j]; s2 += x[j] * x[j];
        }
    }
#pragma unroll
    for (int o = 32; o >= 1; o >>= 1) { s += __shfl_xor(s, o); s2 += __shfl_xor(s2, o); }
    const float mu = s * (1.f / 512.f);
    const float rs = rsqrtf(s2 * (1.f / 512.f) - mu * mu + 1e-5f);
    f4v g0 = *(const f4v*)(g + colb); f4v g1 = *(const f4v*)(g + colb + 4);
    f4v b0 = *(const f4v*)(b + colb); f4v b1 = *(const f4v*)(b + colb + 4);
    s8v o;
#pragma unroll
    for (int j = 0; j < 8; j++) {
        const float gg = j < 4 ? g0[j] : g1[j - 4];
        const float bb = j < 4 ? b0[j] : b1[j - 4];
        o[j] = (short)f2b((x[j] - mu) * rs * gg + bb);
    }
    *(s8v*)(x1 + off) = o;
}

// ===========================================================================
// SLOW PATH kernels (proven r3 fallback): scatter with f32 atomics
// ===========================================================================
__global__ __launch_bounds__(256) void k_deg(const void* __restrict__ EI,
                                             const float* __restrict__ EW,
                                             float* __restrict__ deg, int E,
                                             const int* __restrict__ flags) {
    const int i64 = flags[1];
    const int t = blockIdx.x * 256 + threadIdx.x;
    if (t >= 2 * E) return;
    const int ed = (t < E) ? t : t - E;
    const int dst = (t < E) ? geti(EI, E + ed, i64) : geti(EI, ed, i64);
    atomicAdd(&deg[dst], EW[ed]);
}

__global__ __launch_bounds__(256) void k_scatter(const void* __restrict__ EI,
                                                 const void* __restrict__ ET,
                                                 const float* __restrict__ EW,
                                                 const u16* __restrict__ Y,
                                                 const float* __restrict__ brel,
                                                 float* __restrict__ agg, int E, int rel,
                                                 const int* __restrict__ flags) {
    const int i64 = flags[1];
    const int wave = threadIdx.x >> 6, lane = threadIdx.x & 63;
    const long eid = (long)blockIdx.x * 4 + wave;
    if (eid >= 2 * (long)E) return;
    int ed, src, dst, r;
    if (eid < E) { ed = (int)eid;       r = geti(ET, ed, i64);     src = geti(EI, ed, i64);     dst = geti(EI, E + ed, i64); }
    else         { ed = (int)(eid - E); r = geti(ET, ed, i64) + 2; src = geti(EI, E + ed, i64); dst = geti(EI, ed, i64); }
    if (r != rel) return;
    const float w = EW[ed];
    s8v yv = *(const s8v*)(Y + (long)src * 512 + lane * 8);
    const float* bb = brel + (long)rel * 512 + lane * 8;
    float* ag = agg + (long)dst * 512 + lane * 8;
#pragma unroll
    for (int j = 0; j < 8; j++) atomicAdd(ag + j, w * (bv(yv, j) + bb[j]));
}

__global__ __launch_bounds__(256) void k_n1(const u16* __restrict__ S,
                                            const float* __restrict__ agg,
                                            const float* __restrict__ deg,
                                            const float* __restrict__ bself,
                                            const u16* __restrict__ base,
                                            const float* __restrict__ g,
                                            const float* __restrict__ b,
                                            u16* __restrict__ x1, int N) {
    const int wave = threadIdx.x >> 6, lane = threadIdx.x & 63;
    const int row = blockIdx.x * 4 + wave;
    if (row >= N) return;
    const long off = (long)row * 512 + lane * 8;
    s8v sv = *(const s8v*)(S + off);
    s8v bs = *(const s8v*)(base + off);
    f4v a0 = *(const f4v*)(agg + off);
    f4v a1 = *(const f4v*)(agg + off + 4);
    f4v sb0 = *(const f4v*)(bself + lane * 8);
    f4v sb1 = *(const f4v*)(bself + lane * 8 + 4);
    const float dmx = 1.f / fmaxf(deg[row], 1.f);
    float x[8], s = 0.f, s2 = 0.f;
#pragma unroll
    for (int j = 0; j < 8; j++) {
        const float av = (j < 4 ? a0[j] : a1[j - 4]);
        const float sbv = (j < 4 ? sb0[j] : sb1[j - 4]);
        x[j] = bv(bs, j) + bv(sv, j) + sbv + av * dmx;
        s += x[j]; s2 += x[j] * x[j];
    }
#pragma unroll
    for (int o = 32; o >= 1; o >>= 1) { s += __shfl_xor(s, o); s2 += __shfl_xor(s2, o); }
    const float mu = s * (1.f / 512.f);
    const float rs = rsqrtf(s2 * (1.f / 512.f) - mu * mu + 1e-5f);
    f4v g0 = *(const f4v*)(g + lane * 8); f4v g1 = *(const f4v*)(g + lane * 8 + 4);
    f4v b0 = *(const f4v*)(b + lane * 8); f4v b1 = *(const f4v*)(b + lane * 8 + 4);
    s8v o;
#pragma unroll
    for (int j = 0; j < 8; j++) {
        const float gg = j < 4 ? g0[j] : g1[j - 4];
        const float bb = j < 4 ? b0[j] : b1[j - 4];
        o[j] = (short)f2b((x[j] - mu) * rs * gg + bb);
    }
    *(s8v*)(x1 + off) = o;
}

// ---------------------------------------------------------------------------
// final: two LNs + graph-mix; writes final x bf16 IN PLACE over fio.
// (pure streaming; column sum done by k_colsum afterwards — no atomics here)
// ---------------------------------------------------------------------------
__global__ __launch_bounds__(256) void k_final(const u16* __restrict__ x1,
                                               u16* fio,
                                               const u16* __restrict__ base,
                                               const float* __restrict__ n2g,
                                               const float* __restrict__ n2b,
                                               const float* __restrict__ og,
                                               const float* __restrict__ ob,
                                               const float* __restrict__ gml,
                                               int N) {
    const int wave = threadIdx.x >> 6, lane = threadIdx.x & 63;
    const int row = blockIdx.x * 4 + wave;
    if (row >= N) return;
    const long off = (long)row * 512 + lane * 8;
    s8v xv = *(const s8v*)(x1 + off);
    s8v fv = *(const s8v*)(fio + off);
    float x[8], s = 0.f, s2 = 0.f;
#pragma unroll
    for (int j = 0; j < 8; j++) { x[j] = bv(xv, j) + bv(fv, j); s += x[j]; s2 += x[j] * x[j]; }
#pragma unroll
    for (int o = 32; o >= 1; o >>= 1) { s += __shfl_xor(s, o); s2 += __shfl_xor(s2, o); }
    float mu = s * (1.f / 512.f);
    float rs = rsqrtf(s2 * (1.f / 512.f) - mu * mu + 1e-5f);
    f4v g10 = *(const f4v*)(n2g + lane * 8); f4v g11 = *(const f4v*)(n2g + lane * 8 + 4);
    f4v b10 = *(const f4v*)(n2b + lane * 8); f4v b11 = *(const f4v*)(n2b + lane * 8 + 4);
    float t[8]; s = 0.f; s2 = 0.f;
#pragma unroll
    for (int j = 0; j < 8; j++) {
        const float gg = j < 4 ? g10[j] : g11[j - 4];
        const float bb = j < 4 ? b10[j] : b11[j - 4];
        t[j] = (x[j] - mu) * rs * gg + bb;
        s += t[j]; s2 += t[j] * t[j];
    }
#pragma unroll
    for (int o = 32; o >= 1; o >>= 1) { s += __shfl_xor(s, o); s2 += __shfl_xor(s2, o); }
    mu = s * (1.f / 512.f);
    rs = rsqrtf(s2 * (1.f / 512.f) - mu * mu + 1e-5f);
    f4v g20 = *(const f4v*)(og + lane * 8); f4v g21 = *(const f4v*)(og + lane * 8 + 4);
    f4v b20 = *(const f4v*)(ob + lane * 8); f4v b21 = *(const f4v*)(ob + lane * 8 + 4);
    s8v bs = *(const s8v*)(base + off);
    const float gm = 1.f / (1.f + expf(-gml[0]));
    s8v o;
#pragma unroll
    for (int j = 0; j < 8; j++) {
        const float gg = j < 4 ? g20[j] : g21[j - 4];
        const float bb = j < 4 ? b20[j] : b21[j - 4];
        const float u = (t[j] - mu) * rs * gg + bb;
        const float bsv = bv(bs, j);
        o[j] = (short)f2b(bsv + gm * (u - bsv));
    }
    *(s8v*)(fio + off) = o;
}

// ---------------------------------------------------------------------------
// column sum of final bf16 x: deterministic two-stage, zero atomics.
// stage 1: 512 blocks; block b accumulates rows b, b+512, ... (2 cols/thread)
// ---------------------------------------------------------------------------
__global__ __launch_bounds__(256) void k_colsum(const u16* __restrict__ x,
                                                float* __restrict__ partial, int N) {
    const int b = blockIdx.x, t = threadIdx.x;
    float s0 = 0.f, s1 = 0.f;
    for (int r = b; r < N; r += gridDim.x) {
        const u32 v = *(const u32*)(x + (long)r * 512 + 2 * t);
        s0 += b2f((u16)(v & 0xFFFFu));
        s1 += b2f((u16)(v >> 16));
    }
    partial[(long)b * 512 + 2 * t]     = s0;
    partial[(long)b * 512 + 2 * t + 1] = s1;
}

__global__ void k_emit(const u16* __restrict__ xout, void* __restrict__ dout, long n,
                       const int* __restrict__ flags) {
    const int isbf = flags[0];
    const long t = ((long)blockIdx.x * 256 + threadIdx.x) * 8;
    if (t >= n) return;
    s8v v = *(const s8v*)(xout + t);
    if (isbf) {
        *(s8v*)((u16*)dout + t) = v;
    } else {
        f4v o0, o1;
#pragma unroll
        for (int j = 0; j < 4; j++) { o0[j] = bv(v, j); o1[j] = bv(v, 4 + j); }
        *(f4v*)((float*)dout + t) = o0;
        *(f4v*)((float*)dout + t + 4) = o1;
    }
}

// stage 2 + pooled: PARALLEL reduce of 512 partial rows (one block per column)
// + doc-mix with x[0]. Replaces the single-block latency-serialized loop
// (was 184 us at 0.09% occupancy; 512 iterations x ~900cy HBM latency).
__global__ __launch_bounds__(256) void k_pooled(const u16* __restrict__ xout,
                                                const float* __restrict__ partial,
                                                const float* __restrict__ dml,
                                                void* __restrict__ dout,
                                                long pool_off, int N,
                                                const int* __restrict__ flags) {
    __shared__ float ws[4];
    const int c = blockIdx.x;     // 512 columns
    const int t = threadIdx.x;    // 256 threads: 2 partials each
    float s = partial[(long)t * 512 + c] + partial[(long)(t + 256) * 512 + c];
#pragma unroll
    for (int o = 32; o >= 1; o >>= 1) s += __shfl_xor(s, o);
    if ((t & 63) == 0) ws[t >> 6] = s;
    __syncthreads();
    if (t == 0) {
        const float cs = ws[0] + ws[1] + ws[2] + ws[3];
        const float dm = 1.f / (1.f + expf(-dml[0]));
        const float v = dm * b2f(xout[c]) + (1.f - dm) * (cs / (float)N);
        if (flags[0]) ((u16*)dout)[pool_off + c] = f2b(v);
        else          ((float*)dout)[pool_off + c] = v;
    }
}

// ---------------------------------------------------------------------------
extern "C" void kernel_launch(void* const* d_in, const int* in_sizes, int n_in,
                              void* d_out, int out_size, void* d_ws, size_t ws_size,
                              hipStream_t stream) {
    const void* nf    = d_in[0];
    const void* EI    = d_in[1];
    const void* ET    = d_in[2];
    const void* NT    = d_in[3];
    const void* EW    = d_in[4];
    const void* NTE   = d_in[5];
    const void* Wself = d_in[6];
    const void* bself = d_in[7];
    const void* Wrel  = d_in[8];
    const void* brel  = d_in[9];
    const void* ing   = d_in[10];
    const void* inb   = d_in[11];
    const void* n1g   = d_in[12];
    const void* n1b   = d_in[13];
    const void* Wf1   = d_in[14];
    const void* bf1   = d_in[15];
    const void* Wf2   = d_in[16];
    const void* bf2   = d_in[17];
    const void* n2g   = d_in[18];
    const void* n2b   = d_in[19];
    const void* outg  = d_in[20];
    const void* outb  = d_in[21];
    const void* gml   = d_in[22];
    const void* dml   = d_in[23];

    const int N = in_sizes[0] / 512;     // 50000
    const int E = in_sizes[2];           // 100000

    const size_t ND2 = (size_t)N * 512 * 2;
    const size_t ND4 = (size_t)N * 512 * 4;
    const size_t arena_elems = (size_t)E + 2048 + 512 * 10 + 1024 + 2;
    const size_t arena_bytes = arena_elems * 4;
    // bf16 weight buffers: Wrel(4*512*512) + Wself(512*512) + Wf1(1024*512) + Wf2(512*1024)
    const size_t WRELN = 4ull * 512 * 512, WSELFN = 512ull * 512;
    const size_t WF1N = 1024ull * 512, WF2N = 512ull * 1024;
    const size_t WBFB = (WRELN + WSELFN + WF1N + WF2N) * 2;   // bytes
    const int NPART = 512;
    const size_t partB = (size_t)NPART * 512 * 4;             // 1 MB partial colsums

    // fast path: base + Y4[N,2048]bf16 + S + CSR + misc + bf16 weights
    const size_t Y4B = (size_t)N * 2048 * 2;
    const size_t csrB = (size_t)(N + 1) * 4 + (size_t)N * 4 + (size_t)(2 * E) * 4 * 2;
    const size_t need_fast = ND2 + Y4B + ND2 + csrB + partB + 64 + WBFB + arena_bytes;
    // slow path (r3-proven): base + agg f32 + Ybuf + deg/partial/flags + weights + arena
    const size_t need_slow = ND2 + ND4 + ND2 + (size_t)N * 4 + partB + 64 + WBFB + arena_bytes;

    const int rowBlocks = (N + 3) / 4;
    const dim3 g512(512 / 128, (N + 127) / 128);
    const dim3 g1024(1024 / 128, (N + 127) / 128);
    const dim3 g2048(2048 / 128, (N + 127) / 128);

    if (ws_size >= need_fast) {
        // ------------------- FAST PATH: CSR gather -------------------
        char* p = (char*)d_ws;
        u16*   base   = (u16*)p;                         // ND2
        u16*   Y4     = (u16*)(p + ND2);                 // Y4B; later aliased by mid
        u16*   mid    = Y4;                              // FFN hidden [N,1024] bf16
        u16*   Sbuf   = (u16*)(p + ND2 + Y4B);           // ND2: S, later ffn_out/final x
        char*  q      = p + ND2 + Y4B + ND2;
        u32*   indptr = (u32*)q;                 q += (size_t)(N + 1) * 4;
        u32*   cursor = (u32*)q;                 q += (size_t)N * 4;   // also cnt
        u32*   srcrel = (u32*)q;                 q += (size_t)(2 * E) * 4;
        float* wts    = (float*)q;               q += (size_t)(2 * E) * 4;
        float* partial= (float*)q;               q += partB;
        int*   flags  = (int*)q;                 q += 64;
        u16*   wrelc  = (u16*)q;                 q += WRELN * 2;
        u16*   wselfc = (u16*)q;                 q += WSELFN * 2;
        u16*   wf1c   = (u16*)q;                 q += WF1N * 2;
        u16*   wf2c   = (u16*)q;                 q += WF2N * 2;
        float* arena  = (float*)q;
        float* EWc   = arena;
        float* brelc = EWc + E;
        float* bselfc= brelc + 2048;
        float* ingc  = bselfc + 512;
        float* inbc  = ingc + 512;
        float* n1gc  = inbc + 512;
        float* n1bc  = n1gc + 512;
        float* bf1c  = n1bc + 512;
        float* bf2c  = bf1c + 1024;
        float* n2gc  = bf2c + 512;
        float* n2bc  = n2gc + 512;
        float* outgc = n2bc + 512;
        float* outbc = outgc + 512;
        float* gmlc  = outbc + 512;
        float* dmlc  = gmlc + 1;
        u16* x1 = (u16*)d_out;          // bf16 intermediate; overwritten by k_emit

        k_detect<<<1, 256, 0, stream>>>((const u16*)nf, (const u32*)EI, flags);
        hipMemsetAsync(cursor, 0, (size_t)N * 4, stream);   // cnt

        auto cvt = [&](const void* s, float* d, int n) {
            k_cvt<<<(n + 255) / 256, 256, 0, stream>>>(s, d, n, flags);
        };
        auto cvt16 = [&](const void* s, u16* d, int n) {
            k_cvt16<<<(n + 255) / 256, 256, 0, stream>>>(s, d, n, flags);
        };
        cvt(EW, EWc, E);        cvt(brel, brelc, 2048);  cvt(bself, bselfc, 512);
        cvt(ing, ingc, 512);    cvt(inb, inbc, 512);     cvt(n1g, n1gc, 512);
        cvt(n1b, n1bc, 512);    cvt(bf1, bf1c, 1024);    cvt(bf2, bf2c, 512);
        cvt(n2g, n2gc, 512);    cvt(n2b, n2bc, 512);     cvt(outg, outgc, 512);
        cvt(outb, outbc, 512);  cvt(gml, gmlc, 1);       cvt(dml, dmlc, 1);
        cvt16(Wrel, wrelc, (int)WRELN);   cvt16(Wself, wselfc, (int)WSELFN);
        cvt16(Wf1, wf1c, (int)WF1N);      cvt16(Wf2, wf2c, (int)WF2N);

        k_innorm<<<rowBlocks, 256, 0, stream>>>(nf, NT, NTE, ingc, inbc, base, N, flags);
        // CSR build
        k_count<<<(2 * E + 255) / 256, 256, 0, stream>>>(EI, cursor, E, flags);
        k_scan<<<1, 1024, 0, stream>>>(cursor, indptr, N);
        k_copy32<<<(N + 255) / 256, 256, 0, stream>>>(indptr, cursor, N);
        k_fill<<<(2 * E + 255) / 256, 256, 0, stream>>>(EI, ET, EWc, cursor, srcrel, wts, E, flags);
        // transforms: Y4 = base @ Wrel_cat^T   ;   S = base @ Wself^T
        gemm_bt<0><<<g2048, 256, 0, stream>>>(base, wrelc, nullptr, Y4, N, 2048, 512);
        gemm_bt<0><<<g512, 256, 0, stream>>>(base, wselfc, nullptr, Sbuf, N, 512, 512);
        // fused gather + n1
        k_gather_n1<<<rowBlocks, 256, 0, stream>>>(indptr, srcrel, wts, Y4, Sbuf, base,
                                                   brelc, bselfc, n1gc, n1bc, x1, N);
        // FFN (mid aliases Y4, which is dead now; ffn_out into Sbuf, dead too)
        gemm_bt<1><<<g1024, 256, 0, stream>>>(x1, wf1c, bf1c, mid, N, 1024, 512);
        gemm_bt<0><<<g512, 256, 0, stream>>>(mid, wf2c, bf2c, Sbuf, N, 512, 1024);

        k_final<<<rowBlocks, 256, 0, stream>>>(x1, Sbuf, base, n2gc, n2bc, outgc, outbc,
                                               gmlc, N);
        k_colsum<<<NPART, 256, 0, stream>>>(Sbuf, partial, N);
        k_emit<<<(int)(((long)N * 512 / 8 + 255) / 256), 256, 0, stream>>>(Sbuf, d_out,
                                                                           (long)N * 512, flags);
        k_pooled<<<512, 256, 0, stream>>>(Sbuf, partial, dmlc, d_out, (long)N * 512, N, flags);

    } else if (ws_size >= need_slow) {
        // ------------------- SLOW PATH (r3-proven) -------------------
        char* p = (char*)d_ws;
        u16*   base = (u16*)p;
        float* agg  = (float*)(p + ND2);
        u16*   mid  = (u16*)(p + ND2);
        u16*   Ybuf = (u16*)(p + ND2 + ND4);
        float* deg  = (float*)(p + ND2 + ND4 + ND2);
        float* partial = deg + N;
        int*   flags  = (int*)(partial + NPART * 512);
        char*  q2     = (char*)flags + 64;
        u16*   wrelc  = (u16*)q2;                q2 += WRELN * 2;
        u16*   wselfc = (u16*)q2;                q2 += WSELFN * 2;
        u16*   wf1c   = (u16*)q2;                q2 += WF1N * 2;
        u16*   wf2c   = (u16*)q2;                q2 += WF2N * 2;
        float* arena  = (float*)q2;
        float* EWc   = arena;
        float* brelc = EWc + E;
        float* bselfc= brelc + 2048;
        float* ingc  = bselfc + 512;
        float* inbc  = ingc + 512;
        float* n1gc  = inbc + 512;
        float* n1bc  = n1gc + 512;
        float* bf1c  = n1bc + 512;
        float* bf2c  = bf1c + 1024;
        float* n2gc  = bf2c + 512;
        float* n2bc  = n2gc + 512;
        float* outgc = n2bc + 512;
        float* outbc = outgc + 512;
        float* gmlc  = outbc + 512;
        float* dmlc  = gmlc + 1;
        u16* x1 = (u16*)d_out;

        k_detect<<<1, 256, 0, stream>>>((const u16*)nf, (const u32*)EI, flags);
        hipMemsetAsync(agg, 0, ND4, stream);
        hipMemsetAsync(deg, 0, (size_t)N * 4, stream);

        auto cvt = [&](const void* s, float* d, int n) {
            k_cvt<<<(n + 255) / 256, 256, 0, stream>>>(s, d, n, flags);
        };
        auto cvt16 = [&](const void* s, u16* d, int n) {
            k_cvt16<<<(n + 255) / 256, 256, 0, stream>>>(s, d, n, flags);
        };
        cvt(EW, EWc, E);        cvt(brel, brelc, 2048);  cvt(bself, bselfc, 512);
        cvt(ing, ingc, 512);    cvt(inb, inbc, 512);     cvt(n1g, n1gc, 512);
        cvt(n1b, n1bc, 512);    cvt(bf1, bf1c, 1024);    cvt(bf2, bf2c, 512);
        cvt(n2g, n2gc, 512);    cvt(n2b, n2bc, 512);     cvt(outg, outgc, 512);
        cvt(outb, outbc, 512);  cvt(gml, gmlc, 1);       cvt(dml, dmlc, 1);
        cvt16(Wrel, wrelc, (int)WRELN);   cvt16(Wself, wselfc, (int)WSELFN);
        cvt16(Wf1, wf1c, (int)WF1N);      cvt16(Wf2, wf2c, (int)WF2N);

        k_innorm<<<rowBlocks, 256, 0, stream>>>(nf, NT, NTE, ingc, inbc, base, N, flags);
        k_deg<<<(2 * E + 255) / 256, 256, 0, stream>>>(EI, EWc, deg, E, flags);

        for (int r = 0; r < 4; r++) {
            gemm_bt<0><<<g512, 256, 0, stream>>>(base, wrelc + (size_t)r * 512 * 512, nullptr,
                                                 Ybuf, N, 512, 512);
            k_scatter<<<(2 * E + 3) / 4, 256, 0, stream>>>(EI, ET, EWc, Ybuf, brelc, agg,
                                                           E, r, flags);
        }

        gemm_bt<0><<<g512, 256, 0, stream>>>(base, wselfc, nullptr, Ybuf, N, 512, 512);
        k_n1<<<rowBlocks, 256, 0, stream>>>(Ybuf, agg, deg, bselfc, base, n1gc, n1bc, x1, N);

        gemm_bt<1><<<g1024, 256, 0, stream>>>(x1, wf1c, bf1c, mid, N, 1024, 512);
        gemm_bt<0><<<g512, 256, 0, stream>>>(mid, wf2c, bf2c, Ybuf, N, 512, 1024);

        k_final<<<rowBlocks, 256, 0, stream>>>(x1, Ybuf, base, n2gc, n2bc, outgc, outbc,
                                               gmlc, N);
        k_colsum<<<NPART, 256, 0, stream>>>(Ybuf, partial, N);
        k_emit<<<(int)(((long)N * 512 / 8 + 255) / 256), 256, 0, stream>>>(Ybuf, d_out,
                                                                           (long)N * 512, flags);
        k_pooled<<<512, 256, 0, stream>>>(Ybuf, partial, dmlc, d_out, (long)N * 512, N, flags);
    } else {
        const float val = 2000.f + (float)(ws_size >> 20);
        k_diag<<<(out_size + 255) / 256, 256, 0, stream>>>((u16*)d_out, out_size, val);
    }
}

// Round 7
// 957.244 us; speedup vs baseline: 1.2150x; 1.0309x over previous
//
#include <hip/hip_runtime.h>
#include <hip/hip_bf16.h>

typedef __attribute__((ext_vector_type(8))) short s8v;   // 8 x bf16 (as i16 bits)
typedef __attribute__((ext_vector_type(4))) short s4v;   // 4 x bf16 (8B)
typedef __attribute__((ext_vector_type(4))) float f4v;
typedef unsigned short u16;
typedef unsigned int u32;

__device__ __forceinline__ float b2f(u16 u) {
    union { unsigned int i; float f; } v; v.i = ((unsigned int)u) << 16; return v.f;
}
__device__ __forceinline__ u16 f2b(float f) {
    union { float f; unsigned int i; } v; v.f = f;
    unsigned int r = v.i + 0x7FFFu + ((v.i >> 16) & 1u);  // round-nearest-even
    return (u16)(r >> 16);
}
__device__ __forceinline__ float bv(const s8v& s, int j) { return b2f((u16)s[j]); }
// integer load valid for int32 or int64 (low word) storage
__device__ __forceinline__ int geti(const void* p, long i, int i64) {
    return i64 ? (int)((const u32*)p)[2 * i] : ((const int*)p)[i];
}

// async global -> LDS, 16 bytes per lane (linear LDS dest: uniform base + lane*16)
__device__ __forceinline__ void ld16(const u16* g, u16* l) {
    __builtin_amdgcn_global_load_lds(
        (const __attribute__((address_space(1))) unsigned int*)g,
        (__attribute__((address_space(3))) unsigned int*)l, 16, 0, 0);
}

// ---------------------------------------------------------------------------
// dtype detector: flags[0]=1 floats are bf16 (else f32); flags[1]=1 ints int64.
// ---------------------------------------------------------------------------
__global__ void k_detect(const u16* __restrict__ nf, const u32* __restrict__ EI,
                         int* __restrict__ flags) {
    __shared__ int cnt, nz;
    if (threadIdx.x == 0) { cnt = 0; nz = 0; }
    __syncthreads();
    int c = 0;
    for (int i = threadIdx.x; i < 4096; i += 256) {
        u16 v = nf[2 * i];
        int e = (v >> 7) & 0xFF;
        if (e >= 64 && e < 160) c++;
    }
    atomicAdd(&cnt, c);
    int z = 0;
    for (int i = threadIdx.x; i < 4096; i += 256)
        if (EI[2 * i + 1] != 0) z++;
    atomicAdd(&nz, z);
    __syncthreads();
    if (threadIdx.x == 0) { flags[0] = (cnt >= 2867) ? 1 : 0; flags[1] = (nz == 0) ? 1 : 0; }
}

__global__ void k_cvt(const void* __restrict__ src, float* __restrict__ dst, int n,
                      const int* __restrict__ flags) {
    const int isbf = flags[0];
    int t = blockIdx.x * 256 + threadIdx.x;
    if (t < n) dst[t] = isbf ? b2f(((const u16*)src)[t]) : ((const float*)src)[t];
}

// convert weights to bf16 (copy if already bf16)
__global__ void k_cvt16(const void* __restrict__ src, u16* __restrict__ dst, int n,
                        const int* __restrict__ flags) {
    const int isbf = flags[0];
    int t = blockIdx.x * 256 + threadIdx.x;
    if (t < n) dst[t] = isbf ? ((const u16*)src)[t] : f2b(((const float*)src)[t]);
}

__global__ void k_diag(u16* __restrict__ out, int n, float val) {
    int t = blockIdx.x * 256 + threadIdx.x;
    if (t < n) out[t] = f2b(val);
}

// ---------------------------------------------------------------------------
// GEMM: C[M,Nn] = A[M,K] @ B[Nn,K]^T (+bias f32, optional exact gelu)
// 256x256 tile, BK=64, 8 waves (2Mx4N), 128 KiB double-buffered LDS.
// Counted vmcnt(8) (never 0 in main loop): next tile's 8 global_load_lds fly
// across both barriers and are only awaited one iteration later (T3+T4).
// LDS slot-XOR swizzle (slot ^= row&7 on 16B slots), applied BOTH-sides:
// linear gload_lds dest + inverse-swizzled global source + swizzled ds_read
// (rule #21) -> 2-way (free) instead of 16-way conflicts. setprio on MFMA (T5).
// Epilogue: swapped-operand MFMA -> LDS C-stage (128KB reuse) -> 64B stores.
// XCD-aware bijective block swizzle (T1). A,B bf16.
// Nn multiple of 256, K multiple of 64. M tail clamped on load, guarded store.
// ---------------------------------------------------------------------------
template<int GELU>
__global__ __launch_bounds__(512) void gemm_bt(const u16* __restrict__ A,
                                               const u16* __restrict__ B,
                                               const float* __restrict__ bias,
                                               u16* __restrict__ C,
                                               int M, int Nn, int K) {
    __shared__ u16 lds[2][2][256 * 64];   // [buf][A=0/B=1][256 rows][64 cols] = 128 KiB
    const int t = threadIdx.x;            // 0..511
    const int lane = t & 63;
    const int quad = lane >> 4;
    const int l16  = lane & 15;
    const int wid  = t >> 6;
    const int wm = wid >> 2, wn = wid & 3;   // 2 x 4 wave grid

    // ---- XCD-aware bijective swizzle ----
    const int nwg  = gridDim.x * gridDim.y;
    const int orig = blockIdx.y * gridDim.x + blockIdx.x;
    const int xcd  = orig & 7;
    const int qq   = nwg >> 3, rr = nwg & 7;
    const int base_l = (xcd < rr) ? xcd * (qq + 1) : rr * (qq + 1) + (xcd - rr) * qq;
    const int logical = base_l + (orig >> 3);
    const long m0 = (long)(logical / gridDim.x) * 256;
    const long n0 = (long)(logical % gridDim.x) * 256;

    // ---- staging geometry: per K-tile 8 issues (4 A + 4 B), 512 thr x 16B ----
    // issue q: linear LDS byte = q*8192 + t*16 -> row = q*64 + t/8, phys slot sp = t&7.
    // logical slot sl = sp ^ (row&7) = sp ^ (srow&7): fetch global slot sl so the
    // swizzled reader finds logical data at phys slot L ^ (row&7).
    const int srow = t >> 3;
    const int sl   = (t & 7) ^ (srow & 7);
    long aoff[4], boff[4];
#pragma unroll
    for (int q = 0; q < 4; q++) {
        long ra = m0 + q * 64 + srow; if (ra >= M) ra = M - 1;  // clamp; stores guarded
        aoff[q] = ra * (long)K + sl * 8;
        long rb = n0 + q * 64 + srow;                            // Nn multiple of 256
        boff[q] = rb * (long)K + sl * 8;
    }

    f4v acc[8][4] = {};
    const int NT = K >> 6;

    // prologue: stage tile 0 into buf 0
    {
        u16* la = &lds[0][0][0] + t * 8;
        u16* lb = &lds[0][1][0] + t * 8;
#pragma unroll
        for (int q = 0; q < 4; q++) ld16(A + aoff[q], la + q * 4096);
#pragma unroll
        for (int q = 0; q < 4; q++) ld16(B + boff[q], lb + q * 4096);
    }

    for (int kt = 0; kt < NT; kt++) {
        const int cur = kt & 1;
        if (kt + 1 < NT) {
            const long kc = (long)(kt + 1) * 64;
            u16* la = &lds[cur ^ 1][0][0] + t * 8;
            u16* lb = &lds[cur ^ 1][1][0] + t * 8;
#pragma unroll
            for (int q = 0; q < 4; q++) ld16(A + aoff[q] + kc, la + q * 4096);
#pragma unroll
            for (int q = 0; q < 4; q++) ld16(B + boff[q] + kc, lb + q * 4096);
            __builtin_amdgcn_sched_barrier(0);
            asm volatile("s_waitcnt vmcnt(8)");   // newest 8 (next tile) keep flying
        } else {
            __builtin_amdgcn_sched_barrier(0);
            asm volatile("s_waitcnt vmcnt(0)");   // tail: drain
        }
        __builtin_amdgcn_sched_barrier(0);
        __builtin_amdgcn_s_barrier();             // cur tile staged by ALL waves
        __builtin_amdgcn_sched_barrier(0);

        const u16* LA = &lds[cur][0][0];
        const u16* LB = &lds[cur][1][0];
        s8v bf[4][2];
#pragma unroll
        for (int j = 0; j < 4; j++) {
            const int row = wn * 64 + j * 16 + l16;
#pragma unroll
            for (int ks = 0; ks < 2; ks++)
                bf[j][ks] = *(const s8v*)(LB + row * 64 + ((ks * 4 + quad) ^ (row & 7)) * 8);
        }
        __builtin_amdgcn_s_setprio(1);
#pragma unroll
        for (int i = 0; i < 8; i++) {
            const int row = wm * 128 + i * 16 + l16;
            s8v af0 = *(const s8v*)(LA + row * 64 + ((quad) ^ (row & 7)) * 8);
            s8v af1 = *(const s8v*)(LA + row * 64 + ((4 + quad) ^ (row & 7)) * 8);
#pragma unroll
            for (int j = 0; j < 4; j++) {
                acc[i][j] = __builtin_amdgcn_mfma_f32_16x16x32_bf16(bf[j][0], af0, acc[i][j], 0, 0, 0);
                acc[i][j] = __builtin_amdgcn_mfma_f32_16x16x32_bf16(bf[j][1], af1, acc[i][j], 0, 0, 0);
            }
        }
        __builtin_amdgcn_s_setprio(0);
        asm volatile("s_waitcnt lgkmcnt(0)");     // all LDS reads of cur complete
        __builtin_amdgcn_sched_barrier(0);
        __builtin_amdgcn_s_barrier();             // before next iter overwrites cur^1... (WAR)
        __builtin_amdgcn_sched_barrier(0);
    }
    // swapped layout: m = wm*128+i*16+l16 (row), n = wn*64+j*16+quad*4+r (col)

    // ---- epilogue stage 1: bias/gelu, pack 4 cols -> b64 LDS write (swizzled) ----
    u16* cs = &lds[0][0][0];                      // reuse as [256][256] bf16 = 128 KiB
#pragma unroll
    for (int j = 0; j < 4; j++) {
        const long ncol = n0 + wn * 64 + j * 16 + quad * 4;
        f4v bb = {0.f, 0.f, 0.f, 0.f};
        if (bias) bb = *(const f4v*)(bias + ncol);
        const int chunk = wn * 16 + j * 4 + quad;   // 8B units within row
#pragma unroll
        for (int i = 0; i < 8; i++) {
            const int row = wm * 128 + i * 16 + l16;
            const int cswz = chunk ^ ((row & 7) << 1);   // even XOR: keeps pairs intact
            s4v pk;
#pragma unroll
            for (int r = 0; r < 4; r++) {
                float v = acc[i][j][r] + bb[r];
                if (GELU) v = 0.5f * v * (1.f + erff(v * 0.70710678118654752f));
                pk[r] = (short)f2b(v);
            }
            *(s4v*)(cs + row * 256 + cswz * 4) = pk;
        }
    }
    __syncthreads();

    // ---- epilogue stage 2: coalesced copy-out, 64B per 4-lane group ----
    const int ql = t & 3;
#pragma unroll
    for (int pass = 0; pass < 2; pass++) {
        const int row = pass * 128 + (t >> 2);
        const long grow = m0 + row;
        if (grow < M) {
            const u16* crow = cs + row * 256;
            const int sw = (row & 7) << 1;
#pragma unroll
            for (int k = 0; k < 8; k++) {
                const int cp = ql * 2 + k * 8;           // even 8B-chunk pair start
                s8v v = *(const s8v*)(crow + (cp ^ sw) * 4);
                *(s8v*)(C + grow * (long)Nn + n0 + ql * 8 + k * 32) = v;
            }
        }
    }
}

// ---------------------------------------------------------------------------
// input norm: base = LN(nf + nte[node_type]) * g + b   (one wave per row)
// ---------------------------------------------------------------------------
__global__ __launch_bounds__(256) void k_innorm(const void* __restrict__ nf,
                                                const void* __restrict__ ntype,
                                                const void* __restrict__ nte,
                                                const float* __restrict__ g,
                                                const float* __restrict__ b,
                                                u16* __restrict__ base, int N,
                                                const int* __restrict__ flags) {
    const int isbf = flags[0], i64 = flags[1];
    const int wave = threadIdx.x >> 6, lane = threadIdx.x & 63;
    const int row = blockIdx.x * 4 + wave;
    if (row >= N) return;
    const long off = (long)row * 512 + lane * 8;
    const int nt = geti(ntype, row, i64);
    const long eoff = (long)nt * 512 + lane * 8;
    float x[8];
    if (isbf) {
        s8v xv = *(const s8v*)((const u16*)nf + off);
        s8v ev = *(const s8v*)((const u16*)nte + eoff);
#pragma unroll
        for (int j = 0; j < 8; j++) x[j] = bv(xv, j) + bv(ev, j);
    } else {
        f4v x0 = *(const f4v*)((const float*)nf + off);
        f4v x1 = *(const f4v*)((const float*)nf + off + 4);
        f4v e0 = *(const f4v*)((const float*)nte + eoff);
        f4v e1 = *(const f4v*)((const float*)nte + eoff + 4);
#pragma unroll
        for (int j = 0; j < 4; j++) { x[j] = x0[j] + e0[j]; x[4 + j] = x1[j] + e1[j]; }
    }
    float s = 0.f, s2 = 0.f;
#pragma unroll
    for (int j = 0; j < 8; j++) { s += x[j]; s2 += x[j] * x[j]; }
#pragma unroll
    for (int o = 32; o >= 1; o >>= 1) { s += __shfl_xor(s, o); s2 += __shfl_xor(s2, o); }
    const float mu = s * (1.f / 512.f);
    const float rs = rsqrtf(s2 * (1.f / 512.f) - mu * mu + 1e-5f);
    f4v g0 = *(const f4v*)(g + lane * 8); f4v g1 = *(const f4v*)(g + lane * 8 + 4);
    f4v b0 = *(const f4v*)(b + lane * 8); f4v b1 = *(const f4v*)(b + lane * 8 + 4);
    s8v o;
#pragma unroll
    for (int j = 0; j < 8; j++) {
        const float gg = j < 4 ? g0[j] : g1[j - 4];
        const float bb = j < 4 ? b0[j] : b1[j - 4];
        o[j] = (short)f2b((x[j] - mu) * rs * gg + bb);
    }
    *(s8v*)(base + off) = o;
}

// ===========================================================================
// FAST PATH: CSR build + gather (no feature atomics)
// ===========================================================================
__global__ __launch_bounds__(256) void k_count(const void* __restrict__ EI,
                                               u32* __restrict__ cnt, int E,
                                               const int* __restrict__ flags) {
    const int i64 = flags[1];
    const int t = blockIdx.x * 256 + threadIdx.x;
    if (t >= 2 * E) return;
    const int ed = (t < E) ? t : t - E;
    const int dst = (t < E) ? geti(EI, E + ed, i64) : geti(EI, ed, i64);
    atomicAdd(&cnt[dst], 1u);
}

// single-workgroup exclusive scan (1024 threads, Hillis-Steele per chunk)
__global__ __launch_bounds__(1024) void k_scan(const u32* __restrict__ cnt,
                                               u32* __restrict__ indptr, int N) {
    __shared__ u32 buf[1024];
    __shared__ u32 carry;
    if (threadIdx.x == 0) carry = 0;
    __syncthreads();
    for (int b0 = 0; b0 < N; b0 += 1024) {
        const int i = b0 + threadIdx.x;
        const u32 v = (i < N) ? cnt[i] : 0u;
        buf[threadIdx.x] = v;
        __syncthreads();
        for (int o = 1; o < 1024; o <<= 1) {
            u32 t = (threadIdx.x >= (u32)o) ? buf[threadIdx.x - o] : 0u;
            __syncthreads();
            buf[threadIdx.x] += t;
            __syncthreads();
        }
        const u32 excl = carry + buf[threadIdx.x] - v;
        __syncthreads();
        if (threadIdx.x == 1023) carry += buf[1023];
        if (i < N) indptr[i] = excl;
        __syncthreads();
    }
    if (threadIdx.x == 0) indptr[N] = carry;
}

__global__ void k_copy32(const u32* __restrict__ src, u32* __restrict__ dst, int n) {
    int t = blockIdx.x * 256 + threadIdx.x;
    if (t < n) dst[t] = src[t];
}

__global__ __launch_bounds__(256) void k_fill(const void* __restrict__ EI,
                                              const void* __restrict__ ET,
                                              const float* __restrict__ EW,
                                              u32* __restrict__ cursor,
                                              u32* __restrict__ srcrel,
                                              float* __restrict__ wts, int E,
                                              const int* __restrict__ flags) {
    const int i64 = flags[1];
    const int t = blockIdx.x * 256 + threadIdx.x;
    if (t >= 2 * E) return;
    int ed, src, dst, r;
    if (t < E) { ed = t;     r = geti(ET, ed, i64);     src = geti(EI, ed, i64);     dst = geti(EI, E + ed, i64); }
    else       { ed = t - E; r = geti(ET, ed, i64) + 2; src = geti(EI, E + ed, i64); dst = geti(EI, ed, i64); }
    const u32 pos = atomicAdd(&cursor[dst], 1u);
    srcrel[pos] = (u32)src | ((u32)r << 28);
    wts[pos] = EW[ed];
}

// gather + n1 fused: x1 = LN(base + S + b_self + agg/max(deg,1)) * g + b
// agg[d] = sum_e w*(Y4[src, rel*512+c]) + sum_r wsum_r * brel[r][c]
__global__ __launch_bounds__(256) void k_gather_n1(const u32* __restrict__ indptr,
                                                   const u32* __restrict__ srcrel,
                                                   const float* __restrict__ wts,
                                                   const u16* __restrict__ Y4,   // [N,2048]
                                                   const u16* __restrict__ S,    // [N,512]
                                                   const u16* __restrict__ base,
                                                   const float* __restrict__ brel,  // [4,512]
                                                   const float* __restrict__ bself,
                                                   const float* __restrict__ g,
                                                   const float* __restrict__ b,
                                                   u16* __restrict__ x1, int N) {
    const int wave = threadIdx.x >> 6, lane = threadIdx.x & 63;
    const int row = blockIdx.x * 4 + wave;
    if (row >= N) return;
    const int colb = lane * 8;
    float acc[8] = {}; float wsum[4] = {};
    const u32 beg = indptr[row], end = indptr[row + 1];
    for (u32 i = beg; i < end; i++) {
        const u32 pr = srcrel[i];
        const int src = (int)(pr & 0x0FFFFFFFu);
        const int rel = (int)(pr >> 28);
        const float w = wts[i];
        s8v yv = *(const s8v*)(Y4 + (long)src * 2048 + rel * 512 + colb);
#pragma unroll
        for (int j = 0; j < 8; j++) acc[j] += w * bv(yv, j);
        wsum[rel] += w;
    }
    const float deg = wsum[0] + wsum[1] + wsum[2] + wsum[3];
    const float dmx = 1.f / fmaxf(deg, 1.f);
    const long off = (long)row * 512 + colb;
    s8v sv = *(const s8v*)(S + off);
    s8v bs = *(const s8v*)(base + off);
    f4v sb0 = *(const f4v*)(bself + colb);
    f4v sb1 = *(const f4v*)(bself + colb + 4);
    // bias contribution from each relation
    float x[8], s = 0.f, s2 = 0.f;
#pragma unroll
    for (int h = 0; h < 2; h++) {
        f4v br0 = *(const f4v*)(brel + 0 * 512 + colb + 4 * h);
        f4v br1 = *(const f4v*)(brel + 1 * 512 + colb + 4 * h);
        f4v br2 = *(const f4v*)(brel + 2 * 512 + colb + 4 * h);
        f4v br3 = *(const f4v*)(brel + 3 * 512 + colb + 4 * h);
#pragma unroll
        for (int q = 0; q < 4; q++) {
            const int j = h * 4 + q;
            const float bias4 = wsum[0] * br0[q] + wsum[1] * br1[q] + wsum[2] * br2[q] + wsum[3] * br3[q];
            const float sbv = h ? sb1[q] : sb0[q];
            x[j] = bv(bs, j) + bv(sv, j) + sbv + (acc[j] + bias4) * dmx;
            s += x[j]; s2 += x[j] * x[j];
        }
    }
#pragma unroll
    for (int o = 32; o >= 1; o >>= 1) { s += __shfl_xor(s, o); s2 += __shfl_xor(s2, o); }
    const float mu = s * (1.f / 512.f);
    const float rs = rsqrtf(s2 * (1.f / 512.f) - mu * mu + 1e-5f);
    f4v g0 = *(const f4v*)(g + colb); f4v g1 = *(const f4v*)(g + colb + 4);
    f4v b0 = *(const f4v*)(b + colb); f4v b1 = *(const f4v*)(b + colb + 4);
    s8v o;
#pragma unroll
    for (int j = 0; j < 8; j++) {
        const float gg = j < 4 ? g0[j] : g1[j - 4];
        const float bb = j < 4 ? b0[j] : b1[j - 4];
        o[j] = (short)f2b((x[j] - mu) * rs * gg + bb);
    }
    *(s8v*)(x1 + off) = o;
}

// ===========================================================================
// SLOW PATH kernels (proven r3 fallback): scatter with f32 atomics
// ===========================================================================
__global__ __launch_bounds__(256) void k_deg(const void* __restrict__ EI,
                                             const float* __restrict__ EW,
                                             float* __restrict__ deg, int E,
                                             const int* __restrict__ flags) {
    const int i64 = flags[1];
    const int t = blockIdx.x * 256 + threadIdx.x;
    if (t >= 2 * E) return;
    const int ed = (t < E) ? t : t - E;
    const int dst = (t < E) ? geti(EI, E + ed, i64) : geti(EI, ed, i64);
    atomicAdd(&deg[dst], EW[ed]);
}

__global__ __launch_bounds__(256) void k_scatter(const void* __restrict__ EI,
                                                 const void* __restrict__ ET,
                                                 const float* __restrict__ EW,
                                                 const u16* __restrict__ Y,
                                                 const float* __restrict__ brel,
                                                 float* __restrict__ agg, int E, int rel,
                                                 const int* __restrict__ flags) {
    const int i64 = flags[1];
    const int wave = threadIdx.x >> 6, lane = threadIdx.x & 63;
    const long eid = (long)blockIdx.x * 4 + wave;
    if (eid >= 2 * (long)E) return;
    int ed, src, dst, r;
    if (eid < E) { ed = (int)eid;       r = geti(ET, ed, i64);     src = geti(EI, ed, i64);     dst = geti(EI, E + ed, i64); }
    else         { ed = (int)(eid - E); r = geti(ET, ed, i64) + 2; src = geti(EI, E + ed, i64); dst = geti(EI, ed, i64); }
    if (r != rel) return;
    const float w = EW[ed];
    s8v yv = *(const s8v*)(Y + (long)src * 512 + lane * 8);
    const float* bb = brel + (long)rel * 512 + lane * 8;
    float* ag = agg + (long)dst * 512 + lane * 8;
#pragma unroll
    for (int j = 0; j < 8; j++) atomicAdd(ag + j, w * (bv(yv, j) + bb[j]));
}

__global__ __launch_bounds__(256) void k_n1(const u16* __restrict__ S,
                                            const float* __restrict__ agg,
                                            const float* __restrict__ deg,
                                            const float* __restrict__ bself,
                                            const u16* __restrict__ base,
                                            const float* __restrict__ g,
                                            const float* __restrict__ b,
                                            u16* __restrict__ x1, int N) {
    const int wave = threadIdx.x >> 6, lane = threadIdx.x & 63;
    const int row = blockIdx.x * 4 + wave;
    if (row >= N) return;
    const long off = (long)row * 512 + lane * 8;
    s8v sv = *(const s8v*)(S + off);
    s8v bs = *(const s8v*)(base + off);
    f4v a0 = *(const f4v*)(agg + off);
    f4v a1 = *(const f4v*)(agg + off + 4);
    f4v sb0 = *(const f4v*)(bself + lane * 8);
    f4v sb1 = *(const f4v*)(bself + lane * 8 + 4);
    const float dmx = 1.f / fmaxf(deg[row], 1.f);
    float x[8], s = 0.f, s2 = 0.f;
#pragma unroll
    for (int j = 0; j < 8; j++) {
        const float av = (j < 4 ? a0[j] : a1[j - 4]);
        const float sbv = (j < 4 ? sb0[j] : sb1[j - 4]);
        x[j] = bv(bs, j) + bv(sv, j) + sbv + av * dmx;
        s += x[j]; s2 += x[j] * x[j];
    }
#pragma unroll
    for (int o = 32; o >= 1; o >>= 1) { s += __shfl_xor(s, o); s2 += __shfl_xor(s2, o); }
    const float mu = s * (1.f / 512.f);
    const float rs = rsqrtf(s2 * (1.f / 512.f) - mu * mu + 1e-5f);
    f4v g0 = *(const f4v*)(g + lane * 8); f4v g1 = *(const f4v*)(g + lane * 8 + 4);
    f4v b0 = *(const f4v*)(b + lane * 8); f4v b1 = *(const f4v*)(b + lane * 8 + 4);
    s8v o;
#pragma unroll
    for (int j = 0; j < 8; j++) {
        const float gg = j < 4 ? g0[j] : g1[j - 4];
        const float bb = j < 4 ? b0[j] : b1[j - 4];
        o[j] = (short)f2b((x[j] - mu) * rs * gg + bb);
    }
    *(s8v*)(x1 + off) = o;
}

// ---------------------------------------------------------------------------
// final: two LNs + graph-mix; writes final x bf16 IN PLACE over fio.
// (pure streaming; column sum done by k_colsum afterwards — no atomics here)
// ---------------------------------------------------------------------------
__global__ __launch_bounds__(256) void k_final(const u16* __restrict__ x1,
                                               u16* fio,
                                               const u16* __restrict__ base,
                                               const float* __restrict__ n2g,
                                               const float* __restrict__ n2b,
                                               const float* __restrict__ og,
                                               const float* __restrict__ ob,
                                               const float* __restrict__ gml,
                                               int N) {
    const int wave = threadIdx.x >> 6, lane = threadIdx.x & 63;
    const int row = blockIdx.x * 4 + wave;
    if (row >= N) return;
    const long off = (long)row * 512 + lane * 8;
    s8v xv = *(const s8v*)(x1 + off);
    s8v fv = *(const s8v*)(fio + off);
    float x[8], s = 0.f, s2 = 0.f;
#pragma unroll
    for (int j = 0; j < 8; j++) { x[j] = bv(xv, j) + bv(fv, j); s += x[j]; s2 += x[j] * x[j]; }
#pragma unroll
    for (int o = 32; o >= 1; o >>= 1) { s += __shfl_xor(s, o); s2 += __shfl_xor(s2, o); }
    float mu = s * (1.f / 512.f);
    float rs = rsqrtf(s2 * (1.f / 512.f) - mu * mu + 1e-5f);
    f4v g10 = *(const f4v*)(n2g + lane * 8); f4v g11 = *(const f4v*)(n2g + lane * 8 + 4);
    f4v b10 = *(const f4v*)(n2b + lane * 8); f4v b11 = *(const f4v*)(n2b + lane * 8 + 4);
    float t[8]; s = 0.f; s2 = 0.f;
#pragma unroll
    for (int j = 0; j < 8; j++) {
        const float gg = j < 4 ? g10[j] : g11[j - 4];
        const float bb = j < 4 ? b10[j] : b11[j - 4];
        t[j] = (x[j] - mu) * rs * gg + bb;
        s += t[j]; s2 += t[j] * t[j];
    }
#pragma unroll
    for (int o = 32; o >= 1; o >>= 1) { s += __shfl_xor(s, o); s2 += __shfl_xor(s2, o); }
    mu = s * (1.f / 512.f);
    rs = rsqrtf(s2 * (1.f / 512.f) - mu * mu + 1e-5f);
    f4v g20 = *(const f4v*)(og + lane * 8); f4v g21 = *(const f4v*)(og + lane * 8 + 4);
    f4v b20 = *(const f4v*)(ob + lane * 8); f4v b21 = *(const f4v*)(ob + lane * 8 + 4);
    s8v bs = *(const s8v*)(base + off);
    const float gm = 1.f / (1.f + expf(-gml[0]));
    s8v o;
#pragma unroll
    for (int j = 0; j < 8; j++) {
        const float gg = j < 4 ? g20[j] : g21[j - 4];
        const float bb = j < 4 ? b20[j] : b21[j - 4];
        const float u = (t[j] - mu) * rs * gg + bb;
        const float bsv = bv(bs, j);
        o[j] = (short)f2b(bsv + gm * (u - bsv));
    }
    *(s8v*)(fio + off) = o;
}

// ---------------------------------------------------------------------------
// column sum of final bf16 x: deterministic two-stage, zero atomics.
// stage 1: 512 blocks; block b accumulates rows b, b+512, ... (2 cols/thread)
// ---------------------------------------------------------------------------
__global__ __launch_bounds__(256) void k_colsum(const u16* __restrict__ x,
                                                float* __restrict__ partial, int N) {
    const int b = blockIdx.x, t = threadIdx.x;
    float s0 = 0.f, s1 = 0.f;
    for (int r = b; r < N; r += gridDim.x) {
        const u32 v = *(const u32*)(x + (long)r * 512 + 2 * t);
        s0 += b2f((u16)(v & 0xFFFFu));
        s1 += b2f((u16)(v >> 16));
    }
    partial[(long)b * 512 + 2 * t]     = s0;
    partial[(long)b * 512 + 2 * t + 1] = s1;
}

__global__ void k_emit(const u16* __restrict__ xout, void* __restrict__ dout, long n,
                       const int* __restrict__ flags) {
    const int isbf = flags[0];
    const long t = ((long)blockIdx.x * 256 + threadIdx.x) * 8;
    if (t >= n) return;
    s8v v = *(const s8v*)(xout + t);
    if (isbf) {
        *(s8v*)((u16*)dout + t) = v;
    } else {
        f4v o0, o1;
#pragma unroll
        for (int j = 0; j < 4; j++) { o0[j] = bv(v, j); o1[j] = bv(v, 4 + j); }
        *(f4v*)((float*)dout + t) = o0;
        *(f4v*)((float*)dout + t + 4) = o1;
    }
}

// stage 2 + pooled: PARALLEL reduce of 512 partial rows (one block per column)
// + doc-mix with x[0].
__global__ __launch_bounds__(256) void k_pooled(const u16* __restrict__ xout,
                                                const float* __restrict__ partial,
                                                const float* __restrict__ dml,
                                                void* __restrict__ dout,
                                                long pool_off, int N,
                                                const int* __restrict__ flags) {
    __shared__ float ws[4];
    const int c = blockIdx.x;     // 512 columns
    const int t = threadIdx.x;    // 256 threads: 2 partials each
    float s = partial[(long)t * 512 + c] + partial[(long)(t + 256) * 512 + c];
#pragma unroll
    for (int o = 32; o >= 1; o >>= 1) s += __shfl_xor(s, o);
    if ((t & 63) == 0) ws[t >> 6] = s;
    __syncthreads();
    if (t == 0) {
        const float cs = ws[0] + ws[1] + ws[2] + ws[3];
        const float dm = 1.f / (1.f + expf(-dml[0]));
        const float v = dm * b2f(xout[c]) + (1.f - dm) * (cs / (float)N);
        if (flags[0]) ((u16*)dout)[pool_off + c] = f2b(v);
        else          ((float*)dout)[pool_off + c] = v;
    }
}

// ---------------------------------------------------------------------------
extern "C" void kernel_launch(void* const* d_in, const int* in_sizes, int n_in,
                              void* d_out, int out_size, void* d_ws, size_t ws_size,
                              hipStream_t stream) {
    const void* nf    = d_in[0];
    const void* EI    = d_in[1];
    const void* ET    = d_in[2];
    const void* NT    = d_in[3];
    const void* EW    = d_in[4];
    const void* NTE   = d_in[5];
    const void* Wself = d_in[6];
    const void* bself = d_in[7];
    const void* Wrel  = d_in[8];
    const void* brel  = d_in[9];
    const void* ing   = d_in[10];
    const void* inb   = d_in[11];
    const void* n1g   = d_in[12];
    const void* n1b   = d_in[13];
    const void* Wf1   = d_in[14];
    const void* bf1   = d_in[15];
    const void* Wf2   = d_in[16];
    const void* bf2   = d_in[17];
    const void* n2g   = d_in[18];
    const void* n2b   = d_in[19];
    const void* outg  = d_in[20];
    const void* outb  = d_in[21];
    const void* gml   = d_in[22];
    const void* dml   = d_in[23];

    const int N = in_sizes[0] / 512;     // 50000
    const int E = in_sizes[2];           // 100000

    const size_t ND2 = (size_t)N * 512 * 2;
    const size_t ND4 = (size_t)N * 512 * 4;
    const size_t arena_elems = (size_t)E + 2048 + 512 * 10 + 1024 + 2;
    const size_t arena_bytes = arena_elems * 4;
    // bf16 weight buffers: Wrel(4*512*512) + Wself(512*512) + Wf1(1024*512) + Wf2(512*1024)
    const size_t WRELN = 4ull * 512 * 512, WSELFN = 512ull * 512;
    const size_t WF1N = 1024ull * 512, WF2N = 512ull * 1024;
    const size_t WBFB = (WRELN + WSELFN + WF1N + WF2N) * 2;   // bytes
    const int NPART = 512;
    const size_t partB = (size_t)NPART * 512 * 4;             // 1 MB partial colsums

    // fast path: base + Y4[N,2048]bf16 + S + CSR + misc + bf16 weights
    const size_t Y4B = (size_t)N * 2048 * 2;
    const size_t csrB = (size_t)(N + 1) * 4 + (size_t)N * 4 + (size_t)(2 * E) * 4 * 2;
    const size_t need_fast = ND2 + Y4B + ND2 + csrB + partB + 64 + WBFB + arena_bytes;
    // slow path (r3-proven): base + agg f32 + Ybuf + deg/partial/flags + weights + arena
    const size_t need_slow = ND2 + ND4 + ND2 + (size_t)N * 4 + partB + 64 + WBFB + arena_bytes;

    const int rowBlocks = (N + 3) / 4;
    const int Mt = (N + 255) / 256;
    const dim3 g512(512 / 256, Mt);
    const dim3 g1024(1024 / 256, Mt);
    const dim3 g2048(2048 / 256, Mt);

    if (ws_size >= need_fast) {
        // ------------------- FAST PATH: CSR gather -------------------
        char* p = (char*)d_ws;
        u16*   base   = (u16*)p;                         // ND2
        u16*   Y4     = (u16*)(p + ND2);                 // Y4B; later aliased by mid
        u16*   mid    = Y4;                              // FFN hidden [N,1024] bf16
        u16*   Sbuf   = (u16*)(p + ND2 + Y4B);           // ND2: S, later ffn_out/final x
        char*  q      = p + ND2 + Y4B + ND2;
        u32*   indptr = (u32*)q;                 q += (size_t)(N + 1) * 4;
        u32*   cursor = (u32*)q;                 q += (size_t)N * 4;   // also cnt
        u32*   srcrel = (u32*)q;                 q += (size_t)(2 * E) * 4;
        float* wts    = (float*)q;               q += (size_t)(2 * E) * 4;
        float* partial= (float*)q;               q += partB;
        int*   flags  = (int*)q;                 q += 64;
        u16*   wrelc  = (u16*)q;                 q += WRELN * 2;
        u16*   wselfc = (u16*)q;                 q += WSELFN * 2;
        u16*   wf1c   = (u16*)q;                 q += WF1N * 2;
        u16*   wf2c   = (u16*)q;                 q += WF2N * 2;
        float* arena  = (float*)q;
        float* EWc   = arena;
        float* brelc = EWc + E;
        float* bselfc= brelc + 2048;
        float* ingc  = bselfc + 512;
        float* inbc  = ingc + 512;
        float* n1gc  = inbc + 512;
        float* n1bc  = n1gc + 512;
        float* bf1c  = n1bc + 512;
        float* bf2c  = bf1c + 1024;
        float* n2gc  = bf2c + 512;
        float* n2bc  = n2gc + 512;
        float* outgc = n2bc + 512;
        float* outbc = outgc + 512;
        float* gmlc  = outbc + 512;
        float* dmlc  = gmlc + 1;
        u16* x1 = (u16*)d_out;          // bf16 intermediate; overwritten by k_emit

        k_detect<<<1, 256, 0, stream>>>((const u16*)nf, (const u32*)EI, flags);
        hipMemsetAsync(cursor, 0, (size_t)N * 4, stream);   // cnt

        auto cvt = [&](const void* s, float* d, int n) {
            k_cvt<<<(n + 255) / 256, 256, 0, stream>>>(s, d, n, flags);
        };
        auto cvt16 = [&](const void* s, u16* d, int n) {
            k_cvt16<<<(n + 255) / 256, 256, 0, stream>>>(s, d, n, flags);
        };
        cvt(EW, EWc, E);        cvt(brel, brelc, 2048);  cvt(bself, bselfc, 512);
        cvt(ing, ingc, 512);    cvt(inb, inbc, 512);     cvt(n1g, n1gc, 512);
        cvt(n1b, n1bc, 512);    cvt(bf1, bf1c, 1024);    cvt(bf2, bf2c, 512);
        cvt(n2g, n2gc, 512);    cvt(n2b, n2bc, 512);     cvt(outg, outgc, 512);
        cvt(outb, outbc, 512);  cvt(gml, gmlc, 1);       cvt(dml, dmlc, 1);
        cvt16(Wrel, wrelc, (int)WRELN);   cvt16(Wself, wselfc, (int)WSELFN);
        cvt16(Wf1, wf1c, (int)WF1N);      cvt16(Wf2, wf2c, (int)WF2N);

        k_innorm<<<rowBlocks, 256, 0, stream>>>(nf, NT, NTE, ingc, inbc, base, N, flags);
        // CSR build
        k_count<<<(2 * E + 255) / 256, 256, 0, stream>>>(EI, cursor, E, flags);
        k_scan<<<1, 1024, 0, stream>>>(cursor, indptr, N);
        k_copy32<<<(N + 255) / 256, 256, 0, stream>>>(indptr, cursor, N);
        k_fill<<<(2 * E + 255) / 256, 256, 0, stream>>>(EI, ET, EWc, cursor, srcrel, wts, E, flags);
        // transforms: Y4 = base @ Wrel_cat^T   ;   S = base @ Wself^T
        gemm_bt<0><<<g2048, 512, 0, stream>>>(base, wrelc, nullptr, Y4, N, 2048, 512);
        gemm_bt<0><<<g512, 512, 0, stream>>>(base, wselfc, nullptr, Sbuf, N, 512, 512);
        // fused gather + n1
        k_gather_n1<<<rowBlocks, 256, 0, stream>>>(indptr, srcrel, wts, Y4, Sbuf, base,
                                                   brelc, bselfc, n1gc, n1bc, x1, N);
        // FFN (mid aliases Y4, which is dead now; ffn_out into Sbuf, dead too)
        gemm_bt<1><<<g1024, 512, 0, stream>>>(x1, wf1c, bf1c, mid, N, 1024, 512);
        gemm_bt<0><<<g512, 512, 0, stream>>>(mid, wf2c, bf2c, Sbuf, N, 512, 1024);

        k_final<<<rowBlocks, 256, 0, stream>>>(x1, Sbuf, base, n2gc, n2bc, outgc, outbc,
                                               gmlc, N);
        k_colsum<<<NPART, 256, 0, stream>>>(Sbuf, partial, N);
        k_emit<<<(int)(((long)N * 512 / 8 + 255) / 256), 256, 0, stream>>>(Sbuf, d_out,
                                                                           (long)N * 512, flags);
        k_pooled<<<512, 256, 0, stream>>>(Sbuf, partial, dmlc, d_out, (long)N * 512, N, flags);

    } else if (ws_size >= need_slow) {
        // ------------------- SLOW PATH (r3-proven) -------------------
        char* p = (char*)d_ws;
        u16*   base = (u16*)p;
        float* agg  = (float*)(p + ND2);
        u16*   mid  = (u16*)(p + ND2);
        u16*   Ybuf = (u16*)(p + ND2 + ND4);
        float* deg  = (float*)(p + ND2 + ND4 + ND2);
        float* partial = deg + N;
        int*   flags  = (int*)(partial + NPART * 512);
        char*  q2     = (char*)flags + 64;
        u16*   wrelc  = (u16*)q2;                q2 += WRELN * 2;
        u16*   wselfc = (u16*)q2;                q2 += WSELFN * 2;
        u16*   wf1c   = (u16*)q2;                q2 += WF1N * 2;
        u16*   wf2c   = (u16*)q2;                q2 += WF2N * 2;
        float* arena  = (float*)q2;
        float* EWc   = arena;
        float* brelc = EWc + E;
        float* bselfc= brelc + 2048;
        float* ingc  = bselfc + 512;
        float* inbc  = ingc + 512;
        float* n1gc  = inbc + 512;
        float* n1bc  = n1gc + 512;
        float* bf1c  = n1bc + 512;
        float* bf2c  = bf1c + 1024;
        float* n2gc  = bf2c + 512;
        float* n2bc  = n2gc + 512;
        float* outgc = n2bc + 512;
        float* outbc = outgc + 512;
        float* gmlc  = outbc + 512;
        float* dmlc  = gmlc + 1;
        u16* x1 = (u16*)d_out;

        k_detect<<<1, 256, 0, stream>>>((const u16*)nf, (const u32*)EI, flags);
        hipMemsetAsync(agg, 0, ND4, stream);
        hipMemsetAsync(deg, 0, (size_t)N * 4, stream);

        auto cvt = [&](const void* s, float* d, int n) {
            k_cvt<<<(n + 255) / 256, 256, 0, stream>>>(s, d, n, flags);
        };
        auto cvt16 = [&](const void* s, u16* d, int n) {
            k_cvt16<<<(n + 255) / 256, 256, 0, stream>>>(s, d, n, flags);
        };
        cvt(EW, EWc, E);        cvt(brel, brelc, 2048);  cvt(bself, bselfc, 512);
        cvt(ing, ingc, 512);    cvt(inb, inbc, 512);     cvt(n1g, n1gc, 512);
        cvt(n1b, n1bc, 512);    cvt(bf1, bf1c, 1024);    cvt(bf2, bf2c, 512);
        cvt(n2g, n2gc, 512);    cvt(n2b, n2bc, 512);     cvt(outg, outgc, 512);
        cvt(outb, outbc, 512);  cvt(gml, gmlc, 1);       cvt(dml, dmlc, 1);
        cvt16(Wrel, wrelc, (int)WRELN);   cvt16(Wself, wselfc, (int)WSELFN);
        cvt16(Wf1, wf1c, (int)WF1N);      cvt16(Wf2, wf2c, (int)WF2N);

        k_innorm<<<rowBlocks, 256, 0, stream>>>(nf, NT, NTE, ingc, inbc, base, N, flags);
        k_deg<<<(2 * E + 255) / 256, 256, 0, stream>>>(EI, EWc, deg, E, flags);

        for (int r = 0; r < 4; r++) {
            gemm_bt<0><<<g512, 512, 0, stream>>>(base, wrelc + (size_t)r * 512 * 512, nullptr,
                                                 Ybuf, N, 512, 512);
            k_scatter<<<(2 * E + 3) / 4, 256, 0, stream>>>(EI, ET, EWc, Ybuf, brelc, agg,
                                                           E, r, flags);
        }

        gemm_bt<0><<<g512, 512, 0, stream>>>(base, wselfc, nullptr, Ybuf, N, 512, 512);
        k_n1<<<rowBlocks, 256, 0, stream>>>(Ybuf, agg, deg, bselfc, base, n1gc, n1bc, x1, N);

        gemm_bt<1><<<g1024, 512, 0, stream>>>(x1, wf1c, bf1c, mid, N, 1024, 512);
        gemm_bt<0><<<g512, 512, 0, stream>>>(mid, wf2c, bf2c, Ybuf, N, 512, 1024);

        k_final<<<rowBlocks, 256, 0, stream>>>(x1, Ybuf, base, n2gc, n2bc, outgc, outbc,
                                               gmlc, N);
        k_colsum<<<NPART, 256, 0, stream>>>(Ybuf, partial, N);
        k_emit<<<(int)(((long)N * 512 / 8 + 255) / 256), 256, 0, stream>>>(Ybuf, d_out,
                                                                           (long)N * 512, flags);
        k_pooled<<<512, 256, 0, stream>>>(Ybuf, partial, dmlc, d_out, (long)N * 512, N, flags);
    } else {
        const float val = 2000.f + (float)(ws_size >> 20);
        k_diag<<<(out_size + 255) / 256, 256, 0, stream>>>((u16*)d_out, out_size, val);
    }
}

// Round 8
// 904.540 us; speedup vs baseline: 1.2858x; 1.0583x over previous
//
#include <hip/hip_runtime.h>
#include <hip/hip_bf16.h>

typedef __attribute__((ext_vector_type(8))) short s8v;   // 8 x bf16 (as i16 bits)
typedef __attribute__((ext_vector_type(4))) short s4v;   // 4 x bf16 (8B)
typedef __attribute__((ext_vector_type(4))) float f4v;
typedef unsigned short u16;
typedef unsigned int u32;

__device__ __forceinline__ float b2f(u16 u) {
    union { unsigned int i; float f; } v; v.i = ((unsigned int)u) << 16; return v.f;
}
__device__ __forceinline__ u16 f2b(float f) {
    union { float f; unsigned int i; } v; v.f = f;
    unsigned int r = v.i + 0x7FFFu + ((v.i >> 16) & 1u);  // round-nearest-even
    return (u16)(r >> 16);
}
__device__ __forceinline__ float bv(const s8v& s, int j) { return b2f((u16)s[j]); }
// integer load valid for int32 or int64 (low word) storage
__device__ __forceinline__ int geti(const void* p, long i, int i64) {
    return i64 ? (int)((const u32*)p)[2 * i] : ((const int*)p)[i];
}

// async global -> LDS, 16 bytes per lane (linear LDS dest: uniform base + lane*16)
__device__ __forceinline__ void ld16(const u16* g, u16* l) {
    __builtin_amdgcn_global_load_lds(
        (const __attribute__((address_space(1))) unsigned int*)g,
        (__attribute__((address_space(3))) unsigned int*)l, 16, 0, 0);
}

// ---------------------------------------------------------------------------
// dtype detector: flags[0]=1 floats are bf16 (else f32); flags[1]=1 ints int64.
// ---------------------------------------------------------------------------
__global__ void k_detect(const u16* __restrict__ nf, const u32* __restrict__ EI,
                         int* __restrict__ flags) {
    __shared__ int cnt, nz;
    if (threadIdx.x == 0) { cnt = 0; nz = 0; }
    __syncthreads();
    int c = 0;
    for (int i = threadIdx.x; i < 4096; i += 256) {
        u16 v = nf[2 * i];
        int e = (v >> 7) & 0xFF;
        if (e >= 64 && e < 160) c++;
    }
    atomicAdd(&cnt, c);
    int z = 0;
    for (int i = threadIdx.x; i < 4096; i += 256)
        if (EI[2 * i + 1] != 0) z++;
    atomicAdd(&nz, z);
    __syncthreads();
    if (threadIdx.x == 0) { flags[0] = (cnt >= 2867) ? 1 : 0; flags[1] = (nz == 0) ? 1 : 0; }
}

__global__ void k_cvt(const void* __restrict__ src, float* __restrict__ dst, int n,
                      const int* __restrict__ flags) {
    const int isbf = flags[0];
    int t = blockIdx.x * 256 + threadIdx.x;
    if (t < n) dst[t] = isbf ? b2f(((const u16*)src)[t]) : ((const float*)src)[t];
}

// convert weights to bf16 (copy if already bf16)
__global__ void k_cvt16(const void* __restrict__ src, u16* __restrict__ dst, int n,
                        const int* __restrict__ flags) {
    const int isbf = flags[0];
    int t = blockIdx.x * 256 + threadIdx.x;
    if (t < n) dst[t] = isbf ? ((const u16*)src)[t] : f2b(((const float*)src)[t]);
}

__global__ void k_diag(u16* __restrict__ out, int n, float val) {
    int t = blockIdx.x * 256 + threadIdx.x;
    if (t < n) out[t] = f2b(val);
}

// ---------------------------------------------------------------------------
// GEMM: C[M,Nn] = A[M,K] @ B[Nn,K]^T (+bias f32, optional exact gelu)
// 128x128 tile, BK=64, 4 waves (2x2), 64 KiB double-buffered LDS ->
// TWO blocks resident per CU: inter-block overlap hides barrier drains
// (m97/m114 mechanism) on top of R6's counted-vmcnt loads-in-flight.
// vmcnt(8) proof: in-order VMEM retirement; each thread issues 8/K-tile;
// <=8 outstanding => prior tile's 8 landed. LDS slot-XOR swizzle both-sides
// (linear gload_lds dest + inverse-swizzled global src + swizzled ds_read).
// Epilogue: swapped-operand MFMA -> LDS C-stage -> 64B coalesced stores.
// XCD-aware bijective block swizzle. A,B bf16.
// Nn multiple of 128, K multiple of 64. M tail clamped on load, guarded store.
// ---------------------------------------------------------------------------
template<int GELU>
__global__ __launch_bounds__(256) void gemm_bt(const u16* __restrict__ A,
                                               const u16* __restrict__ B,
                                               const float* __restrict__ bias,
                                               u16* __restrict__ C,
                                               int M, int Nn, int K) {
    __shared__ u16 lds[2][2][128 * 64];   // [buf][A=0/B=1][128 rows][64 cols] = 64 KiB
    const int t = threadIdx.x;            // 0..255
    const int lane = t & 63;
    const int quad = lane >> 4;
    const int l16  = lane & 15;
    const int wid  = t >> 6;
    const int wm = wid >> 1, wn = wid & 1;   // 2 x 2 wave grid

    // ---- XCD-aware bijective swizzle ----
    const int nwg  = gridDim.x * gridDim.y;
    const int orig = blockIdx.y * gridDim.x + blockIdx.x;
    const int xcd  = orig & 7;
    const int qq   = nwg >> 3, rr = nwg & 7;
    const int base_l = (xcd < rr) ? xcd * (qq + 1) : rr * (qq + 1) + (xcd - rr) * qq;
    const int logical = base_l + (orig >> 3);
    const long m0 = (long)(logical / gridDim.x) * 128;
    const long n0 = (long)(logical % gridDim.x) * 128;

    // ---- staging geometry: per K-tile 8 issues (4 A + 4 B), 256 thr x 16B ----
    // issue q: linear LDS byte = q*4096 + t*16 -> row = q*32 + t/8, phys slot t&7.
    // logical slot sl = (t&7) ^ (row&7): fetch global slot sl so the swizzled
    // reader finds logical data at phys slot L ^ (row&7).  (row&7 = (t/8)&7)
    const int srow = t >> 3;
    const int sl   = (t & 7) ^ (srow & 7);
    long aoff[4], boff[4];
#pragma unroll
    for (int q = 0; q < 4; q++) {
        long ra = m0 + q * 32 + srow; if (ra >= M) ra = M - 1;  // clamp; stores guarded
        aoff[q] = ra * (long)K + sl * 8;
        long rb = n0 + q * 32 + srow;                            // Nn multiple of 128
        boff[q] = rb * (long)K + sl * 8;
    }

    f4v acc[4][4] = {};
    const int NT = K >> 6;

    // prologue: stage tile 0 into buf 0
    {
        u16* la = &lds[0][0][0] + t * 8;
        u16* lb = &lds[0][1][0] + t * 8;
#pragma unroll
        for (int q = 0; q < 4; q++) ld16(A + aoff[q], la + q * 2048);
#pragma unroll
        for (int q = 0; q < 4; q++) ld16(B + boff[q], lb + q * 2048);
    }

    for (int kt = 0; kt < NT; kt++) {
        const int cur = kt & 1;
        if (kt + 1 < NT) {
            const long kc = (long)(kt + 1) * 64;
            u16* la = &lds[cur ^ 1][0][0] + t * 8;
            u16* lb = &lds[cur ^ 1][1][0] + t * 8;
#pragma unroll
            for (int q = 0; q < 4; q++) ld16(A + aoff[q] + kc, la + q * 2048);
#pragma unroll
            for (int q = 0; q < 4; q++) ld16(B + boff[q] + kc, lb + q * 2048);
            __builtin_amdgcn_sched_barrier(0);
            asm volatile("s_waitcnt vmcnt(8)");   // newest 8 (next tile) keep flying
        } else {
            __builtin_amdgcn_sched_barrier(0);
            asm volatile("s_waitcnt vmcnt(0)");   // tail: drain
        }
        __builtin_amdgcn_sched_barrier(0);
        __builtin_amdgcn_s_barrier();             // cur tile staged by ALL waves
        __builtin_amdgcn_sched_barrier(0);

        const u16* LA = &lds[cur][0][0];
        const u16* LB = &lds[cur][1][0];
        s8v bf[4][2];
#pragma unroll
        for (int j = 0; j < 4; j++) {
            const int row = wn * 64 + j * 16 + l16;
#pragma unroll
            for (int ks = 0; ks < 2; ks++)
                bf[j][ks] = *(const s8v*)(LB + row * 64 + ((ks * 4 + quad) ^ (row & 7)) * 8);
        }
        __builtin_amdgcn_s_setprio(1);
#pragma unroll
        for (int i = 0; i < 4; i++) {
            const int row = wm * 64 + i * 16 + l16;
            s8v af0 = *(const s8v*)(LA + row * 64 + ((quad) ^ (row & 7)) * 8);
            s8v af1 = *(const s8v*)(LA + row * 64 + ((4 + quad) ^ (row & 7)) * 8);
#pragma unroll
            for (int j = 0; j < 4; j++) {
                acc[i][j] = __builtin_amdgcn_mfma_f32_16x16x32_bf16(bf[j][0], af0, acc[i][j], 0, 0, 0);
                acc[i][j] = __builtin_amdgcn_mfma_f32_16x16x32_bf16(bf[j][1], af1, acc[i][j], 0, 0, 0);
            }
        }
        __builtin_amdgcn_s_setprio(0);
        asm volatile("s_waitcnt lgkmcnt(0)");     // all LDS reads of cur complete
        __builtin_amdgcn_sched_barrier(0);
        __builtin_amdgcn_s_barrier();             // WAR: next iter's stage overwrites cur^1
        __builtin_amdgcn_sched_barrier(0);
    }
    // swapped layout: m = wm*64+i*16+l16 (row), n = wn*64+j*16+quad*4+r (col)

    // ---- epilogue stage 1: bias/gelu, pack 4 cols -> b64 LDS write ----
    // chunk = col_local/4 = wn*16+j*4+quad ; swizzle chunk ^ (row_local & 14)
    u16* cs = &lds[0][0][0];                      // reuse as [128][128] bf16 = 32 KiB
#pragma unroll
    for (int j = 0; j < 4; j++) {
        const long ncol = n0 + wn * 64 + j * 16 + quad * 4;
        f4v bb = {0.f, 0.f, 0.f, 0.f};
        if (bias) bb = *(const f4v*)(bias + ncol);
#pragma unroll
        for (int i = 0; i < 4; i++) {
            const int row_local = wm * 64 + i * 16 + l16;
            const int ch = (wn * 16 + j * 4 + quad) ^ (row_local & 14);
            s4v pk;
#pragma unroll
            for (int r = 0; r < 4; r++) {
                float v = acc[i][j][r] + bb[r];
                if (GELU) v = 0.5f * v * (1.f + erff(v * 0.70710678118654752f));
                pk[r] = (short)f2b(v);
            }
            *(s4v*)(cs + row_local * 128 + ch * 4) = pk;
        }
    }
    __syncthreads();

    // ---- epilogue stage 2: coalesced copy-out, 64B per 4-lane group ----
    // thread t: row = pass*64 + (t>>2), quarter q = t&3; 4 x 16B stores.
    const int q4 = t & 3;
#pragma unroll
    for (int pass = 0; pass < 2; pass++) {
        const int row = pass * 64 + (t >> 2);
        const long grow = m0 + row;
        if (grow < M) {
            const u16* lrow = cs + row * 128;
            const int s = row & 14;
#pragma unroll
            for (int k = 0; k < 4; k++) {
                const int c0 = (q4 * 2 + k * 8) ^ s;   // even -> 16B aligned
                s8v v = *(const s8v*)(lrow + c0 * 4);
                *(s8v*)(C + grow * (long)Nn + n0 + q4 * 8 + k * 32) = v;
            }
        }
    }
}

// ---------------------------------------------------------------------------
// input norm: base = LN(nf + nte[node_type]) * g + b   (one wave per row)
// ---------------------------------------------------------------------------
__global__ __launch_bounds__(256) void k_innorm(const void* __restrict__ nf,
                                                const void* __restrict__ ntype,
                                                const void* __restrict__ nte,
                                                const float* __restrict__ g,
                                                const float* __restrict__ b,
                                                u16* __restrict__ base, int N,
                                                const int* __restrict__ flags) {
    const int isbf = flags[0], i64 = flags[1];
    const int wave = threadIdx.x >> 6, lane = threadIdx.x & 63;
    const int row = blockIdx.x * 4 + wave;
    if (row >= N) return;
    const long off = (long)row * 512 + lane * 8;
    const int nt = geti(ntype, row, i64);
    const long eoff = (long)nt * 512 + lane * 8;
    float x[8];
    if (isbf) {
        s8v xv = *(const s8v*)((const u16*)nf + off);
        s8v ev = *(const s8v*)((const u16*)nte + eoff);
#pragma unroll
        for (int j = 0; j < 8; j++) x[j] = bv(xv, j) + bv(ev, j);
    } else {
        f4v x0 = *(const f4v*)((const float*)nf + off);
        f4v x1 = *(const f4v*)((const float*)nf + off + 4);
        f4v e0 = *(const f4v*)((const float*)nte + eoff);
        f4v e1 = *(const f4v*)((const float*)nte + eoff + 4);
#pragma unroll
        for (int j = 0; j < 4; j++) { x[j] = x0[j] + e0[j]; x[4 + j] = x1[j] + e1[j]; }
    }
    float s = 0.f, s2 = 0.f;
#pragma unroll
    for (int j = 0; j < 8; j++) { s += x[j]; s2 += x[j] * x[j]; }
#pragma unroll
    for (int o = 32; o >= 1; o >>= 1) { s += __shfl_xor(s, o); s2 += __shfl_xor(s2, o); }
    const float mu = s * (1.f / 512.f);
    const float rs = rsqrtf(s2 * (1.f / 512.f) - mu * mu + 1e-5f);
    f4v g0 = *(const f4v*)(g + lane * 8); f4v g1 = *(const f4v*)(g + lane * 8 + 4);
    f4v b0 = *(const f4v*)(b + lane * 8); f4v b1 = *(const f4v*)(b + lane * 8 + 4);
    s8v o;
#pragma unroll
    for (int j = 0; j < 8; j++) {
        const float gg = j < 4 ? g0[j] : g1[j - 4];
        const float bb = j < 4 ? b0[j] : b1[j - 4];
        o[j] = (short)f2b((x[j] - mu) * rs * gg + bb);
    }
    *(s8v*)(base + off) = o;
}

// ===========================================================================
// FAST PATH: CSR build + gather (no feature atomics)
// ===========================================================================
__global__ __launch_bounds__(256) void k_count(const void* __restrict__ EI,
                                               u32* __restrict__ cnt, int E,
                                               const int* __restrict__ flags) {
    const int i64 = flags[1];
    const int t = blockIdx.x * 256 + threadIdx.x;
    if (t >= 2 * E) return;
    const int ed = (t < E) ? t : t - E;
    const int dst = (t < E) ? geti(EI, E + ed, i64) : geti(EI, ed, i64);
    atomicAdd(&cnt[dst], 1u);
}

// single-workgroup exclusive scan (1024 threads, Hillis-Steele per chunk)
__global__ __launch_bounds__(1024) void k_scan(const u32* __restrict__ cnt,
                                               u32* __restrict__ indptr, int N) {
    __shared__ u32 buf[1024];
    __shared__ u32 carry;
    if (threadIdx.x == 0) carry = 0;
    __syncthreads();
    for (int b0 = 0; b0 < N; b0 += 1024) {
        const int i = b0 + threadIdx.x;
        const u32 v = (i < N) ? cnt[i] : 0u;
        buf[threadIdx.x] = v;
        __syncthreads();
        for (int o = 1; o < 1024; o <<= 1) {
            u32 t = (threadIdx.x >= (u32)o) ? buf[threadIdx.x - o] : 0u;
            __syncthreads();
            buf[threadIdx.x] += t;
            __syncthreads();
        }
        const u32 excl = carry + buf[threadIdx.x] - v;
        __syncthreads();
        if (threadIdx.x == 1023) carry += buf[1023];
        if (i < N) indptr[i] = excl;
        __syncthreads();
    }
    if (threadIdx.x == 0) indptr[N] = carry;
}

__global__ void k_copy32(const u32* __restrict__ src, u32* __restrict__ dst, int n) {
    int t = blockIdx.x * 256 + threadIdx.x;
    if (t < n) dst[t] = src[t];
}

__global__ __launch_bounds__(256) void k_fill(const void* __restrict__ EI,
                                              const void* __restrict__ ET,
                                              const float* __restrict__ EW,
                                              u32* __restrict__ cursor,
                                              u32* __restrict__ srcrel,
                                              float* __restrict__ wts, int E,
                                              const int* __restrict__ flags) {
    const int i64 = flags[1];
    const int t = blockIdx.x * 256 + threadIdx.x;
    if (t >= 2 * E) return;
    int ed, src, dst, r;
    if (t < E) { ed = t;     r = geti(ET, ed, i64);     src = geti(EI, ed, i64);     dst = geti(EI, E + ed, i64); }
    else       { ed = t - E; r = geti(ET, ed, i64) + 2; src = geti(EI, E + ed, i64); dst = geti(EI, ed, i64); }
    const u32 pos = atomicAdd(&cursor[dst], 1u);
    srcrel[pos] = (u32)src | ((u32)r << 28);
    wts[pos] = EW[ed];
}

// gather + n1 fused: x1 = LN(base + S + b_self + agg/max(deg,1)) * g + b
// agg[d] = sum_e w*(Y4[src, rel*512+c]) + sum_r wsum_r * brel[r][c]
__global__ __launch_bounds__(256) void k_gather_n1(const u32* __restrict__ indptr,
                                                   const u32* __restrict__ srcrel,
                                                   const float* __restrict__ wts,
                                                   const u16* __restrict__ Y4,   // [N,2048]
                                                   const u16* __restrict__ S,    // [N,512]
                                                   const u16* __restrict__ base,
                                                   const float* __restrict__ brel,  // [4,512]
                                                   const float* __restrict__ bself,
                                                   const float* __restrict__ g,
                                                   const float* __restrict__ b,
                                                   u16* __restrict__ x1, int N) {
    const int wave = threadIdx.x >> 6, lane = threadIdx.x & 63;
    const int row = blockIdx.x * 4 + wave;
    if (row >= N) return;
    const int colb = lane * 8;
    float acc[8] = {}; float wsum[4] = {};
    const u32 beg = indptr[row], end = indptr[row + 1];
    for (u32 i = beg; i < end; i++) {
        const u32 pr = srcrel[i];
        const int src = (int)(pr & 0x0FFFFFFFu);
        const int rel = (int)(pr >> 28);
        const float w = wts[i];
        s8v yv = *(const s8v*)(Y4 + (long)src * 2048 + rel * 512 + colb);
#pragma unroll
        for (int j = 0; j < 8; j++) acc[j] += w * bv(yv, j);
        wsum[rel] += w;
    }
    const float deg = wsum[0] + wsum[1] + wsum[2] + wsum[3];
    const float dmx = 1.f / fmaxf(deg, 1.f);
    const long off = (long)row * 512 + colb;
    s8v sv = *(const s8v*)(S + off);
    s8v bs = *(const s8v*)(base + off);
    f4v sb0 = *(const f4v*)(bself + colb);
    f4v sb1 = *(const f4v*)(bself + colb + 4);
    // bias contribution from each relation
    float x[8], s = 0.f, s2 = 0.f;
#pragma unroll
    for (int h = 0; h < 2; h++) {
        f4v br0 = *(const f4v*)(brel + 0 * 512 + colb + 4 * h);
        f4v br1 = *(const f4v*)(brel + 1 * 512 + colb + 4 * h);
        f4v br2 = *(const f4v*)(brel + 2 * 512 + colb + 4 * h);
        f4v br3 = *(const f4v*)(brel + 3 * 512 + colb + 4 * h);
#pragma unroll
        for (int q = 0; q < 4; q++) {
            const int j = h * 4 + q;
            const float bias4 = wsum[0] * br0[q] + wsum[1] * br1[q] + wsum[2] * br2[q] + wsum[3] * br3[q];
            const float sbv = h ? sb1[q] : sb0[q];
            x[j] = bv(bs, j) + bv(sv, j) + sbv + (acc[j] + bias4) * dmx;
            s += x[j]; s2 += x[j] * x[j];
        }
    }
#pragma unroll
    for (int o = 32; o >= 1; o >>= 1) { s += __shfl_xor(s, o); s2 += __shfl_xor(s2, o); }
    const float mu = s * (1.f / 512.f);
    const float rs = rsqrtf(s2 * (1.f / 512.f) - mu * mu + 1e-5f);
    f4v g0 = *(const f4v*)(g + colb); f4v g1 = *(const f4v*)(g + colb + 4);
    f4v b0 = *(const f4v*)(b + colb); f4v b1 = *(const f4v*)(b + colb + 4);
    s8v o;
#pragma unroll
    for (int j = 0; j < 8; j++) {
        const float gg = j < 4 ? g0[j] : g1[j - 4];
        const float bb = j < 4 ? b0[j] : b1[j - 4];
        o[j] = (short)f2b((x[j] - mu) * rs * gg + bb);
    }
    *(s8v*)(x1 + off) = o;
}

// ===========================================================================
// SLOW PATH kernels (proven r3 fallback): scatter with f32 atomics
// ===========================================================================
__global__ __launch_bounds__(256) void k_deg(const void* __restrict__ EI,
                                             const float* __restrict__ EW,
                                             float* __restrict__ deg, int E,
                                             const int* __restrict__ flags) {
    const int i64 = flags[1];
    const int t = blockIdx.x * 256 + threadIdx.x;
    if (t >= 2 * E) return;
    const int ed = (t < E) ? t : t - E;
    const int dst = (t < E) ? geti(EI, E + ed, i64) : geti(EI, ed, i64);
    atomicAdd(&deg[dst], EW[ed]);
}

__global__ __launch_bounds__(256) void k_scatter(const void* __restrict__ EI,
                                                 const void* __restrict__ ET,
                                                 const float* __restrict__ EW,
                                                 const u16* __restrict__ Y,
                                                 const float* __restrict__ brel,
                                                 float* __restrict__ agg, int E, int rel,
                                                 const int* __restrict__ flags) {
    const int i64 = flags[1];
    const int wave = threadIdx.x >> 6, lane = threadIdx.x & 63;
    const long eid = (long)blockIdx.x * 4 + wave;
    if (eid >= 2 * (long)E) return;
    int ed, src, dst, r;
    if (eid < E) { ed = (int)eid;       r = geti(ET, ed, i64);     src = geti(EI, ed, i64);     dst = geti(EI, E + ed, i64); }
    else         { ed = (int)(eid - E); r = geti(ET, ed, i64) + 2; src = geti(EI, E + ed, i64); dst = geti(EI, ed, i64); }
    if (r != rel) return;
    const float w = EW[ed];
    s8v yv = *(const s8v*)(Y + (long)src * 512 + lane * 8);
    const float* bb = brel + (long)rel * 512 + lane * 8;
    float* ag = agg + (long)dst * 512 + lane * 8;
#pragma unroll
    for (int j = 0; j < 8; j++) atomicAdd(ag + j, w * (bv(yv, j) + bb[j]));
}

__global__ __launch_bounds__(256) void k_n1(const u16* __restrict__ S,
                                            const float* __restrict__ agg,
                                            const float* __restrict__ deg,
                                            const float* __restrict__ bself,
                                            const u16* __restrict__ base,
                                            const float* __restrict__ g,
                                            const float* __restrict__ b,
                                            u16* __restrict__ x1, int N) {
    const int wave = threadIdx.x >> 6, lane = threadIdx.x & 63;
    const int row = blockIdx.x * 4 + wave;
    if (row >= N) return;
    const long off = (long)row * 512 + lane * 8;
    s8v sv = *(const s8v*)(S + off);
    s8v bs = *(const s8v*)(base + off);
    f4v a0 = *(const f4v*)(agg + off);
    f4v a1 = *(const f4v*)(agg + off + 4);
    f4v sb0 = *(const f4v*)(bself + lane * 8);
    f4v sb1 = *(const f4v*)(bself + lane * 8 + 4);
    const float dmx = 1.f / fmaxf(deg[row], 1.f);
    float x[8], s = 0.f, s2 = 0.f;
#pragma unroll
    for (int j = 0; j < 8; j++) {
        const float av = (j < 4 ? a0[j] : a1[j - 4]);
        const float sbv = (j < 4 ? sb0[j] : sb1[j - 4]);
        x[j] = bv(bs, j) + bv(sv, j) + sbv + av * dmx;
        s += x[j]; s2 += x[j] * x[j];
    }
#pragma unroll
    for (int o = 32; o >= 1; o >>= 1) { s += __shfl_xor(s, o); s2 += __shfl_xor(s2, o); }
    const float mu = s * (1.f / 512.f);
    const float rs = rsqrtf(s2 * (1.f / 512.f) - mu * mu + 1e-5f);
    f4v g0 = *(const f4v*)(g + lane * 8); f4v g1 = *(const f4v*)(g + lane * 8 + 4);
    f4v b0 = *(const f4v*)(b + lane * 8); f4v b1 = *(const f4v*)(b + lane * 8 + 4);
    s8v o;
#pragma unroll
    for (int j = 0; j < 8; j++) {
        const float gg = j < 4 ? g0[j] : g1[j - 4];
        const float bb = j < 4 ? b0[j] : b1[j - 4];
        o[j] = (short)f2b((x[j] - mu) * rs * gg + bb);
    }
    *(s8v*)(x1 + off) = o;
}

// ---------------------------------------------------------------------------
// final: two LNs + graph-mix; writes final x bf16 IN PLACE over fio.
// (pure streaming; column sum done by k_colsum afterwards — no atomics here)
// ---------------------------------------------------------------------------
__global__ __launch_bounds__(256) void k_final(const u16* __restrict__ x1,
                                               u16* fio,
                                               const u16* __restrict__ base,
                                               const float* __restrict__ n2g,
                                               const float* __restrict__ n2b,
                                               const float* __restrict__ og,
                                               const float* __restrict__ ob,
                                               const float* __restrict__ gml,
                                               int N) {
    const int wave = threadIdx.x >> 6, lane = threadIdx.x & 63;
    const int row = blockIdx.x * 4 + wave;
    if (row >= N) return;
    const long off = (long)row * 512 + lane * 8;
    s8v xv = *(const s8v*)(x1 + off);
    s8v fv = *(const s8v*)(fio + off);
    float x[8], s = 0.f, s2 = 0.f;
#pragma unroll
    for (int j = 0; j < 8; j++) { x[j] = bv(xv, j) + bv(fv, j); s += x[j]; s2 += x[j] * x[j]; }
#pragma unroll
    for (int o = 32; o >= 1; o >>= 1) { s += __shfl_xor(s, o); s2 += __shfl_xor(s2, o); }
    float mu = s * (1.f / 512.f);
    float rs = rsqrtf(s2 * (1.f / 512.f) - mu * mu + 1e-5f);
    f4v g10 = *(const f4v*)(n2g + lane * 8); f4v g11 = *(const f4v*)(n2g + lane * 8 + 4);
    f4v b10 = *(const f4v*)(n2b + lane * 8); f4v b11 = *(const f4v*)(n2b + lane * 8 + 4);
    float t[8]; s = 0.f; s2 = 0.f;
#pragma unroll
    for (int j = 0; j < 8; j++) {
        const float gg = j < 4 ? g10[j] : g11[j - 4];
        const float bb = j < 4 ? b10[j] : b11[j - 4];
        t[j] = (x[j] - mu) * rs * gg + bb;
        s += t[j]; s2 += t[j] * t[j];
    }
#pragma unroll
    for (int o = 32; o >= 1; o >>= 1) { s += __shfl_xor(s, o); s2 += __shfl_xor(s2, o); }
    mu = s * (1.f / 512.f);
    rs = rsqrtf(s2 * (1.f / 512.f) - mu * mu + 1e-5f);
    f4v g20 = *(const f4v*)(og + lane * 8); f4v g21 = *(const f4v*)(og + lane * 8 + 4);
    f4v b20 = *(const f4v*)(ob + lane * 8); f4v b21 = *(const f4v*)(ob + lane * 8 + 4);
    s8v bs = *(const s8v*)(base + off);
    const float gm = 1.f / (1.f + expf(-gml[0]));
    s8v o;
#pragma unroll
    for (int j = 0; j < 8; j++) {
        const float gg = j < 4 ? g20[j] : g21[j - 4];
        const float bb = j < 4 ? b20[j] : b21[j - 4];
        const float u = (t[j] - mu) * rs * gg + bb;
        const float bsv = bv(bs, j);
        o[j] = (short)f2b(bsv + gm * (u - bsv));
    }
    *(s8v*)(fio + off) = o;
}

// ---------------------------------------------------------------------------
// column sum of final bf16 x: deterministic two-stage, zero atomics.
// stage 1: 512 blocks; block b accumulates rows b, b+512, ... (2 cols/thread)
// ---------------------------------------------------------------------------
__global__ __launch_bounds__(256) void k_colsum(const u16* __restrict__ x,
                                                float* __restrict__ partial, int N) {
    const int b = blockIdx.x, t = threadIdx.x;
    float s0 = 0.f, s1 = 0.f;
    for (int r = b; r < N; r += gridDim.x) {
        const u32 v = *(const u32*)(x + (long)r * 512 + 2 * t);
        s0 += b2f((u16)(v & 0xFFFFu));
        s1 += b2f((u16)(v >> 16));
    }
    partial[(long)b * 512 + 2 * t]     = s0;
    partial[(long)b * 512 + 2 * t + 1] = s1;
}

__global__ void k_emit(const u16* __restrict__ xout, void* __restrict__ dout, long n,
                       const int* __restrict__ flags) {
    const int isbf = flags[0];
    const long t = ((long)blockIdx.x * 256 + threadIdx.x) * 8;
    if (t >= n) return;
    s8v v = *(const s8v*)(xout + t);
    if (isbf) {
        *(s8v*)((u16*)dout + t) = v;
    } else {
        f4v o0, o1;
#pragma unroll
        for (int j = 0; j < 4; j++) { o0[j] = bv(v, j); o1[j] = bv(v, 4 + j); }
        *(f4v*)((float*)dout + t) = o0;
        *(f4v*)((float*)dout + t + 4) = o1;
    }
}

// stage 2 + pooled: PARALLEL reduce of 512 partial rows (one block per column)
// + doc-mix with x[0].
__global__ __launch_bounds__(256) void k_pooled(const u16* __restrict__ xout,
                                                const float* __restrict__ partial,
                                                const float* __restrict__ dml,
                                                void* __restrict__ dout,
                                                long pool_off, int N,
                                                const int* __restrict__ flags) {
    __shared__ float ws[4];
    const int c = blockIdx.x;     // 512 columns
    const int t = threadIdx.x;    // 256 threads: 2 partials each
    float s = partial[(long)t * 512 + c] + partial[(long)(t + 256) * 512 + c];
#pragma unroll
    for (int o = 32; o >= 1; o >>= 1) s += __shfl_xor(s, o);
    if ((t & 63) == 0) ws[t >> 6] = s;
    __syncthreads();
    if (t == 0) {
        const float cs = ws[0] + ws[1] + ws[2] + ws[3];
        const float dm = 1.f / (1.f + expf(-dml[0]));
        const float v = dm * b2f(xout[c]) + (1.f - dm) * (cs / (float)N);
        if (flags[0]) ((u16*)dout)[pool_off + c] = f2b(v);
        else          ((float*)dout)[pool_off + c] = v;
    }
}

// ---------------------------------------------------------------------------
extern "C" void kernel_launch(void* const* d_in, const int* in_sizes, int n_in,
                              void* d_out, int out_size, void* d_ws, size_t ws_size,
                              hipStream_t stream) {
    const void* nf    = d_in[0];
    const void* EI    = d_in[1];
    const void* ET    = d_in[2];
    const void* NT    = d_in[3];
    const void* EW    = d_in[4];
    const void* NTE   = d_in[5];
    const void* Wself = d_in[6];
    const void* bself = d_in[7];
    const void* Wrel  = d_in[8];
    const void* brel  = d_in[9];
    const void* ing   = d_in[10];
    const void* inb   = d_in[11];
    const void* n1g   = d_in[12];
    const void* n1b   = d_in[13];
    const void* Wf1   = d_in[14];
    const void* bf1   = d_in[15];
    const void* Wf2   = d_in[16];
    const void* bf2   = d_in[17];
    const void* n2g   = d_in[18];
    const void* n2b   = d_in[19];
    const void* outg  = d_in[20];
    const void* outb  = d_in[21];
    const void* gml   = d_in[22];
    const void* dml   = d_in[23];

    const int N = in_sizes[0] / 512;     // 50000
    const int E = in_sizes[2];           // 100000

    const size_t ND2 = (size_t)N * 512 * 2;
    const size_t ND4 = (size_t)N * 512 * 4;
    const size_t arena_elems = (size_t)E + 2048 + 512 * 10 + 1024 + 2;
    const size_t arena_bytes = arena_elems * 4;
    // bf16 weight buffers: Wrel(4*512*512) + Wself(512*512) + Wf1(1024*512) + Wf2(512*1024)
    const size_t WRELN = 4ull * 512 * 512, WSELFN = 512ull * 512;
    const size_t WF1N = 1024ull * 512, WF2N = 512ull * 1024;
    const size_t WBFB = (WRELN + WSELFN + WF1N + WF2N) * 2;   // bytes
    const int NPART = 512;
    const size_t partB = (size_t)NPART * 512 * 4;             // 1 MB partial colsums

    // fast path: base + Y4[N,2048]bf16 + S + CSR + misc + bf16 weights
    const size_t Y4B = (size_t)N * 2048 * 2;
    const size_t csrB = (size_t)(N + 1) * 4 + (size_t)N * 4 + (size_t)(2 * E) * 4 * 2;
    const size_t need_fast = ND2 + Y4B + ND2 + csrB + partB + 64 + WBFB + arena_bytes;
    // slow path (r3-proven): base + agg f32 + Ybuf + deg/partial/flags + weights + arena
    const size_t need_slow = ND2 + ND4 + ND2 + (size_t)N * 4 + partB + 64 + WBFB + arena_bytes;

    const int rowBlocks = (N + 3) / 4;
    const int Mt = (N + 127) / 128;
    const dim3 g512(512 / 128, Mt);
    const dim3 g1024(1024 / 128, Mt);
    const dim3 g2048(2048 / 128, Mt);

    if (ws_size >= need_fast) {
        // ------------------- FAST PATH: CSR gather -------------------
        char* p = (char*)d_ws;
        u16*   base   = (u16*)p;                         // ND2
        u16*   Y4     = (u16*)(p + ND2);                 // Y4B; later aliased by mid
        u16*   mid    = Y4;                              // FFN hidden [N,1024] bf16
        u16*   Sbuf   = (u16*)(p + ND2 + Y4B);           // ND2: S, later ffn_out/final x
        char*  q      = p + ND2 + Y4B + ND2;
        u32*   indptr = (u32*)q;                 q += (size_t)(N + 1) * 4;
        u32*   cursor = (u32*)q;                 q += (size_t)N * 4;   // also cnt
        u32*   srcrel = (u32*)q;                 q += (size_t)(2 * E) * 4;
        float* wts    = (float*)q;               q += (size_t)(2 * E) * 4;
        float* partial= (float*)q;               q += partB;
        int*   flags  = (int*)q;                 q += 64;
        u16*   wrelc  = (u16*)q;                 q += WRELN * 2;
        u16*   wselfc = (u16*)q;                 q += WSELFN * 2;
        u16*   wf1c   = (u16*)q;                 q += WF1N * 2;
        u16*   wf2c   = (u16*)q;                 q += WF2N * 2;
        float* arena  = (float*)q;
        float* EWc   = arena;
        float* brelc = EWc + E;
        float* bselfc= brelc + 2048;
        float* ingc  = bselfc + 512;
        float* inbc  = ingc + 512;
        float* n1gc  = inbc + 512;
        float* n1bc  = n1gc + 512;
        float* bf1c  = n1bc + 512;
        float* bf2c  = bf1c + 1024;
        float* n2gc  = bf2c + 512;
        float* n2bc  = n2gc + 512;
        float* outgc = n2bc + 512;
        float* outbc = outgc + 512;
        float* gmlc  = outbc + 512;
        float* dmlc  = gmlc + 1;
        u16* x1 = (u16*)d_out;          // bf16 intermediate; overwritten by k_emit

        k_detect<<<1, 256, 0, stream>>>((const u16*)nf, (const u32*)EI, flags);
        hipMemsetAsync(cursor, 0, (size_t)N * 4, stream);   // cnt

        auto cvt = [&](const void* s, float* d, int n) {
            k_cvt<<<(n + 255) / 256, 256, 0, stream>>>(s, d, n, flags);
        };
        auto cvt16 = [&](const void* s, u16* d, int n) {
            k_cvt16<<<(n + 255) / 256, 256, 0, stream>>>(s, d, n, flags);
        };
        cvt(EW, EWc, E);        cvt(brel, brelc, 2048);  cvt(bself, bselfc, 512);
        cvt(ing, ingc, 512);    cvt(inb, inbc, 512);     cvt(n1g, n1gc, 512);
        cvt(n1b, n1bc, 512);    cvt(bf1, bf1c, 1024);    cvt(bf2, bf2c, 512);
        cvt(n2g, n2gc, 512);    cvt(n2b, n2bc, 512);     cvt(outg, outgc, 512);
        cvt(outb, outbc, 512);  cvt(gml, gmlc, 1);       cvt(dml, dmlc, 1);
        cvt16(Wrel, wrelc, (int)WRELN);   cvt16(Wself, wselfc, (int)WSELFN);
        cvt16(Wf1, wf1c, (int)WF1N);      cvt16(Wf2, wf2c, (int)WF2N);

        k_innorm<<<rowBlocks, 256, 0, stream>>>(nf, NT, NTE, ingc, inbc, base, N, flags);
        // CSR build
        k_count<<<(2 * E + 255) / 256, 256, 0, stream>>>(EI, cursor, E, flags);
        k_scan<<<1, 1024, 0, stream>>>(cursor, indptr, N);
        k_copy32<<<(N + 255) / 256, 256, 0, stream>>>(indptr, cursor, N);
        k_fill<<<(2 * E + 255) / 256, 256, 0, stream>>>(EI, ET, EWc, cursor, srcrel, wts, E, flags);
        // transforms: Y4 = base @ Wrel_cat^T   ;   S = base @ Wself^T
        gemm_bt<0><<<g2048, 256, 0, stream>>>(base, wrelc, nullptr, Y4, N, 2048, 512);
        gemm_bt<0><<<g512, 256, 0, stream>>>(base, wselfc, nullptr, Sbuf, N, 512, 512);
        // fused gather + n1
        k_gather_n1<<<rowBlocks, 256, 0, stream>>>(indptr, srcrel, wts, Y4, Sbuf, base,
                                                   brelc, bselfc, n1gc, n1bc, x1, N);
        // FFN (mid aliases Y4, which is dead now; ffn_out into Sbuf, dead too)
        gemm_bt<1><<<g1024, 256, 0, stream>>>(x1, wf1c, bf1c, mid, N, 1024, 512);
        gemm_bt<0><<<g512, 256, 0, stream>>>(mid, wf2c, bf2c, Sbuf, N, 512, 1024);

        k_final<<<rowBlocks, 256, 0, stream>>>(x1, Sbuf, base, n2gc, n2bc, outgc, outbc,
                                               gmlc, N);
        k_colsum<<<NPART, 256, 0, stream>>>(Sbuf, partial, N);
        k_emit<<<(int)(((long)N * 512 / 8 + 255) / 256), 256, 0, stream>>>(Sbuf, d_out,
                                                                           (long)N * 512, flags);
        k_pooled<<<512, 256, 0, stream>>>(Sbuf, partial, dmlc, d_out, (long)N * 512, N, flags);

    } else if (ws_size >= need_slow) {
        // ------------------- SLOW PATH (r3-proven) -------------------
        char* p = (char*)d_ws;
        u16*   base = (u16*)p;
        float* agg  = (float*)(p + ND2);
        u16*   mid  = (u16*)(p + ND2);
        u16*   Ybuf = (u16*)(p + ND2 + ND4);
        float* deg  = (float*)(p + ND2 + ND4 + ND2);
        float* partial = deg + N;
        int*   flags  = (int*)(partial + NPART * 512);
        char*  q2     = (char*)flags + 64;
        u16*   wrelc  = (u16*)q2;                q2 += WRELN * 2;
        u16*   wselfc = (u16*)q2;                q2 += WSELFN * 2;
        u16*   wf1c   = (u16*)q2;                q2 += WF1N * 2;
        u16*   wf2c   = (u16*)q2;                q2 += WF2N * 2;
        float* arena  = (float*)q2;
        float* EWc   = arena;
        float* brelc = EWc + E;
        float* bselfc= brelc + 2048;
        float* ingc  = bselfc + 512;
        float* inbc  = ingc + 512;
        float* n1gc  = inbc + 512;
        float* n1bc  = n1gc + 512;
        float* bf1c  = n1bc + 512;
        float* bf2c  = bf1c + 1024;
        float* n2gc  = bf2c + 512;
        float* n2bc  = n2gc + 512;
        float* outgc = n2bc + 512;
        float* outbc = outgc + 512;
        float* gmlc  = outbc + 512;
        float* dmlc  = gmlc + 1;
        u16* x1 = (u16*)d_out;

        k_detect<<<1, 256, 0, stream>>>((const u16*)nf, (const u32*)EI, flags);
        hipMemsetAsync(agg, 0, ND4, stream);
        hipMemsetAsync(deg, 0, (size_t)N * 4, stream);

        auto cvt = [&](const void* s, float* d, int n) {
            k_cvt<<<(n + 255) / 256, 256, 0, stream>>>(s, d, n, flags);
        };
        auto cvt16 = [&](const void* s, u16* d, int n) {
            k_cvt16<<<(n + 255) / 256, 256, 0, stream>>>(s, d, n, flags);
        };
        cvt(EW, EWc, E);        cvt(brel, brelc, 2048);  cvt(bself, bselfc, 512);
        cvt(ing, ingc, 512);    cvt(inb, inbc, 512);     cvt(n1g, n1gc, 512);
        cvt(n1b, n1bc, 512);    cvt(bf1, bf1c, 1024);    cvt(bf2, bf2c, 512);
        cvt(n2g, n2gc, 512);    cvt(n2b, n2bc, 512);     cvt(outg, outgc, 512);
        cvt(outb, outbc, 512);  cvt(gml, gmlc, 1);       cvt(dml, dmlc, 1);
        cvt16(Wrel, wrelc, (int)WRELN);   cvt16(Wself, wselfc, (int)WSELFN);
        cvt16(Wf1, wf1c, (int)WF1N);      cvt16(Wf2, wf2c, (int)WF2N);

        k_innorm<<<rowBlocks, 256, 0, stream>>>(nf, NT, NTE, ingc, inbc, base, N, flags);
        k_deg<<<(2 * E + 255) / 256, 256, 0, stream>>>(EI, EWc, deg, E, flags);

        for (int r = 0; r < 4; r++) {
            gemm_bt<0><<<g512, 256, 0, stream>>>(base, wrelc + (size_t)r * 512 * 512, nullptr,
                                                 Ybuf, N, 512, 512);
            k_scatter<<<(2 * E + 3) / 4, 256, 0, stream>>>(EI, ET, EWc, Ybuf, brelc, agg,
                                                           E, r, flags);
        }

        gemm_bt<0><<<g512, 256, 0, stream>>>(base, wselfc, nullptr, Ybuf, N, 512, 512);
        k_n1<<<rowBlocks, 256, 0, stream>>>(Ybuf, agg, deg, bselfc, base, n1gc, n1bc, x1, N);

        gemm_bt<1><<<g1024, 256, 0, stream>>>(x1, wf1c, bf1c, mid, N, 1024, 512);
        gemm_bt<0><<<g512, 256, 0, stream>>>(mid, wf2c, bf2c, Ybuf, N, 512, 1024);

        k_final<<<rowBlocks, 256, 0, stream>>>(x1, Ybuf, base, n2gc, n2bc, outgc, outbc,
                                               gmlc, N);
        k_colsum<<<NPART, 256, 0, stream>>>(Ybuf, partial, N);
        k_emit<<<(int)(((long)N * 512 / 8 + 255) / 256), 256, 0, stream>>>(Ybuf, d_out,
                                                                           (long)N * 512, flags);
        k_pooled<<<512, 256, 0, stream>>>(Ybuf, partial, dmlc, d_out, (long)N * 512, N, flags);
    } else {
        const float val = 2000.f + (float)(ws_size >> 20);
        k_diag<<<(out_size + 255) / 256, 256, 0, stream>>>((u16*)d_out, out_size, val);
    }
}

// Round 9
// 796.320 us; speedup vs baseline: 1.4605x; 1.1359x over previous
//
#include <hip/hip_runtime.h>
#include <hip/hip_bf16.h>

typedef __attribute__((ext_vector_type(8))) short s8v;   // 8 x bf16 (as i16 bits)
typedef __attribute__((ext_vector_type(4))) short s4v;   // 4 x bf16 (8B)
typedef __attribute__((ext_vector_type(4))) float f4v;
typedef unsigned short u16;
typedef unsigned int u32;

__device__ __forceinline__ float b2f(u16 u) {
    union { unsigned int i; float f; } v; v.i = ((unsigned int)u) << 16; return v.f;
}
__device__ __forceinline__ u16 f2b(float f) {
    union { float f; unsigned int i; } v; v.f = f;
    unsigned int r = v.i + 0x7FFFu + ((v.i >> 16) & 1u);  // round-nearest-even
    return (u16)(r >> 16);
}
__device__ __forceinline__ float bv(const s8v& s, int j) { return b2f((u16)s[j]); }
// integer load valid for int32 or int64 (low word) storage
__device__ __forceinline__ int geti(const void* p, long i, int i64) {
    return i64 ? (int)((const u32*)p)[2 * i] : ((const int*)p)[i];
}

// async global -> LDS, 16 bytes per lane (linear LDS dest: uniform base + lane*16)
__device__ __forceinline__ void ld16(const u16* g, u16* l) {
    __builtin_amdgcn_global_load_lds(
        (const __attribute__((address_space(1))) unsigned int*)g,
        (__attribute__((address_space(3))) unsigned int*)l, 16, 0, 0);
}

// ---------------------------------------------------------------------------
// dtype detector: flags[0]=1 floats are bf16 (else f32); flags[1]=1 ints int64.
// ---------------------------------------------------------------------------
__global__ void k_detect(const u16* __restrict__ nf, const u32* __restrict__ EI,
                         int* __restrict__ flags) {
    __shared__ int cnt, nz;
    if (threadIdx.x == 0) { cnt = 0; nz = 0; }
    __syncthreads();
    int c = 0;
    for (int i = threadIdx.x; i < 4096; i += 256) {
        u16 v = nf[2 * i];
        int e = (v >> 7) & 0xFF;
        if (e >= 64 && e < 160) c++;
    }
    atomicAdd(&cnt, c);
    int z = 0;
    for (int i = threadIdx.x; i < 4096; i += 256)
        if (EI[2 * i + 1] != 0) z++;
    atomicAdd(&nz, z);
    __syncthreads();
    if (threadIdx.x == 0) { flags[0] = (cnt >= 2867) ? 1 : 0; flags[1] = (nz == 0) ? 1 : 0; }
}

// ---------------------------------------------------------------------------
// fused parameter-conversion: ONE launch replaces 19 tiny cvt kernels
// (launch-overhead-bound: ~3us each serialized in the capture graph).
// ---------------------------------------------------------------------------
#define MAXJOBS 20
struct CvtJobs {
    const void* src[MAXJOBS];
    void* dst[MAXJOBS];
    int n[MAXJOBS];
    int kind[MAXJOBS];     // 0: f32 out, 1: bf16 out
    int bstart[MAXJOBS + 1];
    int njobs;
};

__global__ __launch_bounds__(256) void k_cvt_all(CvtJobs J, const int* __restrict__ flags) {
    const int isbf = flags[0];
    const int b = blockIdx.x;
    int j = 0;
    while (j + 1 < J.njobs && b >= J.bstart[j + 1]) j++;
    const int t = (b - J.bstart[j]) * 256 + threadIdx.x;
    if (t >= J.n[j]) return;
    if (J.kind[j] == 0)
        ((float*)J.dst[j])[t] = isbf ? b2f(((const u16*)J.src[j])[t]) : ((const float*)J.src[j])[t];
    else
        ((u16*)J.dst[j])[t] = isbf ? ((const u16*)J.src[j])[t] : f2b(((const float*)J.src[j])[t]);
}

__global__ void k_diag(u16* __restrict__ out, int n, float val) {
    int t = blockIdx.x * 256 + threadIdx.x;
    if (t < n) out[t] = f2b(val);
}

// ---------------------------------------------------------------------------
// GEMM: C[M,Nn] = A[M,K] @ B[Nn,K]^T (+bias f32, optional exact gelu)
// 128x128 tile, BK=64, 4 waves (2x2), 64 KiB double-buffered LDS ->
// two blocks resident per CU (inter-block overlap of barrier drains) on top
// of counted-vmcnt loads-in-flight. vmcnt(8): in-order VMEM retirement, each
// thread issues 8/K-tile => <=8 outstanding means prior tile landed.
// LDS slot-XOR swizzle both-sides (linear gload_lds dest + inverse-swizzled
// global src + swizzled ds_read). Epilogue: swapped-operand MFMA -> LDS
// C-stage -> 64B coalesced stores. XCD-aware bijective block swizzle.
// Nn multiple of 128, K multiple of 64. M tail clamped on load, guarded store.
// ---------------------------------------------------------------------------
template<int GELU>
__global__ __launch_bounds__(256) void gemm_bt(const u16* __restrict__ A,
                                               const u16* __restrict__ B,
                                               const float* __restrict__ bias,
                                               u16* __restrict__ C,
                                               int M, int Nn, int K) {
    __shared__ u16 lds[2][2][128 * 64];   // [buf][A=0/B=1][128 rows][64 cols] = 64 KiB
    const int t = threadIdx.x;            // 0..255
    const int lane = t & 63;
    const int quad = lane >> 4;
    const int l16  = lane & 15;
    const int wid  = t >> 6;
    const int wm = wid >> 1, wn = wid & 1;   // 2 x 2 wave grid

    // ---- XCD-aware bijective swizzle ----
    const int nwg  = gridDim.x * gridDim.y;
    const int orig = blockIdx.y * gridDim.x + blockIdx.x;
    const int xcd  = orig & 7;
    const int qq   = nwg >> 3, rr = nwg & 7;
    const int base_l = (xcd < rr) ? xcd * (qq + 1) : rr * (qq + 1) + (xcd - rr) * qq;
    const int logical = base_l + (orig >> 3);
    const long m0 = (long)(logical / gridDim.x) * 128;
    const long n0 = (long)(logical % gridDim.x) * 128;

    // ---- staging geometry: per K-tile 8 issues (4 A + 4 B), 256 thr x 16B ----
    const int srow = t >> 3;
    const int sl   = (t & 7) ^ (srow & 7);
    long aoff[4], boff[4];
#pragma unroll
    for (int q = 0; q < 4; q++) {
        long ra = m0 + q * 32 + srow; if (ra >= M) ra = M - 1;  // clamp; stores guarded
        aoff[q] = ra * (long)K + sl * 8;
        long rb = n0 + q * 32 + srow;                            // Nn multiple of 128
        boff[q] = rb * (long)K + sl * 8;
    }

    f4v acc[4][4] = {};
    const int NT = K >> 6;

    // prologue: stage tile 0 into buf 0
    {
        u16* la = &lds[0][0][0] + t * 8;
        u16* lb = &lds[0][1][0] + t * 8;
#pragma unroll
        for (int q = 0; q < 4; q++) ld16(A + aoff[q], la + q * 2048);
#pragma unroll
        for (int q = 0; q < 4; q++) ld16(B + boff[q], lb + q * 2048);
    }

    for (int kt = 0; kt < NT; kt++) {
        const int cur = kt & 1;
        if (kt + 1 < NT) {
            const long kc = (long)(kt + 1) * 64;
            u16* la = &lds[cur ^ 1][0][0] + t * 8;
            u16* lb = &lds[cur ^ 1][1][0] + t * 8;
#pragma unroll
            for (int q = 0; q < 4; q++) ld16(A + aoff[q] + kc, la + q * 2048);
#pragma unroll
            for (int q = 0; q < 4; q++) ld16(B + boff[q] + kc, lb + q * 2048);
            __builtin_amdgcn_sched_barrier(0);
            asm volatile("s_waitcnt vmcnt(8)");   // newest 8 (next tile) keep flying
        } else {
            __builtin_amdgcn_sched_barrier(0);
            asm volatile("s_waitcnt vmcnt(0)");   // tail: drain
        }
        __builtin_amdgcn_sched_barrier(0);
        __builtin_amdgcn_s_barrier();             // cur tile staged by ALL waves
        __builtin_amdgcn_sched_barrier(0);

        const u16* LA = &lds[cur][0][0];
        const u16* LB = &lds[cur][1][0];
        s8v bf[4][2];
#pragma unroll
        for (int j = 0; j < 4; j++) {
            const int row = wn * 64 + j * 16 + l16;
#pragma unroll
            for (int ks = 0; ks < 2; ks++)
                bf[j][ks] = *(const s8v*)(LB + row * 64 + ((ks * 4 + quad) ^ (row & 7)) * 8);
        }
        __builtin_amdgcn_s_setprio(1);
#pragma unroll
        for (int i = 0; i < 4; i++) {
            const int row = wm * 64 + i * 16 + l16;
            s8v af0 = *(const s8v*)(LA + row * 64 + ((quad) ^ (row & 7)) * 8);
            s8v af1 = *(const s8v*)(LA + row * 64 + ((4 + quad) ^ (row & 7)) * 8);
#pragma unroll
            for (int j = 0; j < 4; j++) {
                acc[i][j] = __builtin_amdgcn_mfma_f32_16x16x32_bf16(bf[j][0], af0, acc[i][j], 0, 0, 0);
                acc[i][j] = __builtin_amdgcn_mfma_f32_16x16x32_bf16(bf[j][1], af1, acc[i][j], 0, 0, 0);
            }
        }
        __builtin_amdgcn_s_setprio(0);
        asm volatile("s_waitcnt lgkmcnt(0)");     // all LDS reads of cur complete
        __builtin_amdgcn_sched_barrier(0);
        __builtin_amdgcn_s_barrier();             // WAR: next iter's stage overwrites cur^1
        __builtin_amdgcn_sched_barrier(0);
    }
    // swapped layout: m = wm*64+i*16+l16 (row), n = wn*64+j*16+quad*4+r (col)

    // ---- epilogue stage 1: bias/gelu, pack 4 cols -> b64 LDS write ----
    u16* cs = &lds[0][0][0];                      // reuse as [128][128] bf16 = 32 KiB
#pragma unroll
    for (int j = 0; j < 4; j++) {
        const long ncol = n0 + wn * 64 + j * 16 + quad * 4;
        f4v bb = {0.f, 0.f, 0.f, 0.f};
        if (bias) bb = *(const f4v*)(bias + ncol);
#pragma unroll
        for (int i = 0; i < 4; i++) {
            const int row_local = wm * 64 + i * 16 + l16;
            const int ch = (wn * 16 + j * 4 + quad) ^ (row_local & 14);
            s4v pk;
#pragma unroll
            for (int r = 0; r < 4; r++) {
                float v = acc[i][j][r] + bb[r];
                if (GELU) v = 0.5f * v * (1.f + erff(v * 0.70710678118654752f));
                pk[r] = (short)f2b(v);
            }
            *(s4v*)(cs + row_local * 128 + ch * 4) = pk;
        }
    }
    __syncthreads();

    // ---- epilogue stage 2: coalesced copy-out, 64B per 4-lane group ----
    const int q4 = t & 3;
#pragma unroll
    for (int pass = 0; pass < 2; pass++) {
        const int row = pass * 64 + (t >> 2);
        const long grow = m0 + row;
        if (grow < M) {
            const u16* lrow = cs + row * 128;
            const int s = row & 14;
#pragma unroll
            for (int k = 0; k < 4; k++) {
                const int c0 = (q4 * 2 + k * 8) ^ s;   // even -> 16B aligned
                s8v v = *(const s8v*)(lrow + c0 * 4);
                *(s8v*)(C + grow * (long)Nn + n0 + q4 * 8 + k * 32) = v;
            }
        }
    }
}

// ---------------------------------------------------------------------------
// input norm: base = LN(nf + nte[node_type]) * g + b   (one wave per row)
// ---------------------------------------------------------------------------
__global__ __launch_bounds__(256) void k_innorm(const void* __restrict__ nf,
                                                const void* __restrict__ ntype,
                                                const void* __restrict__ nte,
                                                const float* __restrict__ g,
                                                const float* __restrict__ b,
                                                u16* __restrict__ base, int N,
                                                const int* __restrict__ flags) {
    const int isbf = flags[0], i64 = flags[1];
    const int wave = threadIdx.x >> 6, lane = threadIdx.x & 63;
    const int row = blockIdx.x * 4 + wave;
    if (row >= N) return;
    const long off = (long)row * 512 + lane * 8;
    const int nt = geti(ntype, row, i64);
    const long eoff = (long)nt * 512 + lane * 8;
    float x[8];
    if (isbf) {
        s8v xv = *(const s8v*)((const u16*)nf + off);
        s8v ev = *(const s8v*)((const u16*)nte + eoff);
#pragma unroll
        for (int j = 0; j < 8; j++) x[j] = bv(xv, j) + bv(ev, j);
    } else {
        f4v x0 = *(const f4v*)((const float*)nf + off);
        f4v x1 = *(const f4v*)((const float*)nf + off + 4);
        f4v e0 = *(const f4v*)((const float*)nte + eoff);
        f4v e1 = *(const f4v*)((const float*)nte + eoff + 4);
#pragma unroll
        for (int j = 0; j < 4; j++) { x[j] = x0[j] + e0[j]; x[4 + j] = x1[j] + e1[j]; }
    }
    float s = 0.f, s2 = 0.f;
#pragma unroll
    for (int j = 0; j < 8; j++) { s += x[j]; s2 += x[j] * x[j]; }
#pragma unroll
    for (int o = 32; o >= 1; o >>= 1) { s += __shfl_xor(s, o); s2 += __shfl_xor(s2, o); }
    const float mu = s * (1.f / 512.f);
    const float rs = rsqrtf(s2 * (1.f / 512.f) - mu * mu + 1e-5f);
    f4v g0 = *(const f4v*)(g + lane * 8); f4v g1 = *(const f4v*)(g + lane * 8 + 4);
    f4v b0 = *(const f4v*)(b + lane * 8); f4v b1 = *(const f4v*)(b + lane * 8 + 4);
    s8v o;
#pragma unroll
    for (int j = 0; j < 8; j++) {
        const float gg = j < 4 ? g0[j] : g1[j - 4];
        const float bb = j < 4 ? b0[j] : b1[j - 4];
        o[j] = (short)f2b((x[j] - mu) * rs * gg + bb);
    }
    *(s8v*)(base + off) = o;
}

// ===========================================================================
// FAST PATH: CSR build + gather (no feature atomics)
// ===========================================================================
__global__ __launch_bounds__(256) void k_count(const void* __restrict__ EI,
                                               u32* __restrict__ cnt, int E,
                                               const int* __restrict__ flags) {
    const int i64 = flags[1];
    const int t = blockIdx.x * 256 + threadIdx.x;
    if (t >= 2 * E) return;
    const int ed = (t < E) ? t : t - E;
    const int dst = (t < E) ? geti(EI, E + ed, i64) : geti(EI, ed, i64);
    atomicAdd(&cnt[dst], 1u);
}

// ---------------------------------------------------------------------------
// parallel 3-stage exclusive scan (replaces the single-workgroup k_scan,
// which serialized 49 chunks x 10 rounds on one CU ~40-60us).
// scan1: per-chunk local exclusive scan into indptr + chunk totals.
// scan2: one block scans <=1024 chunk totals (exclusive) + writes total.
// scan3: add chunk offsets; writes indptr AND cursor; i==0 writes indptr[N].
// ---------------------------------------------------------------------------
__global__ __launch_bounds__(1024) void k_scan1(const u32* __restrict__ cnt,
                                                u32* __restrict__ lexcl,
                                                u32* __restrict__ sums, int N) {
    __shared__ u32 buf[1024];
    const int i = blockIdx.x * 1024 + threadIdx.x;
    const u32 v = (i < N) ? cnt[i] : 0u;
    buf[threadIdx.x] = v;
    __syncthreads();
    for (int o = 1; o < 1024; o <<= 1) {
        u32 tv = (threadIdx.x >= (u32)o) ? buf[threadIdx.x - o] : 0u;
        __syncthreads();
        buf[threadIdx.x] += tv;
        __syncthreads();
    }
    if (i < N) lexcl[i] = buf[threadIdx.x] - v;
    if (threadIdx.x == 1023) sums[blockIdx.x] = buf[1023];
}

__global__ __launch_bounds__(1024) void k_scan2(const u32* __restrict__ sums,
                                                u32* __restrict__ offs, int nch) {
    __shared__ u32 buf[1024];
    const u32 v = (threadIdx.x < (u32)nch) ? sums[threadIdx.x] : 0u;
    buf[threadIdx.x] = v;
    __syncthreads();
    for (int o = 1; o < 1024; o <<= 1) {
        u32 tv = (threadIdx.x >= (u32)o) ? buf[threadIdx.x - o] : 0u;
        __syncthreads();
        buf[threadIdx.x] += tv;
        __syncthreads();
    }
    if (threadIdx.x < (u32)nch) offs[threadIdx.x] = buf[threadIdx.x] - v;
    if (threadIdx.x == (u32)(nch - 1)) offs[nch] = buf[threadIdx.x];   // total
}

__global__ __launch_bounds__(256) void k_scan3(u32* __restrict__ indptr,
                                               const u32* __restrict__ offs,
                                               u32* __restrict__ cursor, int N, int nch) {
    const int i = blockIdx.x * 256 + threadIdx.x;
    if (i < N) {
        const u32 v = indptr[i] + offs[i >> 10];
        indptr[i] = v;
        cursor[i] = v;
    }
    if (i == 0) indptr[N] = offs[nch];
}

__global__ __launch_bounds__(256) void k_fill(const void* __restrict__ EI,
                                              const void* __restrict__ ET,
                                              const float* __restrict__ EW,
                                              u32* __restrict__ cursor,
                                              u32* __restrict__ srcrel,
                                              float* __restrict__ wts, int E,
                                              const int* __restrict__ flags) {
    const int i64 = flags[1];
    const int t = blockIdx.x * 256 + threadIdx.x;
    if (t >= 2 * E) return;
    int ed, src, dst, r;
    if (t < E) { ed = t;     r = geti(ET, ed, i64);     src = geti(EI, ed, i64);     dst = geti(EI, E + ed, i64); }
    else       { ed = t - E; r = geti(ET, ed, i64) + 2; src = geti(EI, E + ed, i64); dst = geti(EI, ed, i64); }
    const u32 pos = atomicAdd(&cursor[dst], 1u);
    srcrel[pos] = (u32)src | ((u32)r << 28);
    wts[pos] = EW[ed];
}

// gather + n1 fused: x1 = LN(base + S + b_self + agg/max(deg,1)) * g + b
// agg[d] = sum_e w*(Y4[src, rel*512+c]) + sum_r wsum_r * brel[r][c]
__global__ __launch_bounds__(256) void k_gather_n1(const u32* __restrict__ indptr,
                                                   const u32* __restrict__ srcrel,
                                                   const float* __restrict__ wts,
                                                   const u16* __restrict__ Y4,   // [N,2048]
                                                   const u16* __restrict__ S,    // [N,512]
                                                   const u16* __restrict__ base,
                                                   const float* __restrict__ brel,  // [4,512]
                                                   const float* __restrict__ bself,
                                                   const float* __restrict__ g,
                                                   const float* __restrict__ b,
                                                   u16* __restrict__ x1, int N) {
    const int wave = threadIdx.x >> 6, lane = threadIdx.x & 63;
    const int row = blockIdx.x * 4 + wave;
    if (row >= N) return;
    const int colb = lane * 8;
    float acc[8] = {}; float wsum[4] = {};
    const u32 beg = indptr[row], end = indptr[row + 1];
    for (u32 i = beg; i < end; i++) {
        const u32 pr = srcrel[i];
        const int src = (int)(pr & 0x0FFFFFFFu);
        const int rel = (int)(pr >> 28);
        const float w = wts[i];
        s8v yv = *(const s8v*)(Y4 + (long)src * 2048 + rel * 512 + colb);
#pragma unroll
        for (int j = 0; j < 8; j++) acc[j] += w * bv(yv, j);
        wsum[rel] += w;
    }
    const float deg = wsum[0] + wsum[1] + wsum[2] + wsum[3];
    const float dmx = 1.f / fmaxf(deg, 1.f);
    const long off = (long)row * 512 + colb;
    s8v sv = *(const s8v*)(S + off);
    s8v bs = *(const s8v*)(base + off);
    f4v sb0 = *(const f4v*)(bself + colb);
    f4v sb1 = *(const f4v*)(bself + colb + 4);
    // bias contribution from each relation
    float x[8], s = 0.f, s2 = 0.f;
#pragma unroll
    for (int h = 0; h < 2; h++) {
        f4v br0 = *(const f4v*)(brel + 0 * 512 + colb + 4 * h);
        f4v br1 = *(const f4v*)(brel + 1 * 512 + colb + 4 * h);
        f4v br2 = *(const f4v*)(brel + 2 * 512 + colb + 4 * h);
        f4v br3 = *(const f4v*)(brel + 3 * 512 + colb + 4 * h);
#pragma unroll
        for (int q = 0; q < 4; q++) {
            const int j = h * 4 + q;
            const float bias4 = wsum[0] * br0[q] + wsum[1] * br1[q] + wsum[2] * br2[q] + wsum[3] * br3[q];
            const float sbv = h ? sb1[q] : sb0[q];
            x[j] = bv(bs, j) + bv(sv, j) + sbv + (acc[j] + bias4) * dmx;
            s += x[j]; s2 += x[j] * x[j];
        }
    }
#pragma unroll
    for (int o = 32; o >= 1; o >>= 1) { s += __shfl_xor(s, o); s2 += __shfl_xor(s2, o); }
    const float mu = s * (1.f / 512.f);
    const float rs = rsqrtf(s2 * (1.f / 512.f) - mu * mu + 1e-5f);
    f4v g0 = *(const f4v*)(g + colb); f4v g1 = *(const f4v*)(g + colb + 4);
    f4v b0 = *(const f4v*)(b + colb); f4v b1 = *(const f4v*)(b + colb + 4);
    s8v o;
#pragma unroll
    for (int j = 0; j < 8; j++) {
        const float gg = j < 4 ? g0[j] : g1[j - 4];
        const float bb = j < 4 ? b0[j] : b1[j - 4];
        o[j] = (short)f2b((x[j] - mu) * rs * gg + bb);
    }
    *(s8v*)(x1 + off) = o;
}

// ===========================================================================
// SLOW PATH kernels (proven r3 fallback): scatter with f32 atomics
// ===========================================================================
__global__ __launch_bounds__(256) void k_deg(const void* __restrict__ EI,
                                             const float* __restrict__ EW,
                                             float* __restrict__ deg, int E,
                                             const int* __restrict__ flags) {
    const int i64 = flags[1];
    const int t = blockIdx.x * 256 + threadIdx.x;
    if (t >= 2 * E) return;
    const int ed = (t < E) ? t : t - E;
    const int dst = (t < E) ? geti(EI, E + ed, i64) : geti(EI, ed, i64);
    atomicAdd(&deg[dst], EW[ed]);
}

__global__ __launch_bounds__(256) void k_scatter(const void* __restrict__ EI,
                                                 const void* __restrict__ ET,
                                                 const float* __restrict__ EW,
                                                 const u16* __restrict__ Y,
                                                 const float* __restrict__ brel,
                                                 float* __restrict__ agg, int E, int rel,
                                                 const int* __restrict__ flags) {
    const int i64 = flags[1];
    const int wave = threadIdx.x >> 6, lane = threadIdx.x & 63;
    const long eid = (long)blockIdx.x * 4 + wave;
    if (eid >= 2 * (long)E) return;
    int ed, src, dst, r;
    if (eid < E) { ed = (int)eid;       r = geti(ET, ed, i64);     src = geti(EI, ed, i64);     dst = geti(EI, E + ed, i64); }
    else         { ed = (int)(eid - E); r = geti(ET, ed, i64) + 2; src = geti(EI, E + ed, i64); dst = geti(EI, ed, i64); }
    if (r != rel) return;
    const float w = EW[ed];
    s8v yv = *(const s8v*)(Y + (long)src * 512 + lane * 8);
    const float* bb = brel + (long)rel * 512 + lane * 8;
    float* ag = agg + (long)dst * 512 + lane * 8;
#pragma unroll
    for (int j = 0; j < 8; j++) atomicAdd(ag + j, w * (bv(yv, j) + bb[j]));
}

__global__ __launch_bounds__(256) void k_n1(const u16* __restrict__ S,
                                            const float* __restrict__ agg,
                                            const float* __restrict__ deg,
                                            const float* __restrict__ bself,
                                            const u16* __restrict__ base,
                                            const float* __restrict__ g,
                                            const float* __restrict__ b,
                                            u16* __restrict__ x1, int N) {
    const int wave = threadIdx.x >> 6, lane = threadIdx.x & 63;
    const int row = blockIdx.x * 4 + wave;
    if (row >= N) return;
    const long off = (long)row * 512 + lane * 8;
    s8v sv = *(const s8v*)(S + off);
    s8v bs = *(const s8v*)(base + off);
    f4v a0 = *(const f4v*)(agg + off);
    f4v a1 = *(const f4v*)(agg + off + 4);
    f4v sb0 = *(const f4v*)(bself + lane * 8);
    f4v sb1 = *(const f4v*)(bself + lane * 8 + 4);
    const float dmx = 1.f / fmaxf(deg[row], 1.f);
    float x[8], s = 0.f, s2 = 0.f;
#pragma unroll
    for (int j = 0; j < 8; j++) {
        const float av = (j < 4 ? a0[j] : a1[j - 4]);
        const float sbv = (j < 4 ? sb0[j] : sb1[j - 4]);
        x[j] = bv(bs, j) + bv(sv, j) + sbv + av * dmx;
        s += x[j]; s2 += x[j] * x[j];
    }
#pragma unroll
    for (int o = 32; o >= 1; o >>= 1) { s += __shfl_xor(s, o); s2 += __shfl_xor(s2, o); }
    const float mu = s * (1.f / 512.f);
    const float rs = rsqrtf(s2 * (1.f / 512.f) - mu * mu + 1e-5f);
    f4v g0 = *(const f4v*)(g + lane * 8); f4v g1 = *(const f4v*)(g + lane * 8 + 4);
    f4v b0 = *(const f4v*)(b + lane * 8); f4v b1 = *(const f4v*)(b + lane * 8 + 4);
    s8v o;
#pragma unroll
    for (int j = 0; j < 8; j++) {
        const float gg = j < 4 ? g0[j] : g1[j - 4];
        const float bb = j < 4 ? b0[j] : b1[j - 4];
        o[j] = (short)f2b((x[j] - mu) * rs * gg + bb);
    }
    *(s8v*)(x1 + off) = o;
}

// ---------------------------------------------------------------------------
// final: two LNs + graph-mix; writes final x bf16 IN PLACE over fio.
// ---------------------------------------------------------------------------
__global__ __launch_bounds__(256) void k_final(const u16* __restrict__ x1,
                                               u16* fio,
                                               const u16* __restrict__ base,
                                               const float* __restrict__ n2g,
                                               const float* __restrict__ n2b,
                                               const float* __restrict__ og,
                                               const float* __restrict__ ob,
                                               const float* __restrict__ gml,
                                               int N) {
    const int wave = threadIdx.x >> 6, lane = threadIdx.x & 63;
    const int row = blockIdx.x * 4 + wave;
    if (row >= N) return;
    const long off = (long)row * 512 + lane * 8;
    s8v xv = *(const s8v*)(x1 + off);
    s8v fv = *(const s8v*)(fio + off);
    float x[8], s = 0.f, s2 = 0.f;
#pragma unroll
    for (int j = 0; j < 8; j++) { x[j] = bv(xv, j) + bv(fv, j); s += x[j]; s2 += x[j] * x[j]; }
#pragma unroll
    for (int o = 32; o >= 1; o >>= 1) { s += __shfl_xor(s, o); s2 += __shfl_xor(s2, o); }
    float mu = s * (1.f / 512.f);
    float rs = rsqrtf(s2 * (1.f / 512.f) - mu * mu + 1e-5f);
    f4v g10 = *(const f4v*)(n2g + lane * 8); f4v g11 = *(const f4v*)(n2g + lane * 8 + 4);
    f4v b10 = *(const f4v*)(n2b + lane * 8); f4v b11 = *(const f4v*)(n2b + lane * 8 + 4);
    float t[8]; s = 0.f; s2 = 0.f;
#pragma unroll
    for (int j = 0; j < 8; j++) {
        const float gg = j < 4 ? g10[j] : g11[j - 4];
        const float bb = j < 4 ? b10[j] : b11[j - 4];
        t[j] = (x[j] - mu) * rs * gg + bb;
        s += t[j]; s2 += t[j] * t[j];
    }
#pragma unroll
    for (int o = 32; o >= 1; o >>= 1) { s += __shfl_xor(s, o); s2 += __shfl_xor(s2, o); }
    mu = s * (1.f / 512.f);
    rs = rsqrtf(s2 * (1.f / 512.f) - mu * mu + 1e-5f);
    f4v g20 = *(const f4v*)(og + lane * 8); f4v g21 = *(const f4v*)(og + lane * 8 + 4);
    f4v b20 = *(const f4v*)(ob + lane * 8); f4v b21 = *(const f4v*)(ob + lane * 8 + 4);
    s8v bs = *(const s8v*)(base + off);
    const float gm = 1.f / (1.f + expf(-gml[0]));
    s8v o;
#pragma unroll
    for (int j = 0; j < 8; j++) {
        const float gg = j < 4 ? g20[j] : g21[j - 4];
        const float bb = j < 4 ? b20[j] : b21[j - 4];
        const float u = (t[j] - mu) * rs * gg + bb;
        const float bsv = bv(bs, j);
        o[j] = (short)f2b(bsv + gm * (u - bsv));
    }
    *(s8v*)(fio + off) = o;
}

// ---------------------------------------------------------------------------
// column sum of final bf16 x: deterministic two-stage, zero atomics.
// ---------------------------------------------------------------------------
__global__ __launch_bounds__(256) void k_colsum(const u16* __restrict__ x,
                                                float* __restrict__ partial, int N) {
    const int b = blockIdx.x, t = threadIdx.x;
    float s0 = 0.f, s1 = 0.f;
    for (int r = b; r < N; r += gridDim.x) {
        const u32 v = *(const u32*)(x + (long)r * 512 + 2 * t);
        s0 += b2f((u16)(v & 0xFFFFu));
        s1 += b2f((u16)(v >> 16));
    }
    partial[(long)b * 512 + 2 * t]     = s0;
    partial[(long)b * 512 + 2 * t + 1] = s1;
}

__global__ void k_emit(const u16* __restrict__ xout, void* __restrict__ dout, long n,
                       const int* __restrict__ flags) {
    const int isbf = flags[0];
    const long t = ((long)blockIdx.x * 256 + threadIdx.x) * 8;
    if (t >= n) return;
    s8v v = *(const s8v*)(xout + t);
    if (isbf) {
        *(s8v*)((u16*)dout + t) = v;
    } else {
        f4v o0, o1;
#pragma unroll
        for (int j = 0; j < 4; j++) { o0[j] = bv(v, j); o1[j] = bv(v, 4 + j); }
        *(f4v*)((float*)dout + t) = o0;
        *(f4v*)((float*)dout + t + 4) = o1;
    }
}

// stage 2 + pooled: PARALLEL reduce of 512 partial rows (one block per column)
__global__ __launch_bounds__(256) void k_pooled(const u16* __restrict__ xout,
                                                const float* __restrict__ partial,
                                                const float* __restrict__ dml,
                                                void* __restrict__ dout,
                                                long pool_off, int N,
                                                const int* __restrict__ flags) {
    __shared__ float ws[4];
    const int c = blockIdx.x;     // 512 columns
    const int t = threadIdx.x;    // 256 threads: 2 partials each
    float s = partial[(long)t * 512 + c] + partial[(long)(t + 256) * 512 + c];
#pragma unroll
    for (int o = 32; o >= 1; o >>= 1) s += __shfl_xor(s, o);
    if ((t & 63) == 0) ws[t >> 6] = s;
    __syncthreads();
    if (t == 0) {
        const float cs = ws[0] + ws[1] + ws[2] + ws[3];
        const float dm = 1.f / (1.f + expf(-dml[0]));
        const float v = dm * b2f(xout[c]) + (1.f - dm) * (cs / (float)N);
        if (flags[0]) ((u16*)dout)[pool_off + c] = f2b(v);
        else          ((float*)dout)[pool_off + c] = v;
    }
}

// ---------------------------------------------------------------------------
extern "C" void kernel_launch(void* const* d_in, const int* in_sizes, int n_in,
                              void* d_out, int out_size, void* d_ws, size_t ws_size,
                              hipStream_t stream) {
    const void* nf    = d_in[0];
    const void* EI    = d_in[1];
    const void* ET    = d_in[2];
    const void* NT    = d_in[3];
    const void* EW    = d_in[4];
    const void* NTE   = d_in[5];
    const void* Wself = d_in[6];
    const void* bself = d_in[7];
    const void* Wrel  = d_in[8];
    const void* brel  = d_in[9];
    const void* ing   = d_in[10];
    const void* inb   = d_in[11];
    const void* n1g   = d_in[12];
    const void* n1b   = d_in[13];
    const void* Wf1   = d_in[14];
    const void* bf1   = d_in[15];
    const void* Wf2   = d_in[16];
    const void* bf2   = d_in[17];
    const void* n2g   = d_in[18];
    const void* n2b   = d_in[19];
    const void* outg  = d_in[20];
    const void* outb  = d_in[21];
    const void* gml   = d_in[22];
    const void* dml   = d_in[23];

    const int N = in_sizes[0] / 512;     // 50000
    const int E = in_sizes[2];           // 100000

    const size_t ND2 = (size_t)N * 512 * 2;
    const size_t ND4 = (size_t)N * 512 * 4;
    const size_t arena_elems = (size_t)E + 2048 + 512 * 10 + 1024 + 2;
    const size_t arena_bytes = arena_elems * 4;
    // bf16 weight buffers: Wrel(4*512*512) + Wself(512*512) + Wf1(1024*512) + Wf2(512*1024)
    const size_t WRELN = 4ull * 512 * 512, WSELFN = 512ull * 512;
    const size_t WF1N = 1024ull * 512, WF2N = 512ull * 1024;
    const size_t WBFB = (WRELN + WSELFN + WF1N + WF2N) * 2;   // bytes
    const int NPART = 512;
    const size_t partB = (size_t)NPART * 512 * 4;             // 1 MB partial colsums
    const int nch = (N + 1023) / 1024;                        // scan chunks
    const size_t scanB = (size_t)(2 * nch + 8) * 4;           // sums + offs

    // fast path: base + Y4[N,2048]bf16 + S + CSR + misc + bf16 weights
    const size_t Y4B = (size_t)N * 2048 * 2;
    const size_t csrB = (size_t)(N + 1) * 4 + (size_t)N * 4 + (size_t)(2 * E) * 4 * 2;
    const size_t need_fast = ND2 + Y4B + ND2 + csrB + partB + 64 + scanB + WBFB + arena_bytes;
    // slow path (r3-proven): base + agg f32 + Ybuf + deg/partial/flags + weights + arena
    const size_t need_slow = ND2 + ND4 + ND2 + (size_t)N * 4 + partB + 64 + WBFB + arena_bytes;

    const int rowBlocks = (N + 3) / 4;
    const int Mt = (N + 127) / 128;
    const dim3 g512(512 / 128, Mt);
    const dim3 g1024(1024 / 128, Mt);
    const dim3 g2048(2048 / 128, Mt);

    if (ws_size >= need_fast) {
        // ------------------- FAST PATH: CSR gather -------------------
        char* p = (char*)d_ws;
        u16*   base   = (u16*)p;                         // ND2
        u16*   Y4     = (u16*)(p + ND2);                 // Y4B; later aliased by mid
        u16*   mid    = Y4;                              // FFN hidden [N,1024] bf16
        u16*   Sbuf   = (u16*)(p + ND2 + Y4B);           // ND2: S, later ffn_out/final x
        char*  q      = p + ND2 + Y4B + ND2;
        u32*   indptr = (u32*)q;                 q += (size_t)(N + 1) * 4;
        u32*   cursor = (u32*)q;                 q += (size_t)N * 4;   // also cnt
        u32*   srcrel = (u32*)q;                 q += (size_t)(2 * E) * 4;
        float* wts    = (float*)q;               q += (size_t)(2 * E) * 4;
        float* partial= (float*)q;               q += partB;
        int*   flags  = (int*)q;                 q += 64;
        u32*   sums   = (u32*)q;                 q += (size_t)nch * 4;
        u32*   offs   = (u32*)q;                 q += (size_t)(nch + 8) * 4;
        u16*   wrelc  = (u16*)q;                 q += WRELN * 2;
        u16*   wselfc = (u16*)q;                 q += WSELFN * 2;
        u16*   wf1c   = (u16*)q;                 q += WF1N * 2;
        u16*   wf2c   = (u16*)q;                 q += WF2N * 2;
        float* arena  = (float*)q;
        float* EWc   = arena;
        float* brelc = EWc + E;
        float* bselfc= brelc + 2048;
        float* ingc  = bselfc + 512;
        float* inbc  = ingc + 512;
        float* n1gc  = inbc + 512;
        float* n1bc  = n1gc + 512;
        float* bf1c  = n1bc + 512;
        float* bf2c  = bf1c + 1024;
        float* n2gc  = bf2c + 512;
        float* n2bc  = n2gc + 512;
        float* outgc = n2bc + 512;
        float* outbc = outgc + 512;
        float* gmlc  = outbc + 512;
        float* dmlc  = gmlc + 1;
        u16* x1 = (u16*)d_out;          // bf16 intermediate; overwritten by k_emit

        k_detect<<<1, 256, 0, stream>>>((const u16*)nf, (const u32*)EI, flags);
        hipMemsetAsync(cursor, 0, (size_t)N * 4, stream);   // cnt

        // ---- fused parameter conversion (one launch for all 19 jobs) ----
        CvtJobs J{};
        int nb = 0, nj = 0;
        auto addjob = [&](const void* s, void* d, int n, int kind) {
            J.src[nj] = s; J.dst[nj] = d; J.n[nj] = n; J.kind[nj] = kind;
            J.bstart[nj] = nb; nb += (n + 255) / 256; nj++;
        };
        addjob(EW, EWc, E, 0);         addjob(brel, brelc, 2048, 0);
        addjob(bself, bselfc, 512, 0); addjob(ing, ingc, 512, 0);
        addjob(inb, inbc, 512, 0);     addjob(n1g, n1gc, 512, 0);
        addjob(n1b, n1bc, 512, 0);     addjob(bf1, bf1c, 1024, 0);
        addjob(bf2, bf2c, 512, 0);     addjob(n2g, n2gc, 512, 0);
        addjob(n2b, n2bc, 512, 0);     addjob(outg, outgc, 512, 0);
        addjob(outb, outbc, 512, 0);   addjob(gml, gmlc, 1, 0);
        addjob(dml, dmlc, 1, 0);
        addjob(Wrel, wrelc, (int)WRELN, 1);   addjob(Wself, wselfc, (int)WSELFN, 1);
        addjob(Wf1, wf1c, (int)WF1N, 1);      addjob(Wf2, wf2c, (int)WF2N, 1);
        J.njobs = nj; J.bstart[nj] = nb;
        k_cvt_all<<<nb, 256, 0, stream>>>(J, flags);

        k_innorm<<<rowBlocks, 256, 0, stream>>>(nf, NT, NTE, ingc, inbc, base, N, flags);
        // CSR build (parallel 3-stage scan)
        k_count<<<(2 * E + 255) / 256, 256, 0, stream>>>(EI, cursor, E, flags);
        k_scan1<<<nch, 1024, 0, stream>>>(cursor, indptr, sums, N);
        k_scan2<<<1, 1024, 0, stream>>>(sums, offs, nch);
        k_scan3<<<(N + 255) / 256, 256, 0, stream>>>(indptr, offs, cursor, N, nch);
        k_fill<<<(2 * E + 255) / 256, 256, 0, stream>>>(EI, ET, EWc, cursor, srcrel, wts, E, flags);
        // transforms: Y4 = base @ Wrel_cat^T   ;   S = base @ Wself^T
        gemm_bt<0><<<g2048, 256, 0, stream>>>(base, wrelc, nullptr, Y4, N, 2048, 512);
        gemm_bt<0><<<g512, 256, 0, stream>>>(base, wselfc, nullptr, Sbuf, N, 512, 512);
        // fused gather + n1
        k_gather_n1<<<rowBlocks, 256, 0, stream>>>(indptr, srcrel, wts, Y4, Sbuf, base,
                                                   brelc, bselfc, n1gc, n1bc, x1, N);
        // FFN (mid aliases Y4, which is dead now; ffn_out into Sbuf, dead too)
        gemm_bt<1><<<g1024, 256, 0, stream>>>(x1, wf1c, bf1c, mid, N, 1024, 512);
        gemm_bt<0><<<g512, 256, 0, stream>>>(mid, wf2c, bf2c, Sbuf, N, 512, 1024);

        k_final<<<rowBlocks, 256, 0, stream>>>(x1, Sbuf, base, n2gc, n2bc, outgc, outbc,
                                               gmlc, N);
        k_colsum<<<NPART, 256, 0, stream>>>(Sbuf, partial, N);
        k_emit<<<(int)(((long)N * 512 / 8 + 255) / 256), 256, 0, stream>>>(Sbuf, d_out,
                                                                           (long)N * 512, flags);
        k_pooled<<<512, 256, 0, stream>>>(Sbuf, partial, dmlc, d_out, (long)N * 512, N, flags);

    } else if (ws_size >= need_slow) {
        // ------------------- SLOW PATH (r3-proven) -------------------
        char* p = (char*)d_ws;
        u16*   base = (u16*)p;
        float* agg  = (float*)(p + ND2);
        u16*   mid  = (u16*)(p + ND2);
        u16*   Ybuf = (u16*)(p + ND2 + ND4);
        float* deg  = (float*)(p + ND2 + ND4 + ND2);
        float* partial = deg + N;
        int*   flags  = (int*)(partial + NPART * 512);
        char*  q2     = (char*)flags + 64;
        u16*   wrelc  = (u16*)q2;                q2 += WRELN * 2;
        u16*   wselfc = (u16*)q2;                q2 += WSELFN * 2;
        u16*   wf1c   = (u16*)q2;                q2 += WF1N * 2;
        u16*   wf2c   = (u16*)q2;                q2 += WF2N * 2;
        float* arena  = (float*)q2;
        float* EWc   = arena;
        float* brelc = EWc + E;
        float* bselfc= brelc + 2048;
        float* ingc  = bselfc + 512;
        float* inbc  = ingc + 512;
        float* n1gc  = inbc + 512;
        float* n1bc  = n1gc + 512;
        float* bf1c  = n1bc + 512;
        float* bf2c  = bf1c + 1024;
        float* n2gc  = bf2c + 512;
        float* n2bc  = n2gc + 512;
        float* outgc = n2bc + 512;
        float* outbc = outgc + 512;
        float* gmlc  = outbc + 512;
        float* dmlc  = gmlc + 1;
        u16* x1 = (u16*)d_out;

        k_detect<<<1, 256, 0, stream>>>((const u16*)nf, (const u32*)EI, flags);
        hipMemsetAsync(agg, 0, ND4, stream);
        hipMemsetAsync(deg, 0, (size_t)N * 4, stream);

        CvtJobs J{};
        int nb = 0, nj = 0;
        auto addjob = [&](const void* s, void* d, int n, int kind) {
            J.src[nj] = s; J.dst[nj] = d; J.n[nj] = n; J.kind[nj] = kind;
            J.bstart[nj] = nb; nb += (n + 255) / 256; nj++;
        };
        addjob(EW, EWc, E, 0);         addjob(brel, brelc, 2048, 0);
        addjob(bself, bselfc, 512, 0); addjob(ing, ingc, 512, 0);
        addjob(inb, inbc, 512, 0);     addjob(n1g, n1gc, 512, 0);
        addjob(n1b, n1bc, 512, 0);     addjob(bf1, bf1c, 1024, 0);
        addjob(bf2, bf2c, 512, 0);     addjob(n2g, n2gc, 512, 0);
        addjob(n2b, n2bc, 512, 0);     addjob(outg, outgc, 512, 0);
        addjob(outb, outbc, 512, 0);   addjob(gml, gmlc, 1, 0);
        addjob(dml, dmlc, 1, 0);
        addjob(Wrel, wrelc, (int)WRELN, 1);   addjob(Wself, wselfc, (int)WSELFN, 1);
        addjob(Wf1, wf1c, (int)WF1N, 1);      addjob(Wf2, wf2c, (int)WF2N, 1);
        J.njobs = nj; J.bstart[nj] = nb;
        k_cvt_all<<<nb, 256, 0, stream>>>(J, flags);

        k_innorm<<<rowBlocks, 256, 0, stream>>>(nf, NT, NTE, ingc, inbc, base, N, flags);
        k_deg<<<(2 * E + 255) / 256, 256, 0, stream>>>(EI, EWc, deg, E, flags);

        for (int r = 0; r < 4; r++) {
            gemm_bt<0><<<g512, 256, 0, stream>>>(base, wrelc + (size_t)r * 512 * 512, nullptr,
                                                 Ybuf, N, 512, 512);
            k_scatter<<<(2 * E + 3) / 4, 256, 0, stream>>>(EI, ET, EWc, Ybuf, brelc, agg,
                                                           E, r, flags);
        }

        gemm_bt<0><<<g512, 256, 0, stream>>>(base, wselfc, nullptr, Ybuf, N, 512, 512);
        k_n1<<<rowBlocks, 256, 0, stream>>>(Ybuf, agg, deg, bselfc, base, n1gc, n1bc, x1, N);

        gemm_bt<1><<<g1024, 256, 0, stream>>>(x1, wf1c, bf1c, mid, N, 1024, 512);
        gemm_bt<0><<<g512, 256, 0, stream>>>(mid, wf2c, bf2c, Ybuf, N, 512, 1024);

        k_final<<<rowBlocks, 256, 0, stream>>>(x1, Ybuf, base, n2gc, n2bc, outgc, outbc,
                                               gmlc, N);
        k_colsum<<<NPART, 256, 0, stream>>>(Ybuf, partial, N);
        k_emit<<<(int)(((long)N * 512 / 8 + 255) / 256), 256, 0, stream>>>(Ybuf, d_out,
                                                                           (long)N * 512, flags);
        k_pooled<<<512, 256, 0, stream>>>(Ybuf, partial, dmlc, d_out, (long)N * 512, N, flags);
    } else {
        const float val = 2000.f + (float)(ws_size >> 20);
        k_diag<<<(out_size + 255) / 256, 256, 0, stream>>>((u16*)d_out, out_size, val);
    }
}